// Round 9
// baseline (876.098 us; speedup 1.0000x reference)
//
#include <hip/hip_runtime.h>
#include <stdint.h>

namespace {

constexpr int NN   = 100000;    // nodes per graph
constexpr int NEDG = 1600000;   // edges per graph
constexpr int TE   = 2 * NEDG;  // 3.2M edges across both graphs
constexpr int NBAT = 512;       // graphs per batch
constexpr int NSEG = 33;        // piecewise-linear segments of edge MLP (32 breakpoints)

// coarse partition: 256 dst-nodes per coarse bucket
constexpr int NC     = 782;     // ceil(2*NN / 256)
constexpr int TILE   = 4096;    // edges per partition block (16 per thread)
constexpr int ABLK   = (TE + TILE - 1) / TILE;  // 782
constexpr int ENTCAP = 5120;    // max entries per coarse bucket (mean 4096, +16 sigma)

// padded LDS strides for the conv edge tables: stride mod 32 = 4 so the
// random per-edge segment id g spreads lanes across bank offsets
// (stride 64/32 gave g*stride mod 32 == 0 -> 8-way conflicts, 8.2M cycles/r8)
constexpr int S1 = 36;  // conv1 (32 features)
constexpr int S2 = 68;  // conv2 (64 features)

// table layout (floats): bp[32] | d1[NSEG*32] | c1[NSEG*32] | per-enc {d2[NSEG*64], c2[NSEG*64]} x2
constexpr int TAB_BP = 0;
constexpr int TAB_D1 = 32;
constexpr int TAB_C1 = TAB_D1 + NSEG * 32;
constexpr int TAB_E2 = TAB_C1 + NSEG * 32;
constexpr int TAB_TOTAL = TAB_E2 + 4 * NSEG * 64;

__device__ __forceinline__ float relu_(float x) { return fmaxf(x, 0.0f); }

__device__ __forceinline__ float4 shfl_xor4(float4 v, int m) {
  return make_float4(__shfl_xor(v.x, m), __shfl_xor(v.y, m),
                     __shfl_xor(v.z, m), __shfl_xor(v.w, m));
}

// ---------------------------------------------------------------------------
// Precompute piecewise-linear tables for e(a) = relu(a*W1+b1)@W2+b2 and the
// folded e2(a) = e(a)@linW + linb. Exact reassociation of the reference math.
// ---------------------------------------------------------------------------
__global__ void build_tables(const float* __restrict__ eW1, const float* __restrict__ eb1,
                             const float* __restrict__ eW2, const float* __restrict__ eb2,
                             const float* __restrict__ sLW, const float* __restrict__ sLb,
                             const float* __restrict__ gLW, const float* __restrict__ gLb,
                             float* __restrict__ tabs) {
  __shared__ float traw[32];
  __shared__ float ts[32];
  __shared__ float dt[NSEG * 32];
  __shared__ float ct[NSEG * 32];
  int tid = threadIdx.x;
  if (tid < 32) {
    float w = eW1[tid], b = eb1[tid];
    traw[tid] = (w != 0.0f) ? (-b / w) : 3.0e38f;
  }
  __syncthreads();
  if (tid < 32) {  // rank sort (stable for duplicates)
    float v = traw[tid];
    int r = 0;
    for (int j = 0; j < 32; ++j) {
      float u = traw[j];
      r += (u < v) || (u == v && j < tid);
    }
    ts[r] = v;
  }
  __syncthreads();
  if (tid < 32) tabs[TAB_BP + tid] = ts[tid];
  for (int idx = tid; idx < NSEG * 32; idx += blockDim.x) {
    int s = idx >> 5, j = idx & 31;
    float a;  // representative point strictly inside segment s: (ts[s-1], ts[s]]
    if (s == 0)            a = ts[0] - 1.0f;
    else if (s == NSEG - 1) a = ts[31] + 1.0f;
    else                   a = 0.5f * ts[s - 1] + 0.5f * ts[s];
    float d = 0.0f, c = 0.0f;
    for (int i = 0; i < 32; ++i) {
      float w = eW1[i], b = eb1[i];
      if (fmaf(a, w, b) > 0.0f) {
        float w2 = eW2[i * 32 + j];
        d = fmaf(w, w2, d);
        c = fmaf(b, w2, c);
      }
    }
    c += eb2[j];
    dt[idx] = d; ct[idx] = c;
    tabs[TAB_D1 + idx] = d;
    tabs[TAB_C1 + idx] = c;
  }
  __syncthreads();
  for (int idx = tid; idx < NSEG * 64; idx += blockDim.x) {
    int s = idx >> 6, k = idx & 63;
    float ds = 0.f, cs = 0.f, dg = 0.f, cg = 0.f;
    for (int j = 0; j < 32; ++j) {
      float dv = dt[s * 32 + j], cv = ct[s * 32 + j];
      float ws = sLW[j * 64 + k], wg = gLW[j * 64 + k];
      ds = fmaf(dv, ws, ds); cs = fmaf(cv, ws, cs);
      dg = fmaf(dv, wg, dg); cg = fmaf(cv, wg, cg);
    }
    cs += sLb[k]; cg += gLb[k];
    tabs[TAB_E2 + idx]                 = ds;
    tabs[TAB_E2 + NSEG * 64 + idx]     = cs;
    tabs[TAB_E2 + 2 * NSEG * 64 + idx] = dg;
    tabs[TAB_E2 + 3 * NSEG * 64 + idx] = cg;
  }
}

// ---------------------------------------------------------------------------
// x0[n,32] = MLP2(clip((names+2)/SCALE,0,1))
// ---------------------------------------------------------------------------
__global__ __launch_bounds__(256, 2) void node_embed(
    const int* __restrict__ names,
    const float* __restrict__ W1, const float* __restrict__ b1,
    const float* __restrict__ W2, const float* __restrict__ b2,
    float* __restrict__ x0) {
  int n = blockIdx.x * 256 + threadIdx.x;
  if (n >= NN) return;
  float norm = ((float)names[n] + 2.0f) / 281474976710655.0f;
  norm = fminf(fmaxf(norm, 0.0f), 1.0f);
  float h[32];
#pragma unroll
  for (int i = 0; i < 32; ++i) h[i] = relu_(fmaf(norm, W1[i], b1[i]));
  float4* out = (float4*)(x0 + (size_t)n * 32);
  for (int j0 = 0; j0 < 32; j0 += 4) {
    float a0 = b2[j0], a1 = b2[j0 + 1], a2 = b2[j0 + 2], a3 = b2[j0 + 3];
#pragma unroll
    for (int i = 0; i < 32; ++i) {
      float hv = h[i];
      a0 = fmaf(hv, W2[i * 32 + j0],     a0);
      a1 = fmaf(hv, W2[i * 32 + j0 + 1], a1);
      a2 = fmaf(hv, W2[i * 32 + j0 + 2], a2);
      a3 = fmaf(hv, W2[i * 32 + j0 + 3], a3);
    }
    out[j0 >> 2] = make_float4(a0, a1, a2, a3);
  }
}

// ---------------------------------------------------------------------------
// CSR build, dense-write edition (round 8: WRITE amp 7x -> ~2x, fixed).
// ---------------------------------------------------------------------------
__global__ __launch_bounds__(256) void coarse_hist(
    const int* __restrict__ dst_s, const int* __restrict__ dst_g,
    int* __restrict__ ccnt) {
  __shared__ int h[NC];
  for (int i = threadIdx.x; i < NC; i += 256) h[i] = 0;
  __syncthreads();
  int base = blockIdx.x * TILE;
#pragma unroll
  for (int j = 0; j < 16; ++j) {
    int i = base + j * 256 + threadIdx.x;
    if (i < TE) {
      int d = (i < NEDG) ? dst_s[i] : (dst_g[i - NEDG] + NN);
      atomicAdd(&h[d >> 8], 1);
    }
  }
  __syncthreads();
  for (int i = threadIdx.x; i < NC; i += 256)
    if (h[i]) atomicAdd(&ccnt[i], h[i]);
}

__global__ __launch_bounds__(1024) void coarse_scan(
    const int* __restrict__ ccnt, int* __restrict__ cbase,
    int* __restrict__ gcur, int* __restrict__ rowptr) {
  __shared__ int s[1024];
  int t = threadIdx.x;
  int v = (t < NC) ? ccnt[t] : 0;
  s[t] = v;
  __syncthreads();
  for (int st = 1; st < 1024; st <<= 1) {
    int u = (t >= st) ? s[t - st] : 0;
    __syncthreads();
    s[t] += u;
    __syncthreads();
  }
  if (t < NC) { cbase[t] = s[t] - v; gcur[t] = s[t] - v; }
  if (t == 0) rowptr[2 * NN] = TE;
}

__global__ __launch_bounds__(256) void coarse_partition(
    const int* __restrict__ src_s, const int* __restrict__ dst_s, const float* __restrict__ attr_s,
    const int* __restrict__ src_g, const int* __restrict__ dst_g, const float* __restrict__ attr_g,
    int* __restrict__ gcur, int2* __restrict__ part) {
  __shared__ int hist[NC];      // counts, then overwritten with global base
  __shared__ int lofs[NC];
  __shared__ int lcur[NC];
  __shared__ int2 sorted[TILE]; // 32 KB
  __shared__ int addr[TILE];    // 16 KB
  __shared__ int scanbuf[256];
  int t = threadIdx.x;
  for (int i = t; i < NC; i += 256) hist[i] = 0;
  __syncthreads();
  int base = blockIdx.x * TILE;
#pragma unroll
  for (int j = 0; j < 16; ++j) {
    int i = base + j * 256 + t;
    if (i < TE) {
      int d = (i < NEDG) ? dst_s[i] : (dst_g[i - NEDG] + NN);
      atomicAdd(&hist[d >> 8], 1);
    }
  }
  __syncthreads();
  int loc[4];
  int sum = 0;
#pragma unroll
  for (int j = 0; j < 4; ++j) {
    int b = t * 4 + j;
    int v = (b < NC) ? hist[b] : 0;
    loc[j] = sum; sum += v;
  }
  scanbuf[t] = sum;
  __syncthreads();
  for (int st = 1; st < 256; st <<= 1) {
    int u = (t >= st) ? scanbuf[t - st] : 0;
    __syncthreads();
    scanbuf[t] += u;
    __syncthreads();
  }
  int texcl = scanbuf[t] - sum;
#pragma unroll
  for (int j = 0; j < 4; ++j) {
    int b = t * 4 + j;
    if (b < NC) { lofs[b] = texcl + loc[j]; lcur[b] = 0; }
  }
  __syncthreads();
  for (int b = t; b < NC; b += 256) {
    int c = hist[b];
    hist[b] = c ? atomicAdd(&gcur[b], c) : 0;
  }
  __syncthreads();
#pragma unroll
  for (int j = 0; j < 16; ++j) {
    int i = base + j * 256 + t;
    if (i < TE) {
      int sl, d; float a;
      if (i < NEDG) { sl = src_s[i]; d = dst_s[i]; a = attr_s[i]; }
      else { int k = i - NEDG; sl = src_g[k]; d = dst_g[k] + NN; a = attr_g[k]; }
      int c = d >> 8;
      int r = atomicAdd(&lcur[c], 1);
      int s = lofs[c] + r;
      sorted[s] = make_int2(sl | ((d & 255) << 17), __float_as_int(a));
      addr[s] = hist[c] + r;
    }
  }
  __syncthreads();
  int tot = (base + TILE <= TE) ? TILE : (TE - base);
  for (int s = t; s < tot; s += 256) part[addr[s]] = sorted[s];
}

__global__ __launch_bounds__(256) void partition_to_csr(
    const int* __restrict__ ccnt, const int* __restrict__ cbase,
    const int2* __restrict__ part, const float* __restrict__ tabs,
    int* __restrict__ rowptr, int2* __restrict__ colattr) {
  __shared__ int2 outE[ENTCAP];  // 40 KB
  __shared__ int hist[256];
  __shared__ int cur[256];
  __shared__ int sc[256];
  __shared__ float bp[32];
  int t = threadIdx.x, b = blockIdx.x;  // grid exact: NC
  if (t < 32) bp[t] = tabs[TAB_BP + t];
  hist[t] = 0;
  __syncthreads();
  int cnt = ccnt[b], base = cbase[b];
  for (int i = t; i < cnt; i += 256)
    atomicAdd(&hist[(part[base + i].x >> 17) & 255], 1);
  __syncthreads();
  int v = hist[t];
  sc[t] = v;
  __syncthreads();
  for (int st = 1; st < 256; st <<= 1) {
    int u = (t >= st) ? sc[t - st] : 0;
    __syncthreads();
    sc[t] += u;
    __syncthreads();
  }
  int excl = sc[t] - v;
  int gnode = b * 256 + t;
  if (gnode < 2 * NN) rowptr[gnode] = base + excl;
  cur[t] = excl;
  __syncthreads();
  for (int i = t; i < cnt; i += 256) {
    int2 e = part[base + i];
    int dl = (e.x >> 17) & 255;
    int srcn = e.x & 0x1FFFF;
    float a = __int_as_float(e.y);
    int seg = 0;
#pragma unroll
    for (int k = 0; k < 32; ++k) seg += (bp[k] < a);
    int pos = atomicAdd(&cur[dl], 1);
    outE[pos] = make_int2(srcn | (seg << 20), e.y);  // src<2^17, seg<64
  }
  __syncthreads();
  for (int i = t; i < cnt; i += 256) colattr[base + i] = outE[i];
}

// ---------------------------------------------------------------------------
// GINE aggregation, dst-major. One WAVE per node; 16 edge slots per wave
// (sub = lane&15), 4 lanes per edge, so a degree-16 node's 16 row-gathers
// issue in ONE independent burst (was 2 dependent rounds of 8).
// hb[n] = x[n] + sum_j relu(x[src_j] + e_j). Edge tables in LDS at padded
// stride (S1/S2, mod 32 = 4) to kill the 8-way bank conflicts of round 8.
// ---------------------------------------------------------------------------
__global__ __launch_bounds__(256) void conv1_agg(
    const float* __restrict__ x0, const int* __restrict__ rowptr,
    const int2* __restrict__ colattr, const float* __restrict__ tabs,
    float* __restrict__ hb) {
  __shared__ float dt[NSEG * S1];
  __shared__ float ct[NSEG * S1];
  for (int i = threadIdx.x; i < NSEG * 32; i += 256) {
    int s = i >> 5, j = i & 31;
    dt[s * S1 + j] = tabs[TAB_D1 + i];
    ct[s * S1 + j] = tabs[TAB_C1 + i];
  }
  __syncthreads();
  int n = blockIdx.x * 4 + (threadIdx.x >> 6);  // grid exact: NN/4
  int lane = threadIdx.x & 63;
  int sub = lane & 15;        // 16 edge slots
  int f0  = (lane >> 4) * 8;  // 4 lanes/edge x 8 features
  int beg = rowptr[n], end = rowptr[n + 1];
  float4 accA = make_float4(0.f, 0.f, 0.f, 0.f);
  float4 accB = make_float4(0.f, 0.f, 0.f, 0.f);
  for (int k = beg + sub; k < end; k += 16) {
    int2 ca = colattr[k];
    unsigned p = (unsigned)ca.x;
    int s = (int)(p & 0xFFFFFu), g = (int)(p >> 20);
    float a = __int_as_float(ca.y);
    const float* r = x0 + (size_t)s * 32 + f0;
    float4 xa = *(const float4*)r;
    float4 xb = *(const float4*)(r + 4);
    const float* dp = dt + g * S1 + f0;
    const float* cp = ct + g * S1 + f0;
    float4 da = *(const float4*)dp;
    float4 db = *(const float4*)(dp + 4);
    float4 ea = *(const float4*)cp;
    float4 eb = *(const float4*)(cp + 4);
    accA.x += relu_(xa.x + fmaf(a, da.x, ea.x));
    accA.y += relu_(xa.y + fmaf(a, da.y, ea.y));
    accA.z += relu_(xa.z + fmaf(a, da.z, ea.z));
    accA.w += relu_(xa.w + fmaf(a, da.w, ea.w));
    accB.x += relu_(xb.x + fmaf(a, db.x, eb.x));
    accB.y += relu_(xb.y + fmaf(a, db.y, eb.y));
    accB.z += relu_(xb.z + fmaf(a, db.z, eb.z));
    accB.w += relu_(xb.w + fmaf(a, db.w, eb.w));
  }
#pragma unroll
  for (int m = 1; m < 16; m <<= 1) {
    float4 oA = shfl_xor4(accA, m);
    float4 oB = shfl_xor4(accB, m);
    accA.x += oA.x; accA.y += oA.y; accA.z += oA.z; accA.w += oA.w;
    accB.x += oB.x; accB.y += oB.y; accB.z += oB.z; accB.w += oB.w;
  }
  if (sub == 0) {
    const float* sp = x0 + (size_t)n * 32 + f0;
    const float4 sA = *(const float4*)sp;
    const float4 sB = *(const float4*)(sp + 4);
    float* op = hb + (size_t)n * 32 + f0;
    *(float4*)op       = make_float4(sA.x + accA.x, sA.y + accA.y, sA.z + accA.z, sA.w + accA.w);
    *(float4*)(op + 4) = make_float4(sB.x + accB.x, sB.y + accB.y, sB.z + accB.z, sB.w + accB.w);
  }
}

__global__ __launch_bounds__(256) void conv2_agg(
    const float* __restrict__ x1, const int* __restrict__ rowptr,
    const int2* __restrict__ colattr, const float* __restrict__ tabs, int enc,
    float* __restrict__ hb) {
  __shared__ float dt[NSEG * S2];
  __shared__ float ct[NSEG * S2];
  const float* d2 = tabs + TAB_E2 + (size_t)enc * 2 * NSEG * 64;
  for (int i = threadIdx.x; i < NSEG * 64; i += 256) {
    int s = i >> 6, j = i & 63;
    dt[s * S2 + j] = d2[i];
    ct[s * S2 + j] = d2[NSEG * 64 + i];
  }
  __syncthreads();
  int n = blockIdx.x * 4 + (threadIdx.x >> 6);  // grid exact: NN/4
  int lane = threadIdx.x & 63;
  int sub = lane & 15;         // 16 edge slots
  int f0  = (lane >> 4) * 16;  // 4 lanes/edge x 16 features
  int beg = rowptr[n], end = rowptr[n + 1];
  float4 acc0 = make_float4(0.f, 0.f, 0.f, 0.f);
  float4 acc1 = acc0, acc2 = acc0, acc3 = acc0;
  for (int k = beg + sub; k < end; k += 16) {
    int2 ca = colattr[k];
    unsigned p = (unsigned)ca.x;
    int s = (int)(p & 0xFFFFFu), g = (int)(p >> 20);
    float a = __int_as_float(ca.y);
    const float* r = x1 + (size_t)s * 64 + f0;
    float4 x0v = *(const float4*)r;
    float4 x1v = *(const float4*)(r + 4);
    float4 x2v = *(const float4*)(r + 8);
    float4 x3v = *(const float4*)(r + 12);
    const float* dp = dt + g * S2 + f0;
    const float* cp = ct + g * S2 + f0;
    float4 d0 = *(const float4*)dp;
    float4 d1 = *(const float4*)(dp + 4);
    float4 d2v = *(const float4*)(dp + 8);
    float4 d3 = *(const float4*)(dp + 12);
    float4 e0 = *(const float4*)cp;
    float4 e1 = *(const float4*)(cp + 4);
    float4 e2 = *(const float4*)(cp + 8);
    float4 e3 = *(const float4*)(cp + 12);
    acc0.x += relu_(x0v.x + fmaf(a, d0.x, e0.x));
    acc0.y += relu_(x0v.y + fmaf(a, d0.y, e0.y));
    acc0.z += relu_(x0v.z + fmaf(a, d0.z, e0.z));
    acc0.w += relu_(x0v.w + fmaf(a, d0.w, e0.w));
    acc1.x += relu_(x1v.x + fmaf(a, d1.x, e1.x));
    acc1.y += relu_(x1v.y + fmaf(a, d1.y, e1.y));
    acc1.z += relu_(x1v.z + fmaf(a, d1.z, e1.z));
    acc1.w += relu_(x1v.w + fmaf(a, d1.w, e1.w));
    acc2.x += relu_(x2v.x + fmaf(a, d2v.x, e2.x));
    acc2.y += relu_(x2v.y + fmaf(a, d2v.y, e2.y));
    acc2.z += relu_(x2v.z + fmaf(a, d2v.z, e2.z));
    acc2.w += relu_(x2v.w + fmaf(a, d2v.w, e2.w));
    acc3.x += relu_(x3v.x + fmaf(a, d3.x, e3.x));
    acc3.y += relu_(x3v.y + fmaf(a, d3.y, e3.y));
    acc3.z += relu_(x3v.z + fmaf(a, d3.z, e3.z));
    acc3.w += relu_(x3v.w + fmaf(a, d3.w, e3.w));
  }
#pragma unroll
  for (int m = 1; m < 16; m <<= 1) {
    float4 o0 = shfl_xor4(acc0, m);
    float4 o1 = shfl_xor4(acc1, m);
    float4 o2 = shfl_xor4(acc2, m);
    float4 o3 = shfl_xor4(acc3, m);
    acc0.x += o0.x; acc0.y += o0.y; acc0.z += o0.z; acc0.w += o0.w;
    acc1.x += o1.x; acc1.y += o1.y; acc1.z += o1.z; acc1.w += o1.w;
    acc2.x += o2.x; acc2.y += o2.y; acc2.z += o2.z; acc2.w += o2.w;
    acc3.x += o3.x; acc3.y += o3.y; acc3.z += o3.z; acc3.w += o3.w;
  }
  if (sub == 0) {
    const float* sp = x1 + (size_t)n * 64 + f0;
    float* op = hb + (size_t)n * 64 + f0;
    float4 s0 = *(const float4*)sp;
    float4 s1 = *(const float4*)(sp + 4);
    float4 s2 = *(const float4*)(sp + 8);
    float4 s3 = *(const float4*)(sp + 12);
    *(float4*)op        = make_float4(s0.x + acc0.x, s0.y + acc0.y, s0.z + acc0.z, s0.w + acc0.w);
    *(float4*)(op + 4)  = make_float4(s1.x + acc1.x, s1.y + acc1.y, s1.z + acc1.z, s1.w + acc1.w);
    *(float4*)(op + 8)  = make_float4(s2.x + acc2.x, s2.y + acc2.y, s2.z + acc2.z, s2.w + acc2.w);
    *(float4*)(op + 12) = make_float4(s3.x + acc3.x, s3.y + acc3.y, s3.z + acc3.z, s3.w + acc3.w);
  }
}

// ---------------------------------------------------------------------------
// Per-node MLP2 (IN -> 64 -> 64), relu on both layers + output (conv wrapper).
// Register-tiled VALU GEMM: 64 nodes/block, thread owns 4 nodes x 4 features.
// ---------------------------------------------------------------------------
template <int IN>
__global__ __launch_bounds__(256) void node_mlp_tile(
    const float* __restrict__ hin,
    const float* __restrict__ W1, const float* __restrict__ b1,
    const float* __restrict__ W2, const float* __restrict__ b2,
    float* __restrict__ xout) {
  __shared__ float hsT[IN][65];   // [k][node], stride 65 -> conflict-free
  __shared__ float ysT[64][65];   // [feature][node]
  int base = blockIdx.x * 64;
  int count = NN - base; if (count > 64) count = 64;
  for (int idx = threadIdx.x; idx < 64 * IN; idx += 256) {
    int node = idx / IN, k = idx - node * IN;
    float v = (node < count) ? hin[(size_t)(base + node) * IN + k] : 0.0f;
    hsT[k][node] = v;
  }
  __syncthreads();
  int nt = threadIdx.x >> 4;   // node quad [0,16)
  int jx = threadIdx.x & 15;   // feature quad [0,16)
  int n0 = nt * 4, f0 = jx * 4;
  float4 acc0, acc1, acc2, acc3;
  {
    const float4 b = *(const float4*)(b1 + f0);
    acc0 = b; acc1 = b; acc2 = b; acc3 = b;
  }
  for (int k = 0; k < IN; ++k) {
    const float4 h = *(const float4*)&hsT[k][n0];
    const float4 w = *(const float4*)(W1 + k * 64 + f0);
    acc0.x = fmaf(h.x, w.x, acc0.x); acc0.y = fmaf(h.x, w.y, acc0.y);
    acc0.z = fmaf(h.x, w.z, acc0.z); acc0.w = fmaf(h.x, w.w, acc0.w);
    acc1.x = fmaf(h.y, w.x, acc1.x); acc1.y = fmaf(h.y, w.y, acc1.y);
    acc1.z = fmaf(h.y, w.z, acc1.z); acc1.w = fmaf(h.y, w.w, acc1.w);
    acc2.x = fmaf(h.z, w.x, acc2.x); acc2.y = fmaf(h.z, w.y, acc2.y);
    acc2.z = fmaf(h.z, w.z, acc2.z); acc2.w = fmaf(h.z, w.w, acc2.w);
    acc3.x = fmaf(h.w, w.x, acc3.x); acc3.y = fmaf(h.w, w.y, acc3.y);
    acc3.z = fmaf(h.w, w.z, acc3.z); acc3.w = fmaf(h.w, w.w, acc3.w);
  }
  ysT[f0 + 0][n0 + 0] = relu_(acc0.x); ysT[f0 + 1][n0 + 0] = relu_(acc0.y);
  ysT[f0 + 2][n0 + 0] = relu_(acc0.z); ysT[f0 + 3][n0 + 0] = relu_(acc0.w);
  ysT[f0 + 0][n0 + 1] = relu_(acc1.x); ysT[f0 + 1][n0 + 1] = relu_(acc1.y);
  ysT[f0 + 2][n0 + 1] = relu_(acc1.z); ysT[f0 + 3][n0 + 1] = relu_(acc1.w);
  ysT[f0 + 0][n0 + 2] = relu_(acc2.x); ysT[f0 + 1][n0 + 2] = relu_(acc2.y);
  ysT[f0 + 2][n0 + 2] = relu_(acc2.z); ysT[f0 + 3][n0 + 2] = relu_(acc2.w);
  ysT[f0 + 0][n0 + 3] = relu_(acc3.x); ysT[f0 + 1][n0 + 3] = relu_(acc3.y);
  ysT[f0 + 2][n0 + 3] = relu_(acc3.z); ysT[f0 + 3][n0 + 3] = relu_(acc3.w);
  __syncthreads();
  {
    const float4 b = *(const float4*)(b2 + f0);
    acc0 = b; acc1 = b; acc2 = b; acc3 = b;
  }
  for (int k = 0; k < 64; ++k) {
    const float4 h = *(const float4*)&ysT[k][n0];
    const float4 w = *(const float4*)(W2 + k * 64 + f0);
    acc0.x = fmaf(h.x, w.x, acc0.x); acc0.y = fmaf(h.x, w.y, acc0.y);
    acc0.z = fmaf(h.x, w.z, acc0.z); acc0.w = fmaf(h.x, w.w, acc0.w);
    acc1.x = fmaf(h.y, w.x, acc1.x); acc1.y = fmaf(h.y, w.y, acc1.y);
    acc1.z = fmaf(h.y, w.z, acc1.z); acc1.w = fmaf(h.y, w.w, acc1.w);
    acc2.x = fmaf(h.z, w.x, acc2.x); acc2.y = fmaf(h.z, w.y, acc2.y);
    acc2.z = fmaf(h.z, w.z, acc2.z); acc2.w = fmaf(h.z, w.w, acc2.w);
    acc3.x = fmaf(h.w, w.x, acc3.x); acc3.y = fmaf(h.w, w.y, acc3.y);
    acc3.z = fmaf(h.w, w.z, acc3.z); acc3.w = fmaf(h.w, w.w, acc3.w);
  }
  float4 o;
  if (0 < count - n0) {
    o = make_float4(relu_(acc0.x), relu_(acc0.y), relu_(acc0.z), relu_(acc0.w));
    *(float4*)(xout + (size_t)(base + n0 + 0) * 64 + f0) = o;
  }
  if (1 < count - n0) {
    o = make_float4(relu_(acc1.x), relu_(acc1.y), relu_(acc1.z), relu_(acc1.w));
    *(float4*)(xout + (size_t)(base + n0 + 1) * 64 + f0) = o;
  }
  if (2 < count - n0) {
    o = make_float4(relu_(acc2.x), relu_(acc2.y), relu_(acc2.z), relu_(acc2.w));
    *(float4*)(xout + (size_t)(base + n0 + 2) * 64 + f0) = o;
  }
  if (3 < count - n0) {
    o = make_float4(relu_(acc3.x), relu_(acc3.y), relu_(acc3.z), relu_(acc3.w));
    *(float4*)(xout + (size_t)(base + n0 + 3) * 64 + f0) = o;
  }
}

// ---------------------------------------------------------------------------
// Batch boundaries from the SORTED batch array (no atomics).
// ---------------------------------------------------------------------------
__global__ __launch_bounds__(256) void batch_bounds_dual(
    const int* __restrict__ bat_s, const int* __restrict__ bat_g,
    int* __restrict__ start_s, int* __restrict__ start_g) {
  int half = blockIdx.x >= 391;
  const int* bat = half ? bat_g : bat_s;
  int* start = half ? start_g : start_s;
  int i = (blockIdx.x - half * 391) * 256 + threadIdx.x;
  if (i >= NN) return;
  int cur = bat[i];
  int prev = (i == 0) ? -1 : bat[i - 1];
  for (int b = prev + 1; b <= cur; ++b) start[b] = i;
  if (i == NN - 1) {
    for (int b = cur + 1; b <= NBAT; ++b) start[b] = NN;
  }
}

__global__ __launch_bounds__(256) void pool_mean(
    const float* __restrict__ x2, const int* __restrict__ start, float* __restrict__ pool) {
  __shared__ float s[4][64];
  int g = blockIdx.x;
  int f = threadIdx.x & 63, c = threadIdx.x >> 6;
  int beg = start[g], end = start[g + 1];
  float acc = 0.0f;
  for (int n = beg + c; n < end; n += 4) acc += x2[(size_t)n * 64 + f];
  s[c][f] = acc;
  __syncthreads();
  if (c == 0) {
    float tot = s[0][f] + s[1][f] + s[2][f] + s[3][f];
    float m = (float)(end - beg);
    pool[g * 64 + f] = tot / fmaxf(m, 1.0f);
  }
}

// ---------------------------------------------------------------------------
// regressor: out[b] = relu([s|g|depth] @ rW1 + rb1) @ rW2 + rb2
// ---------------------------------------------------------------------------
__global__ __launch_bounds__(256) void regressor16(
    const float* __restrict__ ps, const float* __restrict__ pg, const float* __restrict__ depth,
    const float* __restrict__ W1, const float* __restrict__ b1,
    const float* __restrict__ W2, const float* __restrict__ b2,
    float* __restrict__ out) {
  __shared__ float zs[16][132];   // [row][k], k in [0,129)
  __shared__ float ys[64][17];
  int base = blockIdx.x * 16;     // grid 32 blocks x 16 rows = 512 exact
  for (int i = threadIdx.x; i < 16 * 64; i += 256) {
    int ln = i >> 6, k = i & 63;
    zs[ln][k]      = ps[(size_t)(base + ln) * 64 + k];
    zs[ln][64 + k] = pg[(size_t)(base + ln) * 64 + k];
  }
  if (threadIdx.x < 16) zs[threadIdx.x][128] = depth[base + threadIdx.x];
  __syncthreads();
  int g = threadIdx.x >> 4;
  int j = threadIdx.x & 15;
  int f0 = j * 4;
  float a0, a1, a2, a3;
  {
    const float4 b = *(const float4*)(b1 + f0);
    a0 = b.x; a1 = b.y; a2 = b.z; a3 = b.w;
  }
  for (int k = 0; k < 129; ++k) {
    float zv = zs[g][k];
    const float4 w = *(const float4*)(W1 + k * 64 + f0);
    a0 = fmaf(zv, w.x, a0); a1 = fmaf(zv, w.y, a1);
    a2 = fmaf(zv, w.z, a2); a3 = fmaf(zv, w.w, a3);
  }
  ys[f0 + 0][g] = relu_(a0);
  ys[f0 + 1][g] = relu_(a1);
  ys[f0 + 2][g] = relu_(a2);
  ys[f0 + 3][g] = relu_(a3);
  __syncthreads();
  float s = ys[f0 + 0][g] * W2[f0 + 0] + ys[f0 + 1][g] * W2[f0 + 1] +
            ys[f0 + 2][g] * W2[f0 + 2] + ys[f0 + 3][g] * W2[f0 + 3];
#pragma unroll
  for (int m = 1; m < 16; m <<= 1) s += __shfl_xor(s, m);
  if (j == 0) out[base + g] = s + b2[0];
}

}  // namespace

extern "C" void kernel_launch(void* const* d_in, const int* in_sizes, int n_in,
                              void* d_out, int out_size, void* d_ws, size_t ws_size,
                              hipStream_t stream) {
  const int*   names_s = (const int*)d_in[0];
  const int*   ei_s    = (const int*)d_in[1];
  const float* ea_s    = (const float*)d_in[2];
  const int*   bat_s   = (const int*)d_in[3];
  const int*   names_g = (const int*)d_in[4];
  const int*   ei_g    = (const int*)d_in[5];
  const float* ea_g    = (const float*)d_in[6];
  const int*   bat_g   = (const int*)d_in[7];
  const float* depth   = (const float*)d_in[8];
  const float* idW1 = (const float*)d_in[9],  *idb1 = (const float*)d_in[10];
  const float* idW2 = (const float*)d_in[11], *idb2 = (const float*)d_in[12];
  const float* edW1 = (const float*)d_in[13], *edb1 = (const float*)d_in[14];
  const float* edW2 = (const float*)d_in[15], *edb2 = (const float*)d_in[16];
  const float* s1W1 = (const float*)d_in[17], *s1b1 = (const float*)d_in[18];
  const float* s1W2 = (const float*)d_in[19], *s1b2 = (const float*)d_in[20];
  const float* s2W1 = (const float*)d_in[21], *s2b1 = (const float*)d_in[22];
  const float* s2W2 = (const float*)d_in[23], *s2b2 = (const float*)d_in[24];
  const float* s2LW = (const float*)d_in[25], *s2Lb = (const float*)d_in[26];
  const float* g1W1 = (const float*)d_in[27], *g1b1 = (const float*)d_in[28];
  const float* g1W2 = (const float*)d_in[29], *g1b2 = (const float*)d_in[30];
  const float* g2W1 = (const float*)d_in[31], *g2b1 = (const float*)d_in[32];
  const float* g2W2 = (const float*)d_in[33], *g2b2 = (const float*)d_in[34];
  const float* g2LW = (const float*)d_in[35], *g2Lb = (const float*)d_in[36];
  const float* rW1  = (const float*)d_in[37], *rb1  = (const float*)d_in[38];
  const float* rW2  = (const float*)d_in[39], *rb2  = (const float*)d_in[40];
  (void)in_sizes; (void)n_in; (void)out_size; (void)ws_size;

  char* ws = (char*)d_ws;
  size_t off = 0;
  auto alloc = [&](size_t bytes) -> char* {
    char* p = ws + off;
    off += (bytes + 255) & ~(size_t)255;
    return p;
  };
  float* tabs    = (float*)alloc((size_t)TAB_TOTAL * 4);
  // bufA/bufB (51.2 MB) alias the partition scratch: part[] is fully
  // consumed by partition_to_csr before node_embed writes bufA.
  char*  bigreg  = alloc((size_t)2 * NN * 64 * 4);          // 51,200,000 B
  float* bufA    = (float*)bigreg;
  float* bufB    = (float*)(bigreg + (size_t)NN * 64 * 4);
  int2*  part    = (int2*)bigreg;                           // TE*8 = 25.6 MB
  int2*  colattr = (int2*) alloc((size_t)TE * 8);           // final CSR order
  int*   ccnt    = (int*)  alloc((size_t)NC * 4);
  int*   cbase   = (int*)  alloc((size_t)NC * 4);
  int*   gcur    = (int*)  alloc((size_t)NC * 4);
  int*   rowptr  = (int*)  alloc((size_t)(2 * NN + 1) * 4);
  int*   start_s = (int*)  alloc((size_t)(NBAT + 1) * 4);
  int*   start_g = (int*)  alloc((size_t)(NBAT + 1) * 4);
  float* pool_s  = (float*)alloc((size_t)NBAT * 64 * 4);
  float* pool_g  = (float*)alloc((size_t)NBAT * 64 * 4);

  build_tables<<<1, 256, 0, stream>>>(edW1, edb1, edW2, edb2, s2LW, s2Lb, g2LW, g2Lb, tabs);

  // --- dense-write CSR build for BOTH graphs
  hipMemsetAsync(ccnt, 0, (size_t)NC * 4, stream);
  coarse_hist<<<ABLK, 256, 0, stream>>>(ei_s + NEDG, ei_g + NEDG, ccnt);
  coarse_scan<<<1, 1024, 0, stream>>>(ccnt, cbase, gcur, rowptr);
  coarse_partition<<<ABLK, 256, 0, stream>>>(ei_s, ei_s + NEDG, ea_s,
                                             ei_g, ei_g + NEDG, ea_g,
                                             gcur, part);
  partition_to_csr<<<NC, 256, 0, stream>>>(ccnt, cbase, part, tabs, rowptr, colattr);
  batch_bounds_dual<<<782, 256, 0, stream>>>(bat_s, bat_g, start_s, start_g);

  auto encoder = [&](const int* names, const int* start, const int* rp,
                     const float* c1W1, const float* c1b1, const float* c1W2, const float* c1b2,
                     const float* c2W1, const float* c2b1, const float* c2W2, const float* c2b2,
                     int enc, float* pool) {
    node_embed<<<391, 256, 0, stream>>>(names, idW1, idb1, idW2, idb2, bufA);
    conv1_agg<<<NN / 4, 256, 0, stream>>>(bufA, rp, colattr, tabs, bufB);
    node_mlp_tile<32><<<(NN + 63) / 64, 256, 0, stream>>>(bufB, c1W1, c1b1, c1W2, c1b2, bufA);
    conv2_agg<<<NN / 4, 256, 0, stream>>>(bufA, rp, colattr, tabs, enc, bufB);
    node_mlp_tile<64><<<(NN + 63) / 64, 256, 0, stream>>>(bufB, c2W1, c2b1, c2W2, c2b2, bufA);
    pool_mean<<<NBAT, 256, 0, stream>>>(bufA, start, pool);
  };

  encoder(names_s, start_s, rowptr,      s1W1, s1b1, s1W2, s1b2, s2W1, s2b1, s2W2, s2b2, 0, pool_s);
  encoder(names_g, start_g, rowptr + NN, g1W1, g1b1, g1W2, g1b2, g2W1, g2b1, g2W2, g2b2, 1, pool_g);

  regressor16<<<32, 256, 0, stream>>>(pool_s, pool_g, depth, rW1, rb1, rW2, rb2, (float*)d_out);
}

// Round 10
// 823.138 us; speedup vs baseline: 1.0643x; 1.0643x over previous
//
#include <hip/hip_runtime.h>
#include <stdint.h>

namespace {

constexpr int NN   = 100000;    // nodes per graph
constexpr int NEDG = 1600000;   // edges per graph
constexpr int TE   = 2 * NEDG;  // 3.2M edges across both graphs
constexpr int NBAT = 512;       // graphs per batch
constexpr int NSEG = 33;        // piecewise-linear segments of edge MLP (32 breakpoints)

// coarse partition: 256 dst-nodes per coarse bucket
constexpr int NC     = 782;     // ceil(2*NN / 256)
constexpr int TILE   = 4096;    // edges per partition block (16 per thread)
constexpr int ABLK   = (TE + TILE - 1) / TILE;  // 782
constexpr int ENTCAP = 5120;    // max entries per coarse bucket (mean 4096, +16 sigma)

// padded LDS strides for the conv edge tables: stride mod 32 = 4 so the
// random per-edge segment id g spreads lanes across bank offsets.
// r8 (stride 64/32): 8.2M conflict cycles; r9 (padded): 2.8M. Keep padding,
// revert the lane layout to r8's 8-lanes/edge + x2 unroll (r9's 4-lane
// layout doubled per-instruction row scatter and cost 25%).
constexpr int S1 = 36;  // conv1 (32 features)
constexpr int S2 = 68;  // conv2 (64 features)

// table layout (floats): bp[32] | d1[NSEG*32] | c1[NSEG*32] | per-enc {d2[NSEG*64], c2[NSEG*64]} x2
constexpr int TAB_BP = 0;
constexpr int TAB_D1 = 32;
constexpr int TAB_C1 = TAB_D1 + NSEG * 32;
constexpr int TAB_E2 = TAB_C1 + NSEG * 32;
constexpr int TAB_TOTAL = TAB_E2 + 4 * NSEG * 64;

__device__ __forceinline__ float relu_(float x) { return fmaxf(x, 0.0f); }

__device__ __forceinline__ float4 shfl_xor4(float4 v, int m) {
  return make_float4(__shfl_xor(v.x, m), __shfl_xor(v.y, m),
                     __shfl_xor(v.z, m), __shfl_xor(v.w, m));
}

// ---------------------------------------------------------------------------
// Precompute piecewise-linear tables for e(a) = relu(a*W1+b1)@W2+b2 and the
// folded e2(a) = e(a)@linW + linb. Exact reassociation of the reference math.
// ---------------------------------------------------------------------------
__global__ void build_tables(const float* __restrict__ eW1, const float* __restrict__ eb1,
                             const float* __restrict__ eW2, const float* __restrict__ eb2,
                             const float* __restrict__ sLW, const float* __restrict__ sLb,
                             const float* __restrict__ gLW, const float* __restrict__ gLb,
                             float* __restrict__ tabs) {
  __shared__ float traw[32];
  __shared__ float ts[32];
  __shared__ float dt[NSEG * 32];
  __shared__ float ct[NSEG * 32];
  int tid = threadIdx.x;
  if (tid < 32) {
    float w = eW1[tid], b = eb1[tid];
    traw[tid] = (w != 0.0f) ? (-b / w) : 3.0e38f;
  }
  __syncthreads();
  if (tid < 32) {  // rank sort (stable for duplicates)
    float v = traw[tid];
    int r = 0;
    for (int j = 0; j < 32; ++j) {
      float u = traw[j];
      r += (u < v) || (u == v && j < tid);
    }
    ts[r] = v;
  }
  __syncthreads();
  if (tid < 32) tabs[TAB_BP + tid] = ts[tid];
  for (int idx = tid; idx < NSEG * 32; idx += blockDim.x) {
    int s = idx >> 5, j = idx & 31;
    float a;  // representative point strictly inside segment s: (ts[s-1], ts[s]]
    if (s == 0)            a = ts[0] - 1.0f;
    else if (s == NSEG - 1) a = ts[31] + 1.0f;
    else                   a = 0.5f * ts[s - 1] + 0.5f * ts[s];
    float d = 0.0f, c = 0.0f;
    for (int i = 0; i < 32; ++i) {
      float w = eW1[i], b = eb1[i];
      if (fmaf(a, w, b) > 0.0f) {
        float w2 = eW2[i * 32 + j];
        d = fmaf(w, w2, d);
        c = fmaf(b, w2, c);
      }
    }
    c += eb2[j];
    dt[idx] = d; ct[idx] = c;
    tabs[TAB_D1 + idx] = d;
    tabs[TAB_C1 + idx] = c;
  }
  __syncthreads();
  for (int idx = tid; idx < NSEG * 64; idx += blockDim.x) {
    int s = idx >> 6, k = idx & 63;
    float ds = 0.f, cs = 0.f, dg = 0.f, cg = 0.f;
    for (int j = 0; j < 32; ++j) {
      float dv = dt[s * 32 + j], cv = ct[s * 32 + j];
      float ws = sLW[j * 64 + k], wg = gLW[j * 64 + k];
      ds = fmaf(dv, ws, ds); cs = fmaf(cv, ws, cs);
      dg = fmaf(dv, wg, dg); cg = fmaf(cv, wg, cg);
    }
    cs += sLb[k]; cg += gLb[k];
    tabs[TAB_E2 + idx]                 = ds;
    tabs[TAB_E2 + NSEG * 64 + idx]     = cs;
    tabs[TAB_E2 + 2 * NSEG * 64 + idx] = dg;
    tabs[TAB_E2 + 3 * NSEG * 64 + idx] = cg;
  }
}

// ---------------------------------------------------------------------------
// x0[n,32] = MLP2(clip((names+2)/SCALE,0,1))
// ---------------------------------------------------------------------------
__global__ __launch_bounds__(256, 2) void node_embed(
    const int* __restrict__ names,
    const float* __restrict__ W1, const float* __restrict__ b1,
    const float* __restrict__ W2, const float* __restrict__ b2,
    float* __restrict__ x0) {
  int n = blockIdx.x * 256 + threadIdx.x;
  if (n >= NN) return;
  float norm = ((float)names[n] + 2.0f) / 281474976710655.0f;
  norm = fminf(fmaxf(norm, 0.0f), 1.0f);
  float h[32];
#pragma unroll
  for (int i = 0; i < 32; ++i) h[i] = relu_(fmaf(norm, W1[i], b1[i]));
  float4* out = (float4*)(x0 + (size_t)n * 32);
  for (int j0 = 0; j0 < 32; j0 += 4) {
    float a0 = b2[j0], a1 = b2[j0 + 1], a2 = b2[j0 + 2], a3 = b2[j0 + 3];
#pragma unroll
    for (int i = 0; i < 32; ++i) {
      float hv = h[i];
      a0 = fmaf(hv, W2[i * 32 + j0],     a0);
      a1 = fmaf(hv, W2[i * 32 + j0 + 1], a1);
      a2 = fmaf(hv, W2[i * 32 + j0 + 2], a2);
      a3 = fmaf(hv, W2[i * 32 + j0 + 3], a3);
    }
    out[j0 >> 2] = make_float4(a0, a1, a2, a3);
  }
}

// ---------------------------------------------------------------------------
// CSR build, dense-write edition (round 8: WRITE amp 7x -> ~2x, fixed).
// ---------------------------------------------------------------------------
__global__ __launch_bounds__(256) void coarse_hist(
    const int* __restrict__ dst_s, const int* __restrict__ dst_g,
    int* __restrict__ ccnt) {
  __shared__ int h[NC];
  for (int i = threadIdx.x; i < NC; i += 256) h[i] = 0;
  __syncthreads();
  int base = blockIdx.x * TILE;
#pragma unroll
  for (int j = 0; j < 16; ++j) {
    int i = base + j * 256 + threadIdx.x;
    if (i < TE) {
      int d = (i < NEDG) ? dst_s[i] : (dst_g[i - NEDG] + NN);
      atomicAdd(&h[d >> 8], 1);
    }
  }
  __syncthreads();
  for (int i = threadIdx.x; i < NC; i += 256)
    if (h[i]) atomicAdd(&ccnt[i], h[i]);
}

__global__ __launch_bounds__(1024) void coarse_scan(
    const int* __restrict__ ccnt, int* __restrict__ cbase,
    int* __restrict__ gcur, int* __restrict__ rowptr) {
  __shared__ int s[1024];
  int t = threadIdx.x;
  int v = (t < NC) ? ccnt[t] : 0;
  s[t] = v;
  __syncthreads();
  for (int st = 1; st < 1024; st <<= 1) {
    int u = (t >= st) ? s[t - st] : 0;
    __syncthreads();
    s[t] += u;
    __syncthreads();
  }
  if (t < NC) { cbase[t] = s[t] - v; gcur[t] = s[t] - v; }
  if (t == 0) rowptr[2 * NN] = TE;
}

__global__ __launch_bounds__(256) void coarse_partition(
    const int* __restrict__ src_s, const int* __restrict__ dst_s, const float* __restrict__ attr_s,
    const int* __restrict__ src_g, const int* __restrict__ dst_g, const float* __restrict__ attr_g,
    int* __restrict__ gcur, int2* __restrict__ part) {
  __shared__ int hist[NC];      // counts, then overwritten with global base
  __shared__ int lofs[NC];
  __shared__ int lcur[NC];
  __shared__ int2 sorted[TILE]; // 32 KB
  __shared__ int addr[TILE];    // 16 KB
  __shared__ int scanbuf[256];
  int t = threadIdx.x;
  for (int i = t; i < NC; i += 256) hist[i] = 0;
  __syncthreads();
  int base = blockIdx.x * TILE;
#pragma unroll
  for (int j = 0; j < 16; ++j) {
    int i = base + j * 256 + t;
    if (i < TE) {
      int d = (i < NEDG) ? dst_s[i] : (dst_g[i - NEDG] + NN);
      atomicAdd(&hist[d >> 8], 1);
    }
  }
  __syncthreads();
  int loc[4];
  int sum = 0;
#pragma unroll
  for (int j = 0; j < 4; ++j) {
    int b = t * 4 + j;
    int v = (b < NC) ? hist[b] : 0;
    loc[j] = sum; sum += v;
  }
  scanbuf[t] = sum;
  __syncthreads();
  for (int st = 1; st < 256; st <<= 1) {
    int u = (t >= st) ? scanbuf[t - st] : 0;
    __syncthreads();
    scanbuf[t] += u;
    __syncthreads();
  }
  int texcl = scanbuf[t] - sum;
#pragma unroll
  for (int j = 0; j < 4; ++j) {
    int b = t * 4 + j;
    if (b < NC) { lofs[b] = texcl + loc[j]; lcur[b] = 0; }
  }
  __syncthreads();
  for (int b = t; b < NC; b += 256) {
    int c = hist[b];
    hist[b] = c ? atomicAdd(&gcur[b], c) : 0;
  }
  __syncthreads();
#pragma unroll
  for (int j = 0; j < 16; ++j) {
    int i = base + j * 256 + t;
    if (i < TE) {
      int sl, d; float a;
      if (i < NEDG) { sl = src_s[i]; d = dst_s[i]; a = attr_s[i]; }
      else { int k = i - NEDG; sl = src_g[k]; d = dst_g[k] + NN; a = attr_g[k]; }
      int c = d >> 8;
      int r = atomicAdd(&lcur[c], 1);
      int s = lofs[c] + r;
      sorted[s] = make_int2(sl | ((d & 255) << 17), __float_as_int(a));
      addr[s] = hist[c] + r;
    }
  }
  __syncthreads();
  int tot = (base + TILE <= TE) ? TILE : (TE - base);
  for (int s = t; s < tot; s += 256) part[addr[s]] = sorted[s];
}

__global__ __launch_bounds__(256) void partition_to_csr(
    const int* __restrict__ ccnt, const int* __restrict__ cbase,
    const int2* __restrict__ part, const float* __restrict__ tabs,
    int* __restrict__ rowptr, int2* __restrict__ colattr) {
  __shared__ int2 outE[ENTCAP];  // 40 KB
  __shared__ int hist[256];
  __shared__ int cur[256];
  __shared__ int sc[256];
  __shared__ float bp[32];
  int t = threadIdx.x, b = blockIdx.x;  // grid exact: NC
  if (t < 32) bp[t] = tabs[TAB_BP + t];
  hist[t] = 0;
  __syncthreads();
  int cnt = ccnt[b], base = cbase[b];
  for (int i = t; i < cnt; i += 256)
    atomicAdd(&hist[(part[base + i].x >> 17) & 255], 1);
  __syncthreads();
  int v = hist[t];
  sc[t] = v;
  __syncthreads();
  for (int st = 1; st < 256; st <<= 1) {
    int u = (t >= st) ? sc[t - st] : 0;
    __syncthreads();
    sc[t] += u;
    __syncthreads();
  }
  int excl = sc[t] - v;
  int gnode = b * 256 + t;
  if (gnode < 2 * NN) rowptr[gnode] = base + excl;
  cur[t] = excl;
  __syncthreads();
  for (int i = t; i < cnt; i += 256) {
    int2 e = part[base + i];
    int dl = (e.x >> 17) & 255;
    int srcn = e.x & 0x1FFFF;
    float a = __int_as_float(e.y);
    int seg = 0;
#pragma unroll
    for (int k = 0; k < 32; ++k) seg += (bp[k] < a);
    int pos = atomicAdd(&cur[dl], 1);
    outE[pos] = make_int2(srcn | (seg << 20), e.y);  // src<2^17, seg<64
  }
  __syncthreads();
  for (int i = t; i < cnt; i += 256) colattr[base + i] = outE[i];
}

// ---------------------------------------------------------------------------
// GINE aggregation, dst-major. One WAVE per node; round-8 lane layout
// (8 edge slots x 8 lanes/edge, x2 unroll = 16 gathers in flight) + the
// padded LDS stride from round 9. hb[n] = x[n] + sum_j relu(x[src_j] + e_j)
// ---------------------------------------------------------------------------
__global__ __launch_bounds__(256) void conv1_agg(
    const float* __restrict__ x0, const int* __restrict__ rowptr,
    const int2* __restrict__ colattr, const float* __restrict__ tabs,
    float* __restrict__ hb) {
  __shared__ float dt[NSEG * S1];
  __shared__ float ct[NSEG * S1];
  for (int i = threadIdx.x; i < NSEG * 32; i += 256) {
    int s = i >> 5, j = i & 31;
    dt[s * S1 + j] = tabs[TAB_D1 + i];
    ct[s * S1 + j] = tabs[TAB_C1 + i];
  }
  __syncthreads();
  int n = blockIdx.x * 4 + (threadIdx.x >> 6);  // grid exact: NN/4
  int lane = threadIdx.x & 63;
  int sub = lane & 7;        // 8 edges in flight (x2 unroll = 16)
  int f0  = (lane >> 3) * 4; // 8 float4 chunks -> 32 features
  int beg = rowptr[n], end = rowptr[n + 1];
  float4 acc = make_float4(0.f, 0.f, 0.f, 0.f);
  for (int k = beg + sub; k < end; k += 16) {
    int2 ca0 = colattr[k];
    int kb = k + 8;
    bool h1 = kb < end;
    int2 ca1 = h1 ? colattr[kb] : ca0;
    unsigned p0 = (unsigned)ca0.x, p1 = (unsigned)ca1.x;
    int s0 = (int)(p0 & 0xFFFFFu), g0 = (int)(p0 >> 20);
    int s1 = (int)(p1 & 0xFFFFFu), g1 = (int)(p1 >> 20);
    float a0 = __int_as_float(ca0.y), a1 = __int_as_float(ca1.y);
    float4 xv0 = *(const float4*)(x0 + (size_t)s0 * 32 + f0);
    float4 xv1 = *(const float4*)(x0 + (size_t)s1 * 32 + f0);
    float4 d0 = *(const float4*)&dt[g0 * S1 + f0];
    float4 c0 = *(const float4*)&ct[g0 * S1 + f0];
    float4 d1 = *(const float4*)&dt[g1 * S1 + f0];
    float4 c1 = *(const float4*)&ct[g1 * S1 + f0];
    acc.x += relu_(xv0.x + fmaf(a0, d0.x, c0.x));
    acc.y += relu_(xv0.y + fmaf(a0, d0.y, c0.y));
    acc.z += relu_(xv0.z + fmaf(a0, d0.z, c0.z));
    acc.w += relu_(xv0.w + fmaf(a0, d0.w, c0.w));
    if (h1) {
      acc.x += relu_(xv1.x + fmaf(a1, d1.x, c1.x));
      acc.y += relu_(xv1.y + fmaf(a1, d1.y, c1.y));
      acc.z += relu_(xv1.z + fmaf(a1, d1.z, c1.z));
      acc.w += relu_(xv1.w + fmaf(a1, d1.w, c1.w));
    }
  }
#pragma unroll
  for (int m = 1; m < 8; m <<= 1) {
    float4 o = shfl_xor4(acc, m);
    acc.x += o.x; acc.y += o.y; acc.z += o.z; acc.w += o.w;
  }
  if (sub == 0) {
    const float4 self = *(const float4*)(x0 + (size_t)n * 32 + f0);
    *(float4*)(hb + (size_t)n * 32 + f0) =
        make_float4(self.x + acc.x, self.y + acc.y, self.z + acc.z, self.w + acc.w);
  }
}

__global__ __launch_bounds__(256) void conv2_agg(
    const float* __restrict__ x1, const int* __restrict__ rowptr,
    const int2* __restrict__ colattr, const float* __restrict__ tabs, int enc,
    float* __restrict__ hb) {
  __shared__ float dt[NSEG * S2];
  __shared__ float ct[NSEG * S2];
  const float* d2 = tabs + TAB_E2 + (size_t)enc * 2 * NSEG * 64;
  for (int i = threadIdx.x; i < NSEG * 64; i += 256) {
    int s = i >> 6, j = i & 63;
    dt[s * S2 + j] = d2[i];
    ct[s * S2 + j] = d2[NSEG * 64 + i];
  }
  __syncthreads();
  int n = blockIdx.x * 4 + (threadIdx.x >> 6);  // grid exact: NN/4
  int lane = threadIdx.x & 63;
  int sub = lane & 7;        // 8 edges in flight (x2 unroll = 16)
  int f0  = (lane >> 3) * 8; // 8 features per lane -> 64 features
  int beg = rowptr[n], end = rowptr[n + 1];
  float4 accA = make_float4(0.f, 0.f, 0.f, 0.f);
  float4 accB = make_float4(0.f, 0.f, 0.f, 0.f);
  for (int k = beg + sub; k < end; k += 16) {
    int2 ca0 = colattr[k];
    int kb = k + 8;
    bool h1 = kb < end;
    int2 ca1 = h1 ? colattr[kb] : ca0;
    unsigned p0 = (unsigned)ca0.x, p1 = (unsigned)ca1.x;
    int s0 = (int)(p0 & 0xFFFFFu), g0 = (int)(p0 >> 20);
    int s1 = (int)(p1 & 0xFFFFFu), g1 = (int)(p1 >> 20);
    float a0 = __int_as_float(ca0.y), a1 = __int_as_float(ca1.y);
    const float* r0 = x1 + (size_t)s0 * 64 + f0;
    const float* r1 = x1 + (size_t)s1 * 64 + f0;
    float4 xa0 = *(const float4*)r0;
    float4 xb0 = *(const float4*)(r0 + 4);
    float4 xa1 = *(const float4*)r1;
    float4 xb1 = *(const float4*)(r1 + 4);
    const float* dp0 = dt + g0 * S2 + f0;
    const float* cp0 = ct + g0 * S2 + f0;
    float4 da0 = *(const float4*)dp0;
    float4 db0 = *(const float4*)(dp0 + 4);
    float4 ea0 = *(const float4*)cp0;
    float4 eb0 = *(const float4*)(cp0 + 4);
    accA.x += relu_(xa0.x + fmaf(a0, da0.x, ea0.x));
    accA.y += relu_(xa0.y + fmaf(a0, da0.y, ea0.y));
    accA.z += relu_(xa0.z + fmaf(a0, da0.z, ea0.z));
    accA.w += relu_(xa0.w + fmaf(a0, da0.w, ea0.w));
    accB.x += relu_(xb0.x + fmaf(a0, db0.x, eb0.x));
    accB.y += relu_(xb0.y + fmaf(a0, db0.y, eb0.y));
    accB.z += relu_(xb0.z + fmaf(a0, db0.z, eb0.z));
    accB.w += relu_(xb0.w + fmaf(a0, db0.w, eb0.w));
    if (h1) {
      const float* dp1 = dt + g1 * S2 + f0;
      const float* cp1 = ct + g1 * S2 + f0;
      float4 da1 = *(const float4*)dp1;
      float4 db1 = *(const float4*)(dp1 + 4);
      float4 ea1 = *(const float4*)cp1;
      float4 eb1 = *(const float4*)(cp1 + 4);
      accA.x += relu_(xa1.x + fmaf(a1, da1.x, ea1.x));
      accA.y += relu_(xa1.y + fmaf(a1, da1.y, ea1.y));
      accA.z += relu_(xa1.z + fmaf(a1, da1.z, ea1.z));
      accA.w += relu_(xa1.w + fmaf(a1, da1.w, ea1.w));
      accB.x += relu_(xb1.x + fmaf(a1, db1.x, eb1.x));
      accB.y += relu_(xb1.y + fmaf(a1, db1.y, eb1.y));
      accB.z += relu_(xb1.z + fmaf(a1, db1.z, eb1.z));
      accB.w += relu_(xb1.w + fmaf(a1, db1.w, eb1.w));
    }
  }
#pragma unroll
  for (int m = 1; m < 8; m <<= 1) {
    float4 oA = shfl_xor4(accA, m);
    float4 oB = shfl_xor4(accB, m);
    accA.x += oA.x; accA.y += oA.y; accA.z += oA.z; accA.w += oA.w;
    accB.x += oB.x; accB.y += oB.y; accB.z += oB.z; accB.w += oB.w;
  }
  if (sub == 0) {
    const float* sp = x1 + (size_t)n * 64 + f0;
    const float4 sA = *(const float4*)sp;
    const float4 sB = *(const float4*)(sp + 4);
    float* op = hb + (size_t)n * 64 + f0;
    *(float4*)op       = make_float4(sA.x + accA.x, sA.y + accA.y, sA.z + accA.z, sA.w + accA.w);
    *(float4*)(op + 4) = make_float4(sB.x + accB.x, sB.y + accB.y, sB.z + accB.z, sB.w + accB.w);
  }
}

// ---------------------------------------------------------------------------
// Per-node MLP2 (IN -> 64 -> 64), relu on both layers + output (conv wrapper).
// Register-tiled VALU GEMM: 64 nodes/block, thread owns 4 nodes x 4 features.
// ---------------------------------------------------------------------------
template <int IN>
__global__ __launch_bounds__(256) void node_mlp_tile(
    const float* __restrict__ hin,
    const float* __restrict__ W1, const float* __restrict__ b1,
    const float* __restrict__ W2, const float* __restrict__ b2,
    float* __restrict__ xout) {
  __shared__ float hsT[IN][65];   // [k][node], stride 65 -> conflict-free
  __shared__ float ysT[64][65];   // [feature][node]
  int base = blockIdx.x * 64;
  int count = NN - base; if (count > 64) count = 64;
  for (int idx = threadIdx.x; idx < 64 * IN; idx += 256) {
    int node = idx / IN, k = idx - node * IN;
    float v = (node < count) ? hin[(size_t)(base + node) * IN + k] : 0.0f;
    hsT[k][node] = v;
  }
  __syncthreads();
  int nt = threadIdx.x >> 4;   // node quad [0,16)
  int jx = threadIdx.x & 15;   // feature quad [0,16)
  int n0 = nt * 4, f0 = jx * 4;
  float4 acc0, acc1, acc2, acc3;
  {
    const float4 b = *(const float4*)(b1 + f0);
    acc0 = b; acc1 = b; acc2 = b; acc3 = b;
  }
  for (int k = 0; k < IN; ++k) {
    const float4 h = *(const float4*)&hsT[k][n0];
    const float4 w = *(const float4*)(W1 + k * 64 + f0);
    acc0.x = fmaf(h.x, w.x, acc0.x); acc0.y = fmaf(h.x, w.y, acc0.y);
    acc0.z = fmaf(h.x, w.z, acc0.z); acc0.w = fmaf(h.x, w.w, acc0.w);
    acc1.x = fmaf(h.y, w.x, acc1.x); acc1.y = fmaf(h.y, w.y, acc1.y);
    acc1.z = fmaf(h.y, w.z, acc1.z); acc1.w = fmaf(h.y, w.w, acc1.w);
    acc2.x = fmaf(h.z, w.x, acc2.x); acc2.y = fmaf(h.z, w.y, acc2.y);
    acc2.z = fmaf(h.z, w.z, acc2.z); acc2.w = fmaf(h.z, w.w, acc2.w);
    acc3.x = fmaf(h.w, w.x, acc3.x); acc3.y = fmaf(h.w, w.y, acc3.y);
    acc3.z = fmaf(h.w, w.z, acc3.z); acc3.w = fmaf(h.w, w.w, acc3.w);
  }
  ysT[f0 + 0][n0 + 0] = relu_(acc0.x); ysT[f0 + 1][n0 + 0] = relu_(acc0.y);
  ysT[f0 + 2][n0 + 0] = relu_(acc0.z); ysT[f0 + 3][n0 + 0] = relu_(acc0.w);
  ysT[f0 + 0][n0 + 1] = relu_(acc1.x); ysT[f0 + 1][n0 + 1] = relu_(acc1.y);
  ysT[f0 + 2][n0 + 1] = relu_(acc1.z); ysT[f0 + 3][n0 + 1] = relu_(acc1.w);
  ysT[f0 + 0][n0 + 2] = relu_(acc2.x); ysT[f0 + 1][n0 + 2] = relu_(acc2.y);
  ysT[f0 + 2][n0 + 2] = relu_(acc2.z); ysT[f0 + 3][n0 + 2] = relu_(acc2.w);
  ysT[f0 + 0][n0 + 3] = relu_(acc3.x); ysT[f0 + 1][n0 + 3] = relu_(acc3.y);
  ysT[f0 + 2][n0 + 3] = relu_(acc3.z); ysT[f0 + 3][n0 + 3] = relu_(acc3.w);
  __syncthreads();
  {
    const float4 b = *(const float4*)(b2 + f0);
    acc0 = b; acc1 = b; acc2 = b; acc3 = b;
  }
  for (int k = 0; k < 64; ++k) {
    const float4 h = *(const float4*)&ysT[k][n0];
    const float4 w = *(const float4*)(W2 + k * 64 + f0);
    acc0.x = fmaf(h.x, w.x, acc0.x); acc0.y = fmaf(h.x, w.y, acc0.y);
    acc0.z = fmaf(h.x, w.z, acc0.z); acc0.w = fmaf(h.x, w.w, acc0.w);
    acc1.x = fmaf(h.y, w.x, acc1.x); acc1.y = fmaf(h.y, w.y, acc1.y);
    acc1.z = fmaf(h.y, w.z, acc1.z); acc1.w = fmaf(h.y, w.w, acc1.w);
    acc2.x = fmaf(h.z, w.x, acc2.x); acc2.y = fmaf(h.z, w.y, acc2.y);
    acc2.z = fmaf(h.z, w.z, acc2.z); acc2.w = fmaf(h.z, w.w, acc2.w);
    acc3.x = fmaf(h.w, w.x, acc3.x); acc3.y = fmaf(h.w, w.y, acc3.y);
    acc3.z = fmaf(h.w, w.z, acc3.z); acc3.w = fmaf(h.w, w.w, acc3.w);
  }
  float4 o;
  if (0 < count - n0) {
    o = make_float4(relu_(acc0.x), relu_(acc0.y), relu_(acc0.z), relu_(acc0.w));
    *(float4*)(xout + (size_t)(base + n0 + 0) * 64 + f0) = o;
  }
  if (1 < count - n0) {
    o = make_float4(relu_(acc1.x), relu_(acc1.y), relu_(acc1.z), relu_(acc1.w));
    *(float4*)(xout + (size_t)(base + n0 + 1) * 64 + f0) = o;
  }
  if (2 < count - n0) {
    o = make_float4(relu_(acc2.x), relu_(acc2.y), relu_(acc2.z), relu_(acc2.w));
    *(float4*)(xout + (size_t)(base + n0 + 2) * 64 + f0) = o;
  }
  if (3 < count - n0) {
    o = make_float4(relu_(acc3.x), relu_(acc3.y), relu_(acc3.z), relu_(acc3.w));
    *(float4*)(xout + (size_t)(base + n0 + 3) * 64 + f0) = o;
  }
}

// ---------------------------------------------------------------------------
// Batch boundaries from the SORTED batch array (no atomics).
// ---------------------------------------------------------------------------
__global__ __launch_bounds__(256) void batch_bounds_dual(
    const int* __restrict__ bat_s, const int* __restrict__ bat_g,
    int* __restrict__ start_s, int* __restrict__ start_g) {
  int half = blockIdx.x >= 391;
  const int* bat = half ? bat_g : bat_s;
  int* start = half ? start_g : start_s;
  int i = (blockIdx.x - half * 391) * 256 + threadIdx.x;
  if (i >= NN) return;
  int cur = bat[i];
  int prev = (i == 0) ? -1 : bat[i - 1];
  for (int b = prev + 1; b <= cur; ++b) start[b] = i;
  if (i == NN - 1) {
    for (int b = cur + 1; b <= NBAT; ++b) start[b] = NN;
  }
}

__global__ __launch_bounds__(256) void pool_mean(
    const float* __restrict__ x2, const int* __restrict__ start, float* __restrict__ pool) {
  __shared__ float s[4][64];
  int g = blockIdx.x;
  int f = threadIdx.x & 63, c = threadIdx.x >> 6;
  int beg = start[g], end = start[g + 1];
  float acc = 0.0f;
  for (int n = beg + c; n < end; n += 4) acc += x2[(size_t)n * 64 + f];
  s[c][f] = acc;
  __syncthreads();
  if (c == 0) {
    float tot = s[0][f] + s[1][f] + s[2][f] + s[3][f];
    float m = (float)(end - beg);
    pool[g * 64 + f] = tot / fmaxf(m, 1.0f);
  }
}

// ---------------------------------------------------------------------------
// regressor: out[b] = relu([s|g|depth] @ rW1 + rb1) @ rW2 + rb2
// ---------------------------------------------------------------------------
__global__ __launch_bounds__(256) void regressor16(
    const float* __restrict__ ps, const float* __restrict__ pg, const float* __restrict__ depth,
    const float* __restrict__ W1, const float* __restrict__ b1,
    const float* __restrict__ W2, const float* __restrict__ b2,
    float* __restrict__ out) {
  __shared__ float zs[16][132];   // [row][k], k in [0,129)
  __shared__ float ys[64][17];
  int base = blockIdx.x * 16;     // grid 32 blocks x 16 rows = 512 exact
  for (int i = threadIdx.x; i < 16 * 64; i += 256) {
    int ln = i >> 6, k = i & 63;
    zs[ln][k]      = ps[(size_t)(base + ln) * 64 + k];
    zs[ln][64 + k] = pg[(size_t)(base + ln) * 64 + k];
  }
  if (threadIdx.x < 16) zs[threadIdx.x][128] = depth[base + threadIdx.x];
  __syncthreads();
  int g = threadIdx.x >> 4;
  int j = threadIdx.x & 15;
  int f0 = j * 4;
  float a0, a1, a2, a3;
  {
    const float4 b = *(const float4*)(b1 + f0);
    a0 = b.x; a1 = b.y; a2 = b.z; a3 = b.w;
  }
  for (int k = 0; k < 129; ++k) {
    float zv = zs[g][k];
    const float4 w = *(const float4*)(W1 + k * 64 + f0);
    a0 = fmaf(zv, w.x, a0); a1 = fmaf(zv, w.y, a1);
    a2 = fmaf(zv, w.z, a2); a3 = fmaf(zv, w.w, a3);
  }
  ys[f0 + 0][g] = relu_(a0);
  ys[f0 + 1][g] = relu_(a1);
  ys[f0 + 2][g] = relu_(a2);
  ys[f0 + 3][g] = relu_(a3);
  __syncthreads();
  float s = ys[f0 + 0][g] * W2[f0 + 0] + ys[f0 + 1][g] * W2[f0 + 1] +
            ys[f0 + 2][g] * W2[f0 + 2] + ys[f0 + 3][g] * W2[f0 + 3];
#pragma unroll
  for (int m = 1; m < 16; m <<= 1) s += __shfl_xor(s, m);
  if (j == 0) out[base + g] = s + b2[0];
}

}  // namespace

extern "C" void kernel_launch(void* const* d_in, const int* in_sizes, int n_in,
                              void* d_out, int out_size, void* d_ws, size_t ws_size,
                              hipStream_t stream) {
  const int*   names_s = (const int*)d_in[0];
  const int*   ei_s    = (const int*)d_in[1];
  const float* ea_s    = (const float*)d_in[2];
  const int*   bat_s   = (const int*)d_in[3];
  const int*   names_g = (const int*)d_in[4];
  const int*   ei_g    = (const int*)d_in[5];
  const float* ea_g    = (const float*)d_in[6];
  const int*   bat_g   = (const int*)d_in[7];
  const float* depth   = (const float*)d_in[8];
  const float* idW1 = (const float*)d_in[9],  *idb1 = (const float*)d_in[10];
  const float* idW2 = (const float*)d_in[11], *idb2 = (const float*)d_in[12];
  const float* edW1 = (const float*)d_in[13], *edb1 = (const float*)d_in[14];
  const float* edW2 = (const float*)d_in[15], *edb2 = (const float*)d_in[16];
  const float* s1W1 = (const float*)d_in[17], *s1b1 = (const float*)d_in[18];
  const float* s1W2 = (const float*)d_in[19], *s1b2 = (const float*)d_in[20];
  const float* s2W1 = (const float*)d_in[21], *s2b1 = (const float*)d_in[22];
  const float* s2W2 = (const float*)d_in[23], *s2b2 = (const float*)d_in[24];
  const float* s2LW = (const float*)d_in[25], *s2Lb = (const float*)d_in[26];
  const float* g1W1 = (const float*)d_in[27], *g1b1 = (const float*)d_in[28];
  const float* g1W2 = (const float*)d_in[29], *g1b2 = (const float*)d_in[30];
  const float* g2W1 = (const float*)d_in[31], *g2b1 = (const float*)d_in[32];
  const float* g2W2 = (const float*)d_in[33], *g2b2 = (const float*)d_in[34];
  const float* g2LW = (const float*)d_in[35], *g2Lb = (const float*)d_in[36];
  const float* rW1  = (const float*)d_in[37], *rb1  = (const float*)d_in[38];
  const float* rW2  = (const float*)d_in[39], *rb2  = (const float*)d_in[40];
  (void)in_sizes; (void)n_in; (void)out_size; (void)ws_size;

  char* ws = (char*)d_ws;
  size_t off = 0;
  auto alloc = [&](size_t bytes) -> char* {
    char* p = ws + off;
    off += (bytes + 255) & ~(size_t)255;
    return p;
  };
  float* tabs    = (float*)alloc((size_t)TAB_TOTAL * 4);
  // bufA/bufB (51.2 MB) alias the partition scratch: part[] is fully
  // consumed by partition_to_csr before node_embed writes bufA.
  char*  bigreg  = alloc((size_t)2 * NN * 64 * 4);          // 51,200,000 B
  float* bufA    = (float*)bigreg;
  float* bufB    = (float*)(bigreg + (size_t)NN * 64 * 4);
  int2*  part    = (int2*)bigreg;                           // TE*8 = 25.6 MB
  int2*  colattr = (int2*) alloc((size_t)TE * 8);           // final CSR order
  int*   ccnt    = (int*)  alloc((size_t)NC * 4);
  int*   cbase   = (int*)  alloc((size_t)NC * 4);
  int*   gcur    = (int*)  alloc((size_t)NC * 4);
  int*   rowptr  = (int*)  alloc((size_t)(2 * NN + 1) * 4);
  int*   start_s = (int*)  alloc((size_t)(NBAT + 1) * 4);
  int*   start_g = (int*)  alloc((size_t)(NBAT + 1) * 4);
  float* pool_s  = (float*)alloc((size_t)NBAT * 64 * 4);
  float* pool_g  = (float*)alloc((size_t)NBAT * 64 * 4);

  build_tables<<<1, 256, 0, stream>>>(edW1, edb1, edW2, edb2, s2LW, s2Lb, g2LW, g2Lb, tabs);

  // --- dense-write CSR build for BOTH graphs
  hipMemsetAsync(ccnt, 0, (size_t)NC * 4, stream);
  coarse_hist<<<ABLK, 256, 0, stream>>>(ei_s + NEDG, ei_g + NEDG, ccnt);
  coarse_scan<<<1, 1024, 0, stream>>>(ccnt, cbase, gcur, rowptr);
  coarse_partition<<<ABLK, 256, 0, stream>>>(ei_s, ei_s + NEDG, ea_s,
                                             ei_g, ei_g + NEDG, ea_g,
                                             gcur, part);
  partition_to_csr<<<NC, 256, 0, stream>>>(ccnt, cbase, part, tabs, rowptr, colattr);
  batch_bounds_dual<<<782, 256, 0, stream>>>(bat_s, bat_g, start_s, start_g);

  auto encoder = [&](const int* names, const int* start, const int* rp,
                     const float* c1W1, const float* c1b1, const float* c1W2, const float* c1b2,
                     const float* c2W1, const float* c2b1, const float* c2W2, const float* c2b2,
                     int enc, float* pool) {
    node_embed<<<391, 256, 0, stream>>>(names, idW1, idb1, idW2, idb2, bufA);
    conv1_agg<<<NN / 4, 256, 0, stream>>>(bufA, rp, colattr, tabs, bufB);
    node_mlp_tile<32><<<(NN + 63) / 64, 256, 0, stream>>>(bufB, c1W1, c1b1, c1W2, c1b2, bufA);
    conv2_agg<<<NN / 4, 256, 0, stream>>>(bufA, rp, colattr, tabs, enc, bufB);
    node_mlp_tile<64><<<(NN + 63) / 64, 256, 0, stream>>>(bufB, c2W1, c2b1, c2W2, c2b2, bufA);
    pool_mean<<<NBAT, 256, 0, stream>>>(bufA, start, pool);
  };

  encoder(names_s, start_s, rowptr,      s1W1, s1b1, s1W2, s1b2, s2W1, s2b1, s2W2, s2b2, 0, pool_s);
  encoder(names_g, start_g, rowptr + NN, g1W1, g1b1, g1W2, g1b2, g2W1, g2b1, g2W2, g2b2, 1, pool_g);

  regressor16<<<32, 256, 0, stream>>>(pool_s, pool_g, depth, rW1, rb1, rW2, rb2, (float*)d_out);
}

// Round 11
// 775.218 us; speedup vs baseline: 1.1301x; 1.0618x over previous
//
#include <hip/hip_runtime.h>
#include <stdint.h>

namespace {

constexpr int NN   = 100000;    // nodes per graph
constexpr int TN   = 2 * NN;    // nodes across both graphs
constexpr int NEDG = 1600000;   // edges per graph
constexpr int TE   = 2 * NEDG;  // 3.2M edges across both graphs
constexpr int NBAT = 512;       // graphs per batch
constexpr int NSEG = 33;        // piecewise-linear segments of edge MLP (32 breakpoints)

// coarse partition: 256 dst-nodes per coarse bucket
constexpr int NC     = 782;     // ceil(TN / 256)
constexpr int TILE   = 4096;    // edges per partition block (16 per thread)
constexpr int ABLK   = (TE + TILE - 1) / TILE;  // 782
constexpr int ENTCAP = 5120;    // max entries per coarse bucket (mean 4096, +16 sigma)

// padded LDS strides for the conv edge tables (r9: kills 8-way conflicts)
constexpr int S1 = 36;  // conv1 (32 features)
constexpr int S2 = 68;  // conv2 (64 features)

// table layout (floats): bp[32] | d1[NSEG*32] | c1[NSEG*32] | per-enc {d2[NSEG*64], c2[NSEG*64]} x2
constexpr int TAB_BP = 0;
constexpr int TAB_D1 = 32;
constexpr int TAB_C1 = TAB_D1 + NSEG * 32;
constexpr int TAB_E2 = TAB_C1 + NSEG * 32;
constexpr int TAB_TOTAL = TAB_E2 + 4 * NSEG * 64;

__device__ __forceinline__ float relu_(float x) { return fmaxf(x, 0.0f); }

__device__ __forceinline__ float4 shfl_xor4(float4 v, int m) {
  return make_float4(__shfl_xor(v.x, m), __shfl_xor(v.y, m),
                     __shfl_xor(v.z, m), __shfl_xor(v.w, m));
}

// ---------------------------------------------------------------------------
// Precompute piecewise-linear tables for e(a) = relu(a*W1+b1)@W2+b2 and the
// folded e2(a) = e(a)@linW + linb. Exact reassociation of the reference math.
// ---------------------------------------------------------------------------
__global__ void build_tables(const float* __restrict__ eW1, const float* __restrict__ eb1,
                             const float* __restrict__ eW2, const float* __restrict__ eb2,
                             const float* __restrict__ sLW, const float* __restrict__ sLb,
                             const float* __restrict__ gLW, const float* __restrict__ gLb,
                             float* __restrict__ tabs) {
  __shared__ float traw[32];
  __shared__ float ts[32];
  __shared__ float dt[NSEG * 32];
  __shared__ float ct[NSEG * 32];
  int tid = threadIdx.x;
  if (tid < 32) {
    float w = eW1[tid], b = eb1[tid];
    traw[tid] = (w != 0.0f) ? (-b / w) : 3.0e38f;
  }
  __syncthreads();
  if (tid < 32) {  // rank sort (stable for duplicates)
    float v = traw[tid];
    int r = 0;
    for (int j = 0; j < 32; ++j) {
      float u = traw[j];
      r += (u < v) || (u == v && j < tid);
    }
    ts[r] = v;
  }
  __syncthreads();
  if (tid < 32) tabs[TAB_BP + tid] = ts[tid];
  for (int idx = tid; idx < NSEG * 32; idx += blockDim.x) {
    int s = idx >> 5, j = idx & 31;
    float a;  // representative point strictly inside segment s: (ts[s-1], ts[s]]
    if (s == 0)            a = ts[0] - 1.0f;
    else if (s == NSEG - 1) a = ts[31] + 1.0f;
    else                   a = 0.5f * ts[s - 1] + 0.5f * ts[s];
    float d = 0.0f, c = 0.0f;
    for (int i = 0; i < 32; ++i) {
      float w = eW1[i], b = eb1[i];
      if (fmaf(a, w, b) > 0.0f) {
        float w2 = eW2[i * 32 + j];
        d = fmaf(w, w2, d);
        c = fmaf(b, w2, c);
      }
    }
    c += eb2[j];
    dt[idx] = d; ct[idx] = c;
    tabs[TAB_D1 + idx] = d;
    tabs[TAB_C1 + idx] = c;
  }
  __syncthreads();
  for (int idx = tid; idx < NSEG * 64; idx += blockDim.x) {
    int s = idx >> 6, k = idx & 63;
    float ds = 0.f, cs = 0.f, dg = 0.f, cg = 0.f;
    for (int j = 0; j < 32; ++j) {
      float dv = dt[s * 32 + j], cv = ct[s * 32 + j];
      float ws = sLW[j * 64 + k], wg = gLW[j * 64 + k];
      ds = fmaf(dv, ws, ds); cs = fmaf(cv, ws, cs);
      dg = fmaf(dv, wg, dg); cg = fmaf(cv, wg, cg);
    }
    cs += sLb[k]; cg += gLb[k];
    tabs[TAB_E2 + idx]                 = ds;
    tabs[TAB_E2 + NSEG * 64 + idx]     = cs;
    tabs[TAB_E2 + 2 * NSEG * 64 + idx] = dg;
    tabs[TAB_E2 + 3 * NSEG * 64 + idx] = cg;
  }
}

// ---------------------------------------------------------------------------
// x0[n,32] for BOTH graphs in one launch (graph g rows offset by NN)
// ---------------------------------------------------------------------------
__global__ __launch_bounds__(256, 2) void node_embed_dual(
    const int* __restrict__ names_s, const int* __restrict__ names_g,
    const float* __restrict__ W1, const float* __restrict__ b1,
    const float* __restrict__ W2, const float* __restrict__ b2,
    float* __restrict__ x0) {
  int n = blockIdx.x * 256 + threadIdx.x;
  if (n >= TN) return;
  int name = (n < NN) ? names_s[n] : names_g[n - NN];
  float norm = ((float)name + 2.0f) / 281474976710655.0f;
  norm = fminf(fmaxf(norm, 0.0f), 1.0f);
  float h[32];
#pragma unroll
  for (int i = 0; i < 32; ++i) h[i] = relu_(fmaf(norm, W1[i], b1[i]));
  float4* out = (float4*)(x0 + (size_t)n * 32);
  for (int j0 = 0; j0 < 32; j0 += 4) {
    float a0 = b2[j0], a1 = b2[j0 + 1], a2 = b2[j0 + 2], a3 = b2[j0 + 3];
#pragma unroll
    for (int i = 0; i < 32; ++i) {
      float hv = h[i];
      a0 = fmaf(hv, W2[i * 32 + j0],     a0);
      a1 = fmaf(hv, W2[i * 32 + j0 + 1], a1);
      a2 = fmaf(hv, W2[i * 32 + j0 + 2], a2);
      a3 = fmaf(hv, W2[i * 32 + j0 + 3], a3);
    }
    out[j0 >> 2] = make_float4(a0, a1, a2, a3);
  }
}

// ---------------------------------------------------------------------------
// CSR build, dense-write edition (r8: write amp 7x -> ~2x). Entry in part[]:
// src(17) | dlocal(8)<<17 | seg(6)<<25 -- seg precomputed here (r11).
// ---------------------------------------------------------------------------
__global__ __launch_bounds__(256) void coarse_hist(
    const int* __restrict__ dst_s, const int* __restrict__ dst_g,
    int* __restrict__ ccnt) {
  __shared__ int h[NC];
  for (int i = threadIdx.x; i < NC; i += 256) h[i] = 0;
  __syncthreads();
  int base = blockIdx.x * TILE;
#pragma unroll
  for (int j = 0; j < 16; ++j) {
    int i = base + j * 256 + threadIdx.x;
    if (i < TE) {
      int d = (i < NEDG) ? dst_s[i] : (dst_g[i - NEDG] + NN);
      atomicAdd(&h[d >> 8], 1);
    }
  }
  __syncthreads();
  for (int i = threadIdx.x; i < NC; i += 256)
    if (h[i]) atomicAdd(&ccnt[i], h[i]);
}

__global__ __launch_bounds__(1024) void coarse_scan(
    const int* __restrict__ ccnt, int* __restrict__ cbase,
    int* __restrict__ gcur, int* __restrict__ rowptr) {
  __shared__ int s[1024];
  int t = threadIdx.x;
  int v = (t < NC) ? ccnt[t] : 0;
  s[t] = v;
  __syncthreads();
  for (int st = 1; st < 1024; st <<= 1) {
    int u = (t >= st) ? s[t - st] : 0;
    __syncthreads();
    s[t] += u;
    __syncthreads();
  }
  if (t < NC) { cbase[t] = s[t] - v; gcur[t] = s[t] - v; }
  if (t == 0) rowptr[TN] = TE;
}

__global__ __launch_bounds__(256) void coarse_partition(
    const int* __restrict__ src_s, const int* __restrict__ dst_s, const float* __restrict__ attr_s,
    const int* __restrict__ src_g, const int* __restrict__ dst_g, const float* __restrict__ attr_g,
    const float* __restrict__ tabs, int* __restrict__ gcur, int2* __restrict__ part) {
  __shared__ int hist[NC];      // counts, then overwritten with global base
  __shared__ int lofs[NC];
  __shared__ int lcur[NC];
  __shared__ int2 sorted[TILE]; // 32 KB
  __shared__ int addr[TILE];    // 16 KB
  __shared__ int scanbuf[256];
  __shared__ float bp[32];
  int t = threadIdx.x;
  if (t < 32) bp[t] = tabs[TAB_BP + t];
  for (int i = t; i < NC; i += 256) hist[i] = 0;
  __syncthreads();
  int base = blockIdx.x * TILE;
#pragma unroll
  for (int j = 0; j < 16; ++j) {
    int i = base + j * 256 + t;
    if (i < TE) {
      int d = (i < NEDG) ? dst_s[i] : (dst_g[i - NEDG] + NN);
      atomicAdd(&hist[d >> 8], 1);
    }
  }
  __syncthreads();
  int loc[4];
  int sum = 0;
#pragma unroll
  for (int j = 0; j < 4; ++j) {
    int b = t * 4 + j;
    int v = (b < NC) ? hist[b] : 0;
    loc[j] = sum; sum += v;
  }
  scanbuf[t] = sum;
  __syncthreads();
  for (int st = 1; st < 256; st <<= 1) {
    int u = (t >= st) ? scanbuf[t - st] : 0;
    __syncthreads();
    scanbuf[t] += u;
    __syncthreads();
  }
  int texcl = scanbuf[t] - sum;
#pragma unroll
  for (int j = 0; j < 4; ++j) {
    int b = t * 4 + j;
    if (b < NC) { lofs[b] = texcl + loc[j]; lcur[b] = 0; }
  }
  __syncthreads();
  for (int b = t; b < NC; b += 256) {
    int c = hist[b];
    hist[b] = c ? atomicAdd(&gcur[b], c) : 0;
  }
  __syncthreads();
#pragma unroll
  for (int j = 0; j < 16; ++j) {
    int i = base + j * 256 + t;
    if (i < TE) {
      int sl, d; float a;
      if (i < NEDG) { sl = src_s[i]; d = dst_s[i]; a = attr_s[i]; }
      else { int k = i - NEDG; sl = src_g[k]; d = dst_g[k] + NN; a = attr_g[k]; }
      int seg = 0;
#pragma unroll
      for (int q = 0; q < 32; ++q) seg += (bp[q] < a);
      int c = d >> 8;
      int r = atomicAdd(&lcur[c], 1);
      int s = lofs[c] + r;
      sorted[s] = make_int2(sl | ((d & 255) << 17) | (seg << 25), __float_as_int(a));
      addr[s] = hist[c] + r;
    }
  }
  __syncthreads();
  int tot = (base + TILE <= TE) ? TILE : (TE - base);
  for (int s = t; s < tot; s += 256) part[addr[s]] = sorted[s];
}

__global__ __launch_bounds__(256) void partition_to_csr(
    const int* __restrict__ ccnt, const int* __restrict__ cbase,
    const int2* __restrict__ part,
    int* __restrict__ rowptr, int2* __restrict__ colattr) {
  __shared__ int2 outE[ENTCAP];  // 40 KB
  __shared__ int hist[256];
  __shared__ int cur[256];
  __shared__ int sc[256];
  int t = threadIdx.x, b = blockIdx.x;  // grid exact: NC
  hist[t] = 0;
  __syncthreads();
  int cnt = ccnt[b], base = cbase[b];
  for (int i = t; i < cnt; i += 256)
    atomicAdd(&hist[(part[base + i].x >> 17) & 255], 1);
  __syncthreads();
  int v = hist[t];
  sc[t] = v;
  __syncthreads();
  for (int st = 1; st < 256; st <<= 1) {
    int u = (t >= st) ? sc[t - st] : 0;
    __syncthreads();
    sc[t] += u;
    __syncthreads();
  }
  int excl = sc[t] - v;
  int gnode = b * 256 + t;
  if (gnode < TN) rowptr[gnode] = base + excl;
  cur[t] = excl;
  __syncthreads();
  for (int i = t; i < cnt; i += 256) {
    int2 e = part[base + i];
    int dl = (e.x >> 17) & 255;
    int srcn = e.x & 0x1FFFF;
    int seg = (e.x >> 25) & 63;
    int pos = atomicAdd(&cur[dl], 1);
    outE[pos] = make_int2(srcn | (seg << 20), e.y);  // conv format: src<2^17, seg<64
  }
  __syncthreads();
  for (int i = t; i < cnt; i += 256) colattr[base + i] = outE[i];
}

// ---------------------------------------------------------------------------
// GINE aggregation over BOTH graphs, dst-major. r8 lane layout (8 edges x 8
// lanes, x2 unroll = 16 gathers in flight) + padded LDS tables (r9).
// ---------------------------------------------------------------------------
__global__ __launch_bounds__(256) void conv1_dual(
    const float* __restrict__ x0, const int* __restrict__ rowptr,
    const int2* __restrict__ colattr, const float* __restrict__ tabs,
    float* __restrict__ hb) {
  __shared__ float dt[NSEG * S1];
  __shared__ float ct[NSEG * S1];
  for (int i = threadIdx.x; i < NSEG * 32; i += 256) {
    int s = i >> 5, j = i & 31;
    dt[s * S1 + j] = tabs[TAB_D1 + i];
    ct[s * S1 + j] = tabs[TAB_C1 + i];
  }
  __syncthreads();
  int n = blockIdx.x * 4 + (threadIdx.x >> 6);  // grid exact: TN/4
  const float* xb = x0 + (n >= NN ? (size_t)NN * 32 : 0);  // src ids graph-local
  int lane = threadIdx.x & 63;
  int sub = lane & 7;        // 8 edges in flight (x2 unroll = 16)
  int f0  = (lane >> 3) * 4; // 8 float4 chunks -> 32 features
  int beg = rowptr[n], end = rowptr[n + 1];
  float4 acc = make_float4(0.f, 0.f, 0.f, 0.f);
  for (int k = beg + sub; k < end; k += 16) {
    int2 ca0 = colattr[k];
    int kb = k + 8;
    bool h1 = kb < end;
    int2 ca1 = h1 ? colattr[kb] : ca0;
    unsigned p0 = (unsigned)ca0.x, p1 = (unsigned)ca1.x;
    int s0 = (int)(p0 & 0xFFFFFu), g0 = (int)(p0 >> 20);
    int s1 = (int)(p1 & 0xFFFFFu), g1 = (int)(p1 >> 20);
    float a0 = __int_as_float(ca0.y), a1 = __int_as_float(ca1.y);
    float4 xv0 = *(const float4*)(xb + (size_t)s0 * 32 + f0);
    float4 xv1 = *(const float4*)(xb + (size_t)s1 * 32 + f0);
    float4 d0 = *(const float4*)&dt[g0 * S1 + f0];
    float4 c0 = *(const float4*)&ct[g0 * S1 + f0];
    float4 d1 = *(const float4*)&dt[g1 * S1 + f0];
    float4 c1 = *(const float4*)&ct[g1 * S1 + f0];
    acc.x += relu_(xv0.x + fmaf(a0, d0.x, c0.x));
    acc.y += relu_(xv0.y + fmaf(a0, d0.y, c0.y));
    acc.z += relu_(xv0.z + fmaf(a0, d0.z, c0.z));
    acc.w += relu_(xv0.w + fmaf(a0, d0.w, c0.w));
    if (h1) {
      acc.x += relu_(xv1.x + fmaf(a1, d1.x, c1.x));
      acc.y += relu_(xv1.y + fmaf(a1, d1.y, c1.y));
      acc.z += relu_(xv1.z + fmaf(a1, d1.z, c1.z));
      acc.w += relu_(xv1.w + fmaf(a1, d1.w, c1.w));
    }
  }
#pragma unroll
  for (int m = 1; m < 8; m <<= 1) {
    float4 o = shfl_xor4(acc, m);
    acc.x += o.x; acc.y += o.y; acc.z += o.z; acc.w += o.w;
  }
  if (sub == 0) {
    const float4 self = *(const float4*)(x0 + (size_t)n * 32 + f0);
    *(float4*)(hb + (size_t)n * 32 + f0) =
        make_float4(self.x + acc.x, self.y + acc.y, self.z + acc.z, self.w + acc.w);
  }
}

__global__ __launch_bounds__(256) void conv2_dual(
    const float* __restrict__ x1, const int* __restrict__ rowptr,
    const int2* __restrict__ colattr, const float* __restrict__ tabs,
    float* __restrict__ hb) {
  __shared__ float dt[NSEG * S2];
  __shared__ float ct[NSEG * S2];
  int half = blockIdx.x >= (NN / 4);   // block's 4 nodes never span (NN%4==0)
  const float* d2 = tabs + TAB_E2 + (size_t)half * 2 * NSEG * 64;
  for (int i = threadIdx.x; i < NSEG * 64; i += 256) {
    int s = i >> 6, j = i & 63;
    dt[s * S2 + j] = d2[i];
    ct[s * S2 + j] = d2[NSEG * 64 + i];
  }
  __syncthreads();
  int n = blockIdx.x * 4 + (threadIdx.x >> 6);  // grid exact: TN/4
  const float* xb = x1 + (size_t)half * NN * 64;  // src ids graph-local
  int lane = threadIdx.x & 63;
  int sub = lane & 7;        // 8 edges in flight (x2 unroll = 16)
  int f0  = (lane >> 3) * 8; // 8 features per lane -> 64 features
  int beg = rowptr[n], end = rowptr[n + 1];
  float4 accA = make_float4(0.f, 0.f, 0.f, 0.f);
  float4 accB = make_float4(0.f, 0.f, 0.f, 0.f);
  for (int k = beg + sub; k < end; k += 16) {
    int2 ca0 = colattr[k];
    int kb = k + 8;
    bool h1 = kb < end;
    int2 ca1 = h1 ? colattr[kb] : ca0;
    unsigned p0 = (unsigned)ca0.x, p1 = (unsigned)ca1.x;
    int s0 = (int)(p0 & 0xFFFFFu), g0 = (int)(p0 >> 20);
    int s1 = (int)(p1 & 0xFFFFFu), g1 = (int)(p1 >> 20);
    float a0 = __int_as_float(ca0.y), a1 = __int_as_float(ca1.y);
    const float* r0 = xb + (size_t)s0 * 64 + f0;
    const float* r1 = xb + (size_t)s1 * 64 + f0;
    float4 xa0 = *(const float4*)r0;
    float4 xb0 = *(const float4*)(r0 + 4);
    float4 xa1 = *(const float4*)r1;
    float4 xb1 = *(const float4*)(r1 + 4);
    const float* dp0 = dt + g0 * S2 + f0;
    const float* cp0 = ct + g0 * S2 + f0;
    float4 da0 = *(const float4*)dp0;
    float4 db0 = *(const float4*)(dp0 + 4);
    float4 ea0 = *(const float4*)cp0;
    float4 eb0 = *(const float4*)(cp0 + 4);
    accA.x += relu_(xa0.x + fmaf(a0, da0.x, ea0.x));
    accA.y += relu_(xa0.y + fmaf(a0, da0.y, ea0.y));
    accA.z += relu_(xa0.z + fmaf(a0, da0.z, ea0.z));
    accA.w += relu_(xa0.w + fmaf(a0, da0.w, ea0.w));
    accB.x += relu_(xb0.x + fmaf(a0, db0.x, eb0.x));
    accB.y += relu_(xb0.y + fmaf(a0, db0.y, eb0.y));
    accB.z += relu_(xb0.z + fmaf(a0, db0.z, eb0.z));
    accB.w += relu_(xb0.w + fmaf(a0, db0.w, eb0.w));
    if (h1) {
      const float* dp1 = dt + g1 * S2 + f0;
      const float* cp1 = ct + g1 * S2 + f0;
      float4 da1 = *(const float4*)dp1;
      float4 db1 = *(const float4*)(dp1 + 4);
      float4 ea1 = *(const float4*)cp1;
      float4 eb1 = *(const float4*)(cp1 + 4);
      accA.x += relu_(xa1.x + fmaf(a1, da1.x, ea1.x));
      accA.y += relu_(xa1.y + fmaf(a1, da1.y, ea1.y));
      accA.z += relu_(xa1.z + fmaf(a1, da1.z, ea1.z));
      accA.w += relu_(xa1.w + fmaf(a1, da1.w, ea1.w));
      accB.x += relu_(xb1.x + fmaf(a1, db1.x, eb1.x));
      accB.y += relu_(xb1.y + fmaf(a1, db1.y, eb1.y));
      accB.z += relu_(xb1.z + fmaf(a1, db1.z, eb1.z));
      accB.w += relu_(xb1.w + fmaf(a1, db1.w, eb1.w));
    }
  }
#pragma unroll
  for (int m = 1; m < 8; m <<= 1) {
    float4 oA = shfl_xor4(accA, m);
    float4 oB = shfl_xor4(accB, m);
    accA.x += oA.x; accA.y += oA.y; accA.z += oA.z; accA.w += oA.w;
    accB.x += oB.x; accB.y += oB.y; accB.z += oB.z; accB.w += oB.w;
  }
  if (sub == 0) {
    const float* sp = x1 + (size_t)n * 64 + f0;
    const float4 sA = *(const float4*)sp;
    const float4 sB = *(const float4*)(sp + 4);
    float* op = hb + (size_t)n * 64 + f0;
    *(float4*)op       = make_float4(sA.x + accA.x, sA.y + accA.y, sA.z + accA.z, sA.w + accA.w);
    *(float4*)(op + 4) = make_float4(sB.x + accB.x, sB.y + accB.y, sB.z + accB.z, sB.w + accB.w);
  }
}

// ---------------------------------------------------------------------------
// Per-node MLP2 (IN -> 64 -> 64) over BOTH graphs; per-node-quad weight
// selection (a quad never spans the graph boundary since NN % 4 == 0).
// Register-tiled VALU GEMM: 64 nodes/block, thread owns 4 nodes x 4 features.
// ---------------------------------------------------------------------------
template <int IN>
__global__ __launch_bounds__(256) void mlp_dual(
    const float* __restrict__ hin,
    const float* __restrict__ sW1, const float* __restrict__ sb1,
    const float* __restrict__ sW2, const float* __restrict__ sb2,
    const float* __restrict__ gW1, const float* __restrict__ gb1,
    const float* __restrict__ gW2, const float* __restrict__ gb2,
    float* __restrict__ xout) {
  __shared__ float hsT[IN][65];   // [k][node], stride 65 -> conflict-free
  __shared__ float ysT[64][65];   // [feature][node]
  int base = blockIdx.x * 64;     // grid exact: TN/64 = 3125
  for (int idx = threadIdx.x; idx < 64 * IN; idx += 256) {
    int node = idx / IN, k = idx - node * IN;
    hsT[k][node] = hin[(size_t)(base + node) * IN + k];
  }
  __syncthreads();
  int nt = threadIdx.x >> 4;   // node quad [0,16)
  int jx = threadIdx.x & 15;   // feature quad [0,16)
  int n0 = nt * 4, f0 = jx * 4;
  bool isg = (base + n0) >= NN;
  const float* W1 = isg ? gW1 : sW1;
  const float* b1 = isg ? gb1 : sb1;
  const float* W2 = isg ? gW2 : sW2;
  const float* b2 = isg ? gb2 : sb2;
  float4 acc0, acc1, acc2, acc3;
  {
    const float4 b = *(const float4*)(b1 + f0);
    acc0 = b; acc1 = b; acc2 = b; acc3 = b;
  }
  for (int k = 0; k < IN; ++k) {
    const float4 h = *(const float4*)&hsT[k][n0];
    const float4 w = *(const float4*)(W1 + k * 64 + f0);
    acc0.x = fmaf(h.x, w.x, acc0.x); acc0.y = fmaf(h.x, w.y, acc0.y);
    acc0.z = fmaf(h.x, w.z, acc0.z); acc0.w = fmaf(h.x, w.w, acc0.w);
    acc1.x = fmaf(h.y, w.x, acc1.x); acc1.y = fmaf(h.y, w.y, acc1.y);
    acc1.z = fmaf(h.y, w.z, acc1.z); acc1.w = fmaf(h.y, w.w, acc1.w);
    acc2.x = fmaf(h.z, w.x, acc2.x); acc2.y = fmaf(h.z, w.y, acc2.y);
    acc2.z = fmaf(h.z, w.z, acc2.z); acc2.w = fmaf(h.z, w.w, acc2.w);
    acc3.x = fmaf(h.w, w.x, acc3.x); acc3.y = fmaf(h.w, w.y, acc3.y);
    acc3.z = fmaf(h.w, w.z, acc3.z); acc3.w = fmaf(h.w, w.w, acc3.w);
  }
  ysT[f0 + 0][n0 + 0] = relu_(acc0.x); ysT[f0 + 1][n0 + 0] = relu_(acc0.y);
  ysT[f0 + 2][n0 + 0] = relu_(acc0.z); ysT[f0 + 3][n0 + 0] = relu_(acc0.w);
  ysT[f0 + 0][n0 + 1] = relu_(acc1.x); ysT[f0 + 1][n0 + 1] = relu_(acc1.y);
  ysT[f0 + 2][n0 + 1] = relu_(acc1.z); ysT[f0 + 3][n0 + 1] = relu_(acc1.w);
  ysT[f0 + 0][n0 + 2] = relu_(acc2.x); ysT[f0 + 1][n0 + 2] = relu_(acc2.y);
  ysT[f0 + 2][n0 + 2] = relu_(acc2.z); ysT[f0 + 3][n0 + 2] = relu_(acc2.w);
  ysT[f0 + 0][n0 + 3] = relu_(acc3.x); ysT[f0 + 1][n0 + 3] = relu_(acc3.y);
  ysT[f0 + 2][n0 + 3] = relu_(acc3.z); ysT[f0 + 3][n0 + 3] = relu_(acc3.w);
  __syncthreads();
  {
    const float4 b = *(const float4*)(b2 + f0);
    acc0 = b; acc1 = b; acc2 = b; acc3 = b;
  }
  for (int k = 0; k < 64; ++k) {
    const float4 h = *(const float4*)&ysT[k][n0];
    const float4 w = *(const float4*)(W2 + k * 64 + f0);
    acc0.x = fmaf(h.x, w.x, acc0.x); acc0.y = fmaf(h.x, w.y, acc0.y);
    acc0.z = fmaf(h.x, w.z, acc0.z); acc0.w = fmaf(h.x, w.w, acc0.w);
    acc1.x = fmaf(h.y, w.x, acc1.x); acc1.y = fmaf(h.y, w.y, acc1.y);
    acc1.z = fmaf(h.y, w.z, acc1.z); acc1.w = fmaf(h.y, w.w, acc1.w);
    acc2.x = fmaf(h.z, w.x, acc2.x); acc2.y = fmaf(h.z, w.y, acc2.y);
    acc2.z = fmaf(h.z, w.z, acc2.z); acc2.w = fmaf(h.z, w.w, acc2.w);
    acc3.x = fmaf(h.w, w.x, acc3.x); acc3.y = fmaf(h.w, w.y, acc3.y);
    acc3.z = fmaf(h.w, w.z, acc3.z); acc3.w = fmaf(h.w, w.w, acc3.w);
  }
  float4 o;
  o = make_float4(relu_(acc0.x), relu_(acc0.y), relu_(acc0.z), relu_(acc0.w));
  *(float4*)(xout + (size_t)(base + n0 + 0) * 64 + f0) = o;
  o = make_float4(relu_(acc1.x), relu_(acc1.y), relu_(acc1.z), relu_(acc1.w));
  *(float4*)(xout + (size_t)(base + n0 + 1) * 64 + f0) = o;
  o = make_float4(relu_(acc2.x), relu_(acc2.y), relu_(acc2.z), relu_(acc2.w));
  *(float4*)(xout + (size_t)(base + n0 + 2) * 64 + f0) = o;
  o = make_float4(relu_(acc3.x), relu_(acc3.y), relu_(acc3.z), relu_(acc3.w));
  *(float4*)(xout + (size_t)(base + n0 + 3) * 64 + f0) = o;
}

// ---------------------------------------------------------------------------
// Batch boundaries from the SORTED batch array (no atomics).
// ---------------------------------------------------------------------------
__global__ __launch_bounds__(256) void batch_bounds_dual(
    const int* __restrict__ bat_s, const int* __restrict__ bat_g,
    int* __restrict__ start_s, int* __restrict__ start_g) {
  int half = blockIdx.x >= 391;
  const int* bat = half ? bat_g : bat_s;
  int* start = half ? start_g : start_s;
  int i = (blockIdx.x - half * 391) * 256 + threadIdx.x;
  if (i >= NN) return;
  int cur = bat[i];
  int prev = (i == 0) ? -1 : bat[i - 1];
  for (int b = prev + 1; b <= cur; ++b) start[b] = i;
  if (i == NN - 1) {
    for (int b = cur + 1; b <= NBAT; ++b) start[b] = NN;
  }
}

__global__ __launch_bounds__(256) void pool_dual(
    const float* __restrict__ x2,
    const int* __restrict__ start_s, const int* __restrict__ start_g,
    float* __restrict__ pool_s, float* __restrict__ pool_g) {
  __shared__ float s[4][64];
  int half = blockIdx.x >= NBAT;    // grid: 2*NBAT
  int g = blockIdx.x - half * NBAT;
  const int* start = half ? start_g : start_s;
  float* pool = half ? pool_g : pool_s;
  const float* xb = x2 + (size_t)half * NN * 64;
  int f = threadIdx.x & 63, c = threadIdx.x >> 6;
  int beg = start[g], end = start[g + 1];
  float acc = 0.0f;
  for (int n = beg + c; n < end; n += 4) acc += xb[(size_t)n * 64 + f];
  s[c][f] = acc;
  __syncthreads();
  if (c == 0) {
    float tot = s[0][f] + s[1][f] + s[2][f] + s[3][f];
    float m = (float)(end - beg);
    pool[g * 64 + f] = tot / fmaxf(m, 1.0f);
  }
}

// ---------------------------------------------------------------------------
// regressor: out[b] = relu([s|g|depth] @ rW1 + rb1) @ rW2 + rb2
// ---------------------------------------------------------------------------
__global__ __launch_bounds__(256) void regressor16(
    const float* __restrict__ ps, const float* __restrict__ pg, const float* __restrict__ depth,
    const float* __restrict__ W1, const float* __restrict__ b1,
    const float* __restrict__ W2, const float* __restrict__ b2,
    float* __restrict__ out) {
  __shared__ float zs[16][132];   // [row][k], k in [0,129)
  __shared__ float ys[64][17];
  int base = blockIdx.x * 16;     // grid 32 blocks x 16 rows = 512 exact
  for (int i = threadIdx.x; i < 16 * 64; i += 256) {
    int ln = i >> 6, k = i & 63;
    zs[ln][k]      = ps[(size_t)(base + ln) * 64 + k];
    zs[ln][64 + k] = pg[(size_t)(base + ln) * 64 + k];
  }
  if (threadIdx.x < 16) zs[threadIdx.x][128] = depth[base + threadIdx.x];
  __syncthreads();
  int g = threadIdx.x >> 4;
  int j = threadIdx.x & 15;
  int f0 = j * 4;
  float a0, a1, a2, a3;
  {
    const float4 b = *(const float4*)(b1 + f0);
    a0 = b.x; a1 = b.y; a2 = b.z; a3 = b.w;
  }
  for (int k = 0; k < 129; ++k) {
    float zv = zs[g][k];
    const float4 w = *(const float4*)(W1 + k * 64 + f0);
    a0 = fmaf(zv, w.x, a0); a1 = fmaf(zv, w.y, a1);
    a2 = fmaf(zv, w.z, a2); a3 = fmaf(zv, w.w, a3);
  }
  ys[f0 + 0][g] = relu_(a0);
  ys[f0 + 1][g] = relu_(a1);
  ys[f0 + 2][g] = relu_(a2);
  ys[f0 + 3][g] = relu_(a3);
  __syncthreads();
  float s = ys[f0 + 0][g] * W2[f0 + 0] + ys[f0 + 1][g] * W2[f0 + 1] +
            ys[f0 + 2][g] * W2[f0 + 2] + ys[f0 + 3][g] * W2[f0 + 3];
#pragma unroll
  for (int m = 1; m < 16; m <<= 1) s += __shfl_xor(s, m);
  if (j == 0) out[base + g] = s + b2[0];
}

}  // namespace

extern "C" void kernel_launch(void* const* d_in, const int* in_sizes, int n_in,
                              void* d_out, int out_size, void* d_ws, size_t ws_size,
                              hipStream_t stream) {
  const int*   names_s = (const int*)d_in[0];
  const int*   ei_s    = (const int*)d_in[1];
  const float* ea_s    = (const float*)d_in[2];
  const int*   bat_s   = (const int*)d_in[3];
  const int*   names_g = (const int*)d_in[4];
  const int*   ei_g    = (const int*)d_in[5];
  const float* ea_g    = (const float*)d_in[6];
  const int*   bat_g   = (const int*)d_in[7];
  const float* depth   = (const float*)d_in[8];
  const float* idW1 = (const float*)d_in[9],  *idb1 = (const float*)d_in[10];
  const float* idW2 = (const float*)d_in[11], *idb2 = (const float*)d_in[12];
  const float* edW1 = (const float*)d_in[13], *edb1 = (const float*)d_in[14];
  const float* edW2 = (const float*)d_in[15], *edb2 = (const float*)d_in[16];
  const float* s1W1 = (const float*)d_in[17], *s1b1 = (const float*)d_in[18];
  const float* s1W2 = (const float*)d_in[19], *s1b2 = (const float*)d_in[20];
  const float* s2W1 = (const float*)d_in[21], *s2b1 = (const float*)d_in[22];
  const float* s2W2 = (const float*)d_in[23], *s2b2 = (const float*)d_in[24];
  const float* s2LW = (const float*)d_in[25], *s2Lb = (const float*)d_in[26];
  const float* g1W1 = (const float*)d_in[27], *g1b1 = (const float*)d_in[28];
  const float* g1W2 = (const float*)d_in[29], *g1b2 = (const float*)d_in[30];
  const float* g2W1 = (const float*)d_in[31], *g2b1 = (const float*)d_in[32];
  const float* g2W2 = (const float*)d_in[33], *g2b2 = (const float*)d_in[34];
  const float* g2LW = (const float*)d_in[35], *g2Lb = (const float*)d_in[36];
  const float* rW1  = (const float*)d_in[37], *rb1  = (const float*)d_in[38];
  const float* rW2  = (const float*)d_in[39], *rb2  = (const float*)d_in[40];
  (void)in_sizes; (void)n_in; (void)out_size; (void)ws_size;

  char* ws = (char*)d_ws;
  size_t off = 0;
  auto alloc = [&](size_t bytes) -> char* {
    char* p = ws + off;
    off += (bytes + 255) & ~(size_t)255;
    return p;
  };
  float* tabs    = (float*)alloc((size_t)TAB_TOTAL * 4);
  // Activation region (102.4 MB) with aliasing:
  //   part[TE] (25.6M)    aliases bytes [0, 25.6M)   -- consumed before embed
  //   x0 [TN][32] (25.6M) at bytes [0, 25.6M)
  //   h1 [TN][32] (25.6M) at bytes [25.6M, 51.2M)
  //   x1 [TN][64] (51.2M) at bytes [51.2M, 102.4M)
  //   h2 [TN][64] (51.2M) at bytes [0, 51.2M)        -- x0+h1 dead by conv2
  //   x2 [TN][64] (51.2M) at bytes [51.2M, 102.4M)   -- x1 dead by mlp2
  char*  act   = alloc((size_t)TN * 64 * 4 * 2);            // 102,400,000 B
  int2*  part  = (int2*)act;
  float* x0buf = (float*)act;
  float* h1buf = (float*)(act + (size_t)TN * 32 * 4);
  float* x1buf = (float*)(act + (size_t)TN * 64 * 4);
  float* h2buf = (float*)act;
  float* x2buf = x1buf;
  int2*  colattr = (int2*) alloc((size_t)TE * 8);           // final CSR order
  int*   ccnt    = (int*)  alloc((size_t)NC * 4);
  int*   cbase   = (int*)  alloc((size_t)NC * 4);
  int*   gcur    = (int*)  alloc((size_t)NC * 4);
  int*   rowptr  = (int*)  alloc((size_t)(TN + 1) * 4);
  int*   start_s = (int*)  alloc((size_t)(NBAT + 1) * 4);
  int*   start_g = (int*)  alloc((size_t)(NBAT + 1) * 4);
  float* pool_s  = (float*)alloc((size_t)NBAT * 64 * 4);
  float* pool_g  = (float*)alloc((size_t)NBAT * 64 * 4);

  build_tables<<<1, 256, 0, stream>>>(edW1, edb1, edW2, edb2, s2LW, s2Lb, g2LW, g2Lb, tabs);

  // --- dense-write CSR build for BOTH graphs
  hipMemsetAsync(ccnt, 0, (size_t)NC * 4, stream);
  coarse_hist<<<ABLK, 256, 0, stream>>>(ei_s + NEDG, ei_g + NEDG, ccnt);
  coarse_scan<<<1, 1024, 0, stream>>>(ccnt, cbase, gcur, rowptr);
  coarse_partition<<<ABLK, 256, 0, stream>>>(ei_s, ei_s + NEDG, ea_s,
                                             ei_g, ei_g + NEDG, ea_g,
                                             tabs, gcur, part);
  partition_to_csr<<<NC, 256, 0, stream>>>(ccnt, cbase, part, rowptr, colattr);
  batch_bounds_dual<<<782, 256, 0, stream>>>(bat_s, bat_g, start_s, start_g);

  // --- merged dual-graph encoder pipeline (one launch per stage)
  node_embed_dual<<<(TN + 255) / 256, 256, 0, stream>>>(names_s, names_g,
                                                        idW1, idb1, idW2, idb2, x0buf);
  conv1_dual<<<TN / 4, 256, 0, stream>>>(x0buf, rowptr, colattr, tabs, h1buf);
  mlp_dual<32><<<TN / 64, 256, 0, stream>>>(h1buf,
                                            s1W1, s1b1, s1W2, s1b2,
                                            g1W1, g1b1, g1W2, g1b2, x1buf);
  conv2_dual<<<TN / 4, 256, 0, stream>>>(x1buf, rowptr, colattr, tabs, h2buf);
  mlp_dual<64><<<TN / 64, 256, 0, stream>>>(h2buf,
                                            s2W1, s2b1, s2W2, s2b2,
                                            g2W1, g2b1, g2W2, g2b2, x2buf);
  pool_dual<<<2 * NBAT, 256, 0, stream>>>(x2buf, start_s, start_g, pool_s, pool_g);

  regressor16<<<32, 256, 0, stream>>>(pool_s, pool_g, depth, rW1, rb1, rW2, rb2, (float*)d_out);
}

// Round 12
// 755.723 us; speedup vs baseline: 1.1593x; 1.0258x over previous
//
#include <hip/hip_runtime.h>
#include <hip/hip_fp16.h>
#include <stdint.h>

namespace {

constexpr int NN   = 100000;    // nodes per graph
constexpr int TN   = 2 * NN;    // nodes across both graphs
constexpr int NEDG = 1600000;   // edges per graph
constexpr int TE   = 2 * NEDG;  // 3.2M edges across both graphs
constexpr int NBAT = 512;       // graphs per batch
constexpr int NSEG = 33;        // piecewise-linear segments of edge MLP (32 breakpoints)

// coarse partition: 256 dst-nodes per coarse bucket
constexpr int NC     = 782;     // ceil(TN / 256)
constexpr int TILE   = 4096;    // edges per partition block (16 per thread)
constexpr int ABLK   = (TE + TILE - 1) / TILE;  // 782
constexpr int ENTCAP = 5120;    // max entries per coarse bucket (mean 4096, +16 sigma)

// padded LDS strides for the conv edge tables (r9: kills 8-way conflicts)
constexpr int S1 = 36;  // conv1 (32 features)
constexpr int S2 = 68;  // conv2 (64 features)

// table layout (floats): bp[32] | d1[NSEG*32] | c1[NSEG*32] | per-enc {d2[NSEG*64], c2[NSEG*64]} x2
constexpr int TAB_BP = 0;
constexpr int TAB_D1 = 32;
constexpr int TAB_C1 = TAB_D1 + NSEG * 32;
constexpr int TAB_E2 = TAB_C1 + NSEG * 32;
constexpr int TAB_TOTAL = TAB_E2 + 4 * NSEG * 64;

__device__ __forceinline__ float relu_(float x) { return fmaxf(x, 0.0f); }

__device__ __forceinline__ float4 shfl_xor4(float4 v, int m) {
  return make_float4(__shfl_xor(v.x, m), __shfl_xor(v.y, m),
                     __shfl_xor(v.z, m), __shfl_xor(v.w, m));
}

__device__ __forceinline__ float2 h2f2(int u) {
  __half2 h = *reinterpret_cast<__half2*>(&u);
  return __half22float2(h);
}
__device__ __forceinline__ int f2h2(float a, float b) {
  __half2 h = __floats2half2_rn(a, b);
  return *reinterpret_cast<int*>(&h);
}

// ---------------------------------------------------------------------------
// Precompute piecewise-linear tables for e(a) = relu(a*W1+b1)@W2+b2 and the
// folded e2(a) = e(a)@linW + linb. Exact reassociation of the reference math.
// ---------------------------------------------------------------------------
__global__ void build_tables(const float* __restrict__ eW1, const float* __restrict__ eb1,
                             const float* __restrict__ eW2, const float* __restrict__ eb2,
                             const float* __restrict__ sLW, const float* __restrict__ sLb,
                             const float* __restrict__ gLW, const float* __restrict__ gLb,
                             float* __restrict__ tabs) {
  __shared__ float traw[32];
  __shared__ float ts[32];
  __shared__ float dt[NSEG * 32];
  __shared__ float ct[NSEG * 32];
  int tid = threadIdx.x;
  if (tid < 32) {
    float w = eW1[tid], b = eb1[tid];
    traw[tid] = (w != 0.0f) ? (-b / w) : 3.0e38f;
  }
  __syncthreads();
  if (tid < 32) {  // rank sort (stable for duplicates)
    float v = traw[tid];
    int r = 0;
    for (int j = 0; j < 32; ++j) {
      float u = traw[j];
      r += (u < v) || (u == v && j < tid);
    }
    ts[r] = v;
  }
  __syncthreads();
  if (tid < 32) tabs[TAB_BP + tid] = ts[tid];
  for (int idx = tid; idx < NSEG * 32; idx += blockDim.x) {
    int s = idx >> 5, j = idx & 31;
    float a;  // representative point strictly inside segment s: (ts[s-1], ts[s]]
    if (s == 0)            a = ts[0] - 1.0f;
    else if (s == NSEG - 1) a = ts[31] + 1.0f;
    else                   a = 0.5f * ts[s - 1] + 0.5f * ts[s];
    float d = 0.0f, c = 0.0f;
    for (int i = 0; i < 32; ++i) {
      float w = eW1[i], b = eb1[i];
      if (fmaf(a, w, b) > 0.0f) {
        float w2 = eW2[i * 32 + j];
        d = fmaf(w, w2, d);
        c = fmaf(b, w2, c);
      }
    }
    c += eb2[j];
    dt[idx] = d; ct[idx] = c;
    tabs[TAB_D1 + idx] = d;
    tabs[TAB_C1 + idx] = c;
  }
  __syncthreads();
  for (int idx = tid; idx < NSEG * 64; idx += blockDim.x) {
    int s = idx >> 6, k = idx & 63;
    float ds = 0.f, cs = 0.f, dg = 0.f, cg = 0.f;
    for (int j = 0; j < 32; ++j) {
      float dv = dt[s * 32 + j], cv = ct[s * 32 + j];
      float ws = sLW[j * 64 + k], wg = gLW[j * 64 + k];
      ds = fmaf(dv, ws, ds); cs = fmaf(cv, ws, cs);
      dg = fmaf(dv, wg, dg); cg = fmaf(cv, wg, cg);
    }
    cs += sLb[k]; cg += gLb[k];
    tabs[TAB_E2 + idx]                 = ds;
    tabs[TAB_E2 + NSEG * 64 + idx]     = cs;
    tabs[TAB_E2 + 2 * NSEG * 64 + idx] = dg;
    tabs[TAB_E2 + 3 * NSEG * 64 + idx] = cg;
  }
}

// ---------------------------------------------------------------------------
// x0[n,32] for BOTH graphs + fp16 shadow copy (the conv1 gather source)
// ---------------------------------------------------------------------------
__global__ __launch_bounds__(256, 2) void node_embed_dual(
    const int* __restrict__ names_s, const int* __restrict__ names_g,
    const float* __restrict__ W1, const float* __restrict__ b1,
    const float* __restrict__ W2, const float* __restrict__ b2,
    float* __restrict__ x0, __half* __restrict__ x0h) {
  int n = blockIdx.x * 256 + threadIdx.x;
  if (n >= TN) return;
  int name = (n < NN) ? names_s[n] : names_g[n - NN];
  float norm = ((float)name + 2.0f) / 281474976710655.0f;
  norm = fminf(fmaxf(norm, 0.0f), 1.0f);
  float h[32];
#pragma unroll
  for (int i = 0; i < 32; ++i) h[i] = relu_(fmaf(norm, W1[i], b1[i]));
  float4* out = (float4*)(x0 + (size_t)n * 32);
  int2* outh = (int2*)(x0h + (size_t)n * 32);
  for (int j0 = 0; j0 < 32; j0 += 4) {
    float a0 = b2[j0], a1 = b2[j0 + 1], a2 = b2[j0 + 2], a3 = b2[j0 + 3];
#pragma unroll
    for (int i = 0; i < 32; ++i) {
      float hv = h[i];
      a0 = fmaf(hv, W2[i * 32 + j0],     a0);
      a1 = fmaf(hv, W2[i * 32 + j0 + 1], a1);
      a2 = fmaf(hv, W2[i * 32 + j0 + 2], a2);
      a3 = fmaf(hv, W2[i * 32 + j0 + 3], a3);
    }
    out[j0 >> 2] = make_float4(a0, a1, a2, a3);
    outh[j0 >> 2] = make_int2(f2h2(a0, a1), f2h2(a2, a3));
  }
}

// ---------------------------------------------------------------------------
// CSR build, dense-write edition (r8). Entry in part[]:
// src(17) | dlocal(8)<<17 | seg(6)<<25 (seg precomputed here).
// ---------------------------------------------------------------------------
__global__ __launch_bounds__(256) void coarse_hist(
    const int* __restrict__ dst_s, const int* __restrict__ dst_g,
    int* __restrict__ ccnt) {
  __shared__ int h[NC];
  for (int i = threadIdx.x; i < NC; i += 256) h[i] = 0;
  __syncthreads();
  int base = blockIdx.x * TILE;
#pragma unroll
  for (int j = 0; j < 16; ++j) {
    int i = base + j * 256 + threadIdx.x;
    if (i < TE) {
      int d = (i < NEDG) ? dst_s[i] : (dst_g[i - NEDG] + NN);
      atomicAdd(&h[d >> 8], 1);
    }
  }
  __syncthreads();
  for (int i = threadIdx.x; i < NC; i += 256)
    if (h[i]) atomicAdd(&ccnt[i], h[i]);
}

__global__ __launch_bounds__(1024) void coarse_scan(
    const int* __restrict__ ccnt, int* __restrict__ cbase,
    int* __restrict__ gcur, int* __restrict__ rowptr) {
  __shared__ int s[1024];
  int t = threadIdx.x;
  int v = (t < NC) ? ccnt[t] : 0;
  s[t] = v;
  __syncthreads();
  for (int st = 1; st < 1024; st <<= 1) {
    int u = (t >= st) ? s[t - st] : 0;
    __syncthreads();
    s[t] += u;
    __syncthreads();
  }
  if (t < NC) { cbase[t] = s[t] - v; gcur[t] = s[t] - v; }
  if (t == 0) rowptr[TN] = TE;
}

__global__ __launch_bounds__(256) void coarse_partition(
    const int* __restrict__ src_s, const int* __restrict__ dst_s, const float* __restrict__ attr_s,
    const int* __restrict__ src_g, const int* __restrict__ dst_g, const float* __restrict__ attr_g,
    const float* __restrict__ tabs, int* __restrict__ gcur, int2* __restrict__ part) {
  __shared__ int hist[NC];      // counts, then overwritten with global base
  __shared__ int lofs[NC];
  __shared__ int lcur[NC];
  __shared__ int2 sorted[TILE]; // 32 KB
  __shared__ int addr[TILE];    // 16 KB
  __shared__ int scanbuf[256];
  __shared__ float bp[32];
  int t = threadIdx.x;
  if (t < 32) bp[t] = tabs[TAB_BP + t];
  for (int i = t; i < NC; i += 256) hist[i] = 0;
  __syncthreads();
  int base = blockIdx.x * TILE;
#pragma unroll
  for (int j = 0; j < 16; ++j) {
    int i = base + j * 256 + t;
    if (i < TE) {
      int d = (i < NEDG) ? dst_s[i] : (dst_g[i - NEDG] + NN);
      atomicAdd(&hist[d >> 8], 1);
    }
  }
  __syncthreads();
  int loc[4];
  int sum = 0;
#pragma unroll
  for (int j = 0; j < 4; ++j) {
    int b = t * 4 + j;
    int v = (b < NC) ? hist[b] : 0;
    loc[j] = sum; sum += v;
  }
  scanbuf[t] = sum;
  __syncthreads();
  for (int st = 1; st < 256; st <<= 1) {
    int u = (t >= st) ? scanbuf[t - st] : 0;
    __syncthreads();
    scanbuf[t] += u;
    __syncthreads();
  }
  int texcl = scanbuf[t] - sum;
#pragma unroll
  for (int j = 0; j < 4; ++j) {
    int b = t * 4 + j;
    if (b < NC) { lofs[b] = texcl + loc[j]; lcur[b] = 0; }
  }
  __syncthreads();
  for (int b = t; b < NC; b += 256) {
    int c = hist[b];
    hist[b] = c ? atomicAdd(&gcur[b], c) : 0;
  }
  __syncthreads();
#pragma unroll
  for (int j = 0; j < 16; ++j) {
    int i = base + j * 256 + t;
    if (i < TE) {
      int sl, d; float a;
      if (i < NEDG) { sl = src_s[i]; d = dst_s[i]; a = attr_s[i]; }
      else { int k = i - NEDG; sl = src_g[k]; d = dst_g[k] + NN; a = attr_g[k]; }
      int seg = 0;
#pragma unroll
      for (int q = 0; q < 32; ++q) seg += (bp[q] < a);
      int c = d >> 8;
      int r = atomicAdd(&lcur[c], 1);
      int s = lofs[c] + r;
      sorted[s] = make_int2(sl | ((d & 255) << 17) | (seg << 25), __float_as_int(a));
      addr[s] = hist[c] + r;
    }
  }
  __syncthreads();
  int tot = (base + TILE <= TE) ? TILE : (TE - base);
  for (int s = t; s < tot; s += 256) part[addr[s]] = sorted[s];
}

__global__ __launch_bounds__(256) void partition_to_csr(
    const int* __restrict__ ccnt, const int* __restrict__ cbase,
    const int2* __restrict__ part,
    int* __restrict__ rowptr, int2* __restrict__ colattr) {
  __shared__ int2 outE[ENTCAP];  // 40 KB
  __shared__ int hist[256];
  __shared__ int cur[256];
  __shared__ int sc[256];
  int t = threadIdx.x, b = blockIdx.x;  // grid exact: NC
  hist[t] = 0;
  __syncthreads();
  int cnt = ccnt[b], base = cbase[b];
  for (int i = t; i < cnt; i += 256)
    atomicAdd(&hist[(part[base + i].x >> 17) & 255], 1);
  __syncthreads();
  int v = hist[t];
  sc[t] = v;
  __syncthreads();
  for (int st = 1; st < 256; st <<= 1) {
    int u = (t >= st) ? sc[t - st] : 0;
    __syncthreads();
    sc[t] += u;
    __syncthreads();
  }
  int excl = sc[t] - v;
  int gnode = b * 256 + t;
  if (gnode < TN) rowptr[gnode] = base + excl;
  cur[t] = excl;
  __syncthreads();
  for (int i = t; i < cnt; i += 256) {
    int2 e = part[base + i];
    int dl = (e.x >> 17) & 255;
    int srcn = e.x & 0x1FFFF;
    int seg = (e.x >> 25) & 63;
    int pos = atomicAdd(&cur[dl], 1);
    outE[pos] = make_int2(srcn | (seg << 20), e.y);  // conv format: src<2^17, seg<64
  }
  __syncthreads();
  for (int i = t; i < cnt; i += 256) colattr[base + i] = outE[i];
}

// ---------------------------------------------------------------------------
// GINE aggregation over BOTH graphs, dst-major. Gather source is the fp16
// shadow (halves FETCH: conv row 256B->128B); self term + accumulate in fp32.
// r8 lane layout (8 edges x 8 lanes, x2 unroll), padded LDS edge tables (r9).
// ---------------------------------------------------------------------------
__global__ __launch_bounds__(256) void conv1_dual(
    const float* __restrict__ x0, const __half* __restrict__ x0h,
    const int* __restrict__ rowptr, const int2* __restrict__ colattr,
    const float* __restrict__ tabs, float* __restrict__ hb) {
  __shared__ float dt[NSEG * S1];
  __shared__ float ct[NSEG * S1];
  for (int i = threadIdx.x; i < NSEG * 32; i += 256) {
    int s = i >> 5, j = i & 31;
    dt[s * S1 + j] = tabs[TAB_D1 + i];
    ct[s * S1 + j] = tabs[TAB_C1 + i];
  }
  __syncthreads();
  int n = blockIdx.x * 4 + (threadIdx.x >> 6);  // grid exact: TN/4
  const __half* xb = x0h + (n >= NN ? (size_t)NN * 32 : 0);  // src ids graph-local
  int lane = threadIdx.x & 63;
  int sub = lane & 7;        // 8 edges in flight (x2 unroll = 16)
  int f0  = (lane >> 3) * 4; // 8 quads -> 32 features
  int beg = rowptr[n], end = rowptr[n + 1];
  float4 acc = make_float4(0.f, 0.f, 0.f, 0.f);
  for (int k = beg + sub; k < end; k += 16) {
    int2 ca0 = colattr[k];
    int kb = k + 8;
    bool h1 = kb < end;
    int2 ca1 = h1 ? colattr[kb] : ca0;
    unsigned p0 = (unsigned)ca0.x, p1 = (unsigned)ca1.x;
    int s0 = (int)(p0 & 0xFFFFFu), g0 = (int)(p0 >> 20);
    int s1 = (int)(p1 & 0xFFFFFu), g1 = (int)(p1 >> 20);
    float a0 = __int_as_float(ca0.y), a1 = __int_as_float(ca1.y);
    int2 hv0 = *(const int2*)(xb + (size_t)s0 * 32 + f0);
    int2 hv1 = *(const int2*)(xb + (size_t)s1 * 32 + f0);
    float2 x00 = h2f2(hv0.x), x01 = h2f2(hv0.y);
    float2 x10 = h2f2(hv1.x), x11 = h2f2(hv1.y);
    float4 d0 = *(const float4*)&dt[g0 * S1 + f0];
    float4 c0 = *(const float4*)&ct[g0 * S1 + f0];
    float4 d1 = *(const float4*)&dt[g1 * S1 + f0];
    float4 c1 = *(const float4*)&ct[g1 * S1 + f0];
    acc.x += relu_(x00.x + fmaf(a0, d0.x, c0.x));
    acc.y += relu_(x00.y + fmaf(a0, d0.y, c0.y));
    acc.z += relu_(x01.x + fmaf(a0, d0.z, c0.z));
    acc.w += relu_(x01.y + fmaf(a0, d0.w, c0.w));
    if (h1) {
      acc.x += relu_(x10.x + fmaf(a1, d1.x, c1.x));
      acc.y += relu_(x10.y + fmaf(a1, d1.y, c1.y));
      acc.z += relu_(x11.x + fmaf(a1, d1.z, c1.z));
      acc.w += relu_(x11.y + fmaf(a1, d1.w, c1.w));
    }
  }
#pragma unroll
  for (int m = 1; m < 8; m <<= 1) {
    float4 o = shfl_xor4(acc, m);
    acc.x += o.x; acc.y += o.y; acc.z += o.z; acc.w += o.w;
  }
  if (sub == 0) {
    const float4 self = *(const float4*)(x0 + (size_t)n * 32 + f0);
    *(float4*)(hb + (size_t)n * 32 + f0) =
        make_float4(self.x + acc.x, self.y + acc.y, self.z + acc.z, self.w + acc.w);
  }
}

__global__ __launch_bounds__(256) void conv2_dual(
    const float* __restrict__ x1, const __half* __restrict__ x1h,
    const int* __restrict__ rowptr, const int2* __restrict__ colattr,
    const float* __restrict__ tabs, float* __restrict__ hb) {
  __shared__ float dt[NSEG * S2];
  __shared__ float ct[NSEG * S2];
  int half = blockIdx.x >= (NN / 4);   // block's 4 nodes never span (NN%4==0)
  const float* d2 = tabs + TAB_E2 + (size_t)half * 2 * NSEG * 64;
  for (int i = threadIdx.x; i < NSEG * 64; i += 256) {
    int s = i >> 6, j = i & 63;
    dt[s * S2 + j] = d2[i];
    ct[s * S2 + j] = d2[NSEG * 64 + i];
  }
  __syncthreads();
  int n = blockIdx.x * 4 + (threadIdx.x >> 6);  // grid exact: TN/4
  const __half* xb = x1h + (size_t)half * NN * 64;  // src ids graph-local
  int lane = threadIdx.x & 63;
  int sub = lane & 7;        // 8 edges in flight (x2 unroll = 16)
  int f0  = (lane >> 3) * 8; // 8 features per lane -> 64 features
  int beg = rowptr[n], end = rowptr[n + 1];
  float4 accA = make_float4(0.f, 0.f, 0.f, 0.f);
  float4 accB = make_float4(0.f, 0.f, 0.f, 0.f);
  for (int k = beg + sub; k < end; k += 16) {
    int2 ca0 = colattr[k];
    int kb = k + 8;
    bool h1 = kb < end;
    int2 ca1 = h1 ? colattr[kb] : ca0;
    unsigned p0 = (unsigned)ca0.x, p1 = (unsigned)ca1.x;
    int s0 = (int)(p0 & 0xFFFFFu), g0 = (int)(p0 >> 20);
    int s1 = (int)(p1 & 0xFFFFFu), g1 = (int)(p1 >> 20);
    float a0 = __int_as_float(ca0.y), a1 = __int_as_float(ca1.y);
    int4 hv0 = *(const int4*)(xb + (size_t)s0 * 64 + f0);
    int4 hv1 = *(const int4*)(xb + (size_t)s1 * 64 + f0);
    float2 xa0 = h2f2(hv0.x), xa1 = h2f2(hv0.y), xa2 = h2f2(hv0.z), xa3 = h2f2(hv0.w);
    const float* dp0 = dt + g0 * S2 + f0;
    const float* cp0 = ct + g0 * S2 + f0;
    float4 da0 = *(const float4*)dp0;
    float4 db0 = *(const float4*)(dp0 + 4);
    float4 ea0 = *(const float4*)cp0;
    float4 eb0 = *(const float4*)(cp0 + 4);
    accA.x += relu_(xa0.x + fmaf(a0, da0.x, ea0.x));
    accA.y += relu_(xa0.y + fmaf(a0, da0.y, ea0.y));
    accA.z += relu_(xa1.x + fmaf(a0, da0.z, ea0.z));
    accA.w += relu_(xa1.y + fmaf(a0, da0.w, ea0.w));
    accB.x += relu_(xa2.x + fmaf(a0, db0.x, eb0.x));
    accB.y += relu_(xa2.y + fmaf(a0, db0.y, eb0.y));
    accB.z += relu_(xa3.x + fmaf(a0, db0.z, eb0.z));
    accB.w += relu_(xa3.y + fmaf(a0, db0.w, eb0.w));
    if (h1) {
      float2 ya0 = h2f2(hv1.x), ya1 = h2f2(hv1.y), ya2 = h2f2(hv1.z), ya3 = h2f2(hv1.w);
      const float* dp1 = dt + g1 * S2 + f0;
      const float* cp1 = ct + g1 * S2 + f0;
      float4 da1 = *(const float4*)dp1;
      float4 db1 = *(const float4*)(dp1 + 4);
      float4 ea1 = *(const float4*)cp1;
      float4 eb1 = *(const float4*)(cp1 + 4);
      accA.x += relu_(ya0.x + fmaf(a1, da1.x, ea1.x));
      accA.y += relu_(ya0.y + fmaf(a1, da1.y, ea1.y));
      accA.z += relu_(ya1.x + fmaf(a1, da1.z, ea1.z));
      accA.w += relu_(ya1.y + fmaf(a1, da1.w, ea1.w));
      accB.x += relu_(ya2.x + fmaf(a1, db1.x, eb1.x));
      accB.y += relu_(ya2.y + fmaf(a1, db1.y, eb1.y));
      accB.z += relu_(ya3.x + fmaf(a1, db1.z, eb1.z));
      accB.w += relu_(ya3.y + fmaf(a1, db1.w, eb1.w));
    }
  }
#pragma unroll
  for (int m = 1; m < 8; m <<= 1) {
    float4 oA = shfl_xor4(accA, m);
    float4 oB = shfl_xor4(accB, m);
    accA.x += oA.x; accA.y += oA.y; accA.z += oA.z; accA.w += oA.w;
    accB.x += oB.x; accB.y += oB.y; accB.z += oB.z; accB.w += oB.w;
  }
  if (sub == 0) {
    const float* sp = x1 + (size_t)n * 64 + f0;
    const float4 sA = *(const float4*)sp;
    const float4 sB = *(const float4*)(sp + 4);
    float* op = hb + (size_t)n * 64 + f0;
    *(float4*)op       = make_float4(sA.x + accA.x, sA.y + accA.y, sA.z + accA.z, sA.w + accA.w);
    *(float4*)(op + 4) = make_float4(sB.x + accB.x, sB.y + accB.y, sB.z + accB.z, sB.w + accB.w);
  }
}

// ---------------------------------------------------------------------------
// Per-node MLP2 (IN -> 64 -> 64) over BOTH graphs; per-node-quad weight
// selection. Optional fp16 shadow output (hout != nullptr) for conv gathers.
// ---------------------------------------------------------------------------
template <int IN>
__global__ __launch_bounds__(256) void mlp_dual(
    const float* __restrict__ hin,
    const float* __restrict__ sW1, const float* __restrict__ sb1,
    const float* __restrict__ sW2, const float* __restrict__ sb2,
    const float* __restrict__ gW1, const float* __restrict__ gb1,
    const float* __restrict__ gW2, const float* __restrict__ gb2,
    float* __restrict__ xout, __half* __restrict__ hout) {
  __shared__ float hsT[IN][65];   // [k][node], stride 65 -> conflict-free
  __shared__ float ysT[64][65];   // [feature][node]
  int base = blockIdx.x * 64;     // grid exact: TN/64 = 3125
  for (int idx = threadIdx.x; idx < 64 * IN; idx += 256) {
    int node = idx / IN, k = idx - node * IN;
    hsT[k][node] = hin[(size_t)(base + node) * IN + k];
  }
  __syncthreads();
  int nt = threadIdx.x >> 4;   // node quad [0,16)
  int jx = threadIdx.x & 15;   // feature quad [0,16)
  int n0 = nt * 4, f0 = jx * 4;
  bool isg = (base + n0) >= NN;
  const float* W1 = isg ? gW1 : sW1;
  const float* b1 = isg ? gb1 : sb1;
  const float* W2 = isg ? gW2 : sW2;
  const float* b2 = isg ? gb2 : sb2;
  float4 acc0, acc1, acc2, acc3;
  {
    const float4 b = *(const float4*)(b1 + f0);
    acc0 = b; acc1 = b; acc2 = b; acc3 = b;
  }
  for (int k = 0; k < IN; ++k) {
    const float4 h = *(const float4*)&hsT[k][n0];
    const float4 w = *(const float4*)(W1 + k * 64 + f0);
    acc0.x = fmaf(h.x, w.x, acc0.x); acc0.y = fmaf(h.x, w.y, acc0.y);
    acc0.z = fmaf(h.x, w.z, acc0.z); acc0.w = fmaf(h.x, w.w, acc0.w);
    acc1.x = fmaf(h.y, w.x, acc1.x); acc1.y = fmaf(h.y, w.y, acc1.y);
    acc1.z = fmaf(h.y, w.z, acc1.z); acc1.w = fmaf(h.y, w.w, acc1.w);
    acc2.x = fmaf(h.z, w.x, acc2.x); acc2.y = fmaf(h.z, w.y, acc2.y);
    acc2.z = fmaf(h.z, w.z, acc2.z); acc2.w = fmaf(h.z, w.w, acc2.w);
    acc3.x = fmaf(h.w, w.x, acc3.x); acc3.y = fmaf(h.w, w.y, acc3.y);
    acc3.z = fmaf(h.w, w.z, acc3.z); acc3.w = fmaf(h.w, w.w, acc3.w);
  }
  ysT[f0 + 0][n0 + 0] = relu_(acc0.x); ysT[f0 + 1][n0 + 0] = relu_(acc0.y);
  ysT[f0 + 2][n0 + 0] = relu_(acc0.z); ysT[f0 + 3][n0 + 0] = relu_(acc0.w);
  ysT[f0 + 0][n0 + 1] = relu_(acc1.x); ysT[f0 + 1][n0 + 1] = relu_(acc1.y);
  ysT[f0 + 2][n0 + 1] = relu_(acc1.z); ysT[f0 + 3][n0 + 1] = relu_(acc1.w);
  ysT[f0 + 0][n0 + 2] = relu_(acc2.x); ysT[f0 + 1][n0 + 2] = relu_(acc2.y);
  ysT[f0 + 2][n0 + 2] = relu_(acc2.z); ysT[f0 + 3][n0 + 2] = relu_(acc2.w);
  ysT[f0 + 0][n0 + 3] = relu_(acc3.x); ysT[f0 + 1][n0 + 3] = relu_(acc3.y);
  ysT[f0 + 2][n0 + 3] = relu_(acc3.z); ysT[f0 + 3][n0 + 3] = relu_(acc3.w);
  __syncthreads();
  {
    const float4 b = *(const float4*)(b2 + f0);
    acc0 = b; acc1 = b; acc2 = b; acc3 = b;
  }
  for (int k = 0; k < 64; ++k) {
    const float4 h = *(const float4*)&ysT[k][n0];
    const float4 w = *(const float4*)(W2 + k * 64 + f0);
    acc0.x = fmaf(h.x, w.x, acc0.x); acc0.y = fmaf(h.x, w.y, acc0.y);
    acc0.z = fmaf(h.x, w.z, acc0.z); acc0.w = fmaf(h.x, w.w, acc0.w);
    acc1.x = fmaf(h.y, w.x, acc1.x); acc1.y = fmaf(h.y, w.y, acc1.y);
    acc1.z = fmaf(h.y, w.z, acc1.z); acc1.w = fmaf(h.y, w.w, acc1.w);
    acc2.x = fmaf(h.z, w.x, acc2.x); acc2.y = fmaf(h.z, w.y, acc2.y);
    acc2.z = fmaf(h.z, w.z, acc2.z); acc2.w = fmaf(h.z, w.w, acc2.w);
    acc3.x = fmaf(h.w, w.x, acc3.x); acc3.y = fmaf(h.w, w.y, acc3.y);
    acc3.z = fmaf(h.w, w.z, acc3.z); acc3.w = fmaf(h.w, w.w, acc3.w);
  }
  float4 o;
  o = make_float4(relu_(acc0.x), relu_(acc0.y), relu_(acc0.z), relu_(acc0.w));
  *(float4*)(xout + (size_t)(base + n0 + 0) * 64 + f0) = o;
  if (hout) *(int2*)(hout + (size_t)(base + n0 + 0) * 64 + f0) = make_int2(f2h2(o.x, o.y), f2h2(o.z, o.w));
  o = make_float4(relu_(acc1.x), relu_(acc1.y), relu_(acc1.z), relu_(acc1.w));
  *(float4*)(xout + (size_t)(base + n0 + 1) * 64 + f0) = o;
  if (hout) *(int2*)(hout + (size_t)(base + n0 + 1) * 64 + f0) = make_int2(f2h2(o.x, o.y), f2h2(o.z, o.w));
  o = make_float4(relu_(acc2.x), relu_(acc2.y), relu_(acc2.z), relu_(acc2.w));
  *(float4*)(xout + (size_t)(base + n0 + 2) * 64 + f0) = o;
  if (hout) *(int2*)(hout + (size_t)(base + n0 + 2) * 64 + f0) = make_int2(f2h2(o.x, o.y), f2h2(o.z, o.w));
  o = make_float4(relu_(acc3.x), relu_(acc3.y), relu_(acc3.z), relu_(acc3.w));
  *(float4*)(xout + (size_t)(base + n0 + 3) * 64 + f0) = o;
  if (hout) *(int2*)(hout + (size_t)(base + n0 + 3) * 64 + f0) = make_int2(f2h2(o.x, o.y), f2h2(o.z, o.w));
}

// ---------------------------------------------------------------------------
// Batch boundaries from the SORTED batch array (no atomics).
// ---------------------------------------------------------------------------
__global__ __launch_bounds__(256) void batch_bounds_dual(
    const int* __restrict__ bat_s, const int* __restrict__ bat_g,
    int* __restrict__ start_s, int* __restrict__ start_g) {
  int half = blockIdx.x >= 391;
  const int* bat = half ? bat_g : bat_s;
  int* start = half ? start_g : start_s;
  int i = (blockIdx.x - half * 391) * 256 + threadIdx.x;
  if (i >= NN) return;
  int cur = bat[i];
  int prev = (i == 0) ? -1 : bat[i - 1];
  for (int b = prev + 1; b <= cur; ++b) start[b] = i;
  if (i == NN - 1) {
    for (int b = cur + 1; b <= NBAT; ++b) start[b] = NN;
  }
}

__global__ __launch_bounds__(256) void pool_dual(
    const float* __restrict__ x2,
    const int* __restrict__ start_s, const int* __restrict__ start_g,
    float* __restrict__ pool_s, float* __restrict__ pool_g) {
  __shared__ float s[4][64];
  int half = blockIdx.x >= NBAT;    // grid: 2*NBAT
  int g = blockIdx.x - half * NBAT;
  const int* start = half ? start_g : start_s;
  float* pool = half ? pool_g : pool_s;
  const float* xb = x2 + (size_t)half * NN * 64;
  int f = threadIdx.x & 63, c = threadIdx.x >> 6;
  int beg = start[g], end = start[g + 1];
  float acc = 0.0f;
  for (int n = beg + c; n < end; n += 4) acc += xb[(size_t)n * 64 + f];
  s[c][f] = acc;
  __syncthreads();
  if (c == 0) {
    float tot = s[0][f] + s[1][f] + s[2][f] + s[3][f];
    float m = (float)(end - beg);
    pool[g * 64 + f] = tot / fmaxf(m, 1.0f);
  }
}

// ---------------------------------------------------------------------------
// regressor: out[b] = relu([s|g|depth] @ rW1 + rb1) @ rW2 + rb2
// ---------------------------------------------------------------------------
__global__ __launch_bounds__(256) void regressor16(
    const float* __restrict__ ps, const float* __restrict__ pg, const float* __restrict__ depth,
    const float* __restrict__ W1, const float* __restrict__ b1,
    const float* __restrict__ W2, const float* __restrict__ b2,
    float* __restrict__ out) {
  __shared__ float zs[16][132];   // [row][k], k in [0,129)
  __shared__ float ys[64][17];
  int base = blockIdx.x * 16;     // grid 32 blocks x 16 rows = 512 exact
  for (int i = threadIdx.x; i < 16 * 64; i += 256) {
    int ln = i >> 6, k = i & 63;
    zs[ln][k]      = ps[(size_t)(base + ln) * 64 + k];
    zs[ln][64 + k] = pg[(size_t)(base + ln) * 64 + k];
  }
  if (threadIdx.x < 16) zs[threadIdx.x][128] = depth[base + threadIdx.x];
  __syncthreads();
  int g = threadIdx.x >> 4;
  int j = threadIdx.x & 15;
  int f0 = j * 4;
  float a0, a1, a2, a3;
  {
    const float4 b = *(const float4*)(b1 + f0);
    a0 = b.x; a1 = b.y; a2 = b.z; a3 = b.w;
  }
  for (int k = 0; k < 129; ++k) {
    float zv = zs[g][k];
    const float4 w = *(const float4*)(W1 + k * 64 + f0);
    a0 = fmaf(zv, w.x, a0); a1 = fmaf(zv, w.y, a1);
    a2 = fmaf(zv, w.z, a2); a3 = fmaf(zv, w.w, a3);
  }
  ys[f0 + 0][g] = relu_(a0);
  ys[f0 + 1][g] = relu_(a1);
  ys[f0 + 2][g] = relu_(a2);
  ys[f0 + 3][g] = relu_(a3);
  __syncthreads();
  float s = ys[f0 + 0][g] * W2[f0 + 0] + ys[f0 + 1][g] * W2[f0 + 1] +
            ys[f0 + 2][g] * W2[f0 + 2] + ys[f0 + 3][g] * W2[f0 + 3];
#pragma unroll
  for (int m = 1; m < 16; m <<= 1) s += __shfl_xor(s, m);
  if (j == 0) out[base + g] = s + b2[0];
}

}  // namespace

extern "C" void kernel_launch(void* const* d_in, const int* in_sizes, int n_in,
                              void* d_out, int out_size, void* d_ws, size_t ws_size,
                              hipStream_t stream) {
  const int*   names_s = (const int*)d_in[0];
  const int*   ei_s    = (const int*)d_in[1];
  const float* ea_s    = (const float*)d_in[2];
  const int*   bat_s   = (const int*)d_in[3];
  const int*   names_g = (const int*)d_in[4];
  const int*   ei_g    = (const int*)d_in[5];
  const float* ea_g    = (const float*)d_in[6];
  const int*   bat_g   = (const int*)d_in[7];
  const float* depth   = (const float*)d_in[8];
  const float* idW1 = (const float*)d_in[9],  *idb1 = (const float*)d_in[10];
  const float* idW2 = (const float*)d_in[11], *idb2 = (const float*)d_in[12];
  const float* edW1 = (const float*)d_in[13], *edb1 = (const float*)d_in[14];
  const float* edW2 = (const float*)d_in[15], *edb2 = (const float*)d_in[16];
  const float* s1W1 = (const float*)d_in[17], *s1b1 = (const float*)d_in[18];
  const float* s1W2 = (const float*)d_in[19], *s1b2 = (const float*)d_in[20];
  const float* s2W1 = (const float*)d_in[21], *s2b1 = (const float*)d_in[22];
  const float* s2W2 = (const float*)d_in[23], *s2b2 = (const float*)d_in[24];
  const float* s2LW = (const float*)d_in[25], *s2Lb = (const float*)d_in[26];
  const float* g1W1 = (const float*)d_in[27], *g1b1 = (const float*)d_in[28];
  const float* g1W2 = (const float*)d_in[29], *g1b2 = (const float*)d_in[30];
  const float* g2W1 = (const float*)d_in[31], *g2b1 = (const float*)d_in[32];
  const float* g2W2 = (const float*)d_in[33], *g2b2 = (const float*)d_in[34];
  const float* g2LW = (const float*)d_in[35], *g2Lb = (const float*)d_in[36];
  const float* rW1  = (const float*)d_in[37], *rb1  = (const float*)d_in[38];
  const float* rW2  = (const float*)d_in[39], *rb2  = (const float*)d_in[40];
  (void)in_sizes; (void)n_in; (void)out_size; (void)ws_size;

  char* ws = (char*)d_ws;
  size_t off = 0;
  auto alloc = [&](size_t bytes) -> char* {
    char* p = ws + off;
    off += (bytes + 255) & ~(size_t)255;
    return p;
  };
  float* tabs    = (float*)alloc((size_t)TAB_TOTAL * 4);
  // Activation region (102.4 MB) with aliasing (part consumed before embed):
  char*  act   = alloc((size_t)TN * 64 * 4 * 2);            // 102,400,000 B
  int2*  part  = (int2*)act;
  float* x0buf = (float*)act;
  float* h1buf = (float*)(act + (size_t)TN * 32 * 4);
  float* x1buf = (float*)(act + (size_t)TN * 64 * 4);
  float* h2buf = (float*)act;
  float* x2buf = x1buf;
  __half* x0h  = (__half*)alloc((size_t)TN * 32 * 2);       // 12.8 MB fp16 shadow
  __half* x1h  = (__half*)alloc((size_t)TN * 64 * 2);       // 25.6 MB fp16 shadow
  int2*  colattr = (int2*) alloc((size_t)TE * 8);           // final CSR order
  int*   ccnt    = (int*)  alloc((size_t)NC * 4);
  int*   cbase   = (int*)  alloc((size_t)NC * 4);
  int*   gcur    = (int*)  alloc((size_t)NC * 4);
  int*   rowptr  = (int*)  alloc((size_t)(TN + 1) * 4);
  int*   start_s = (int*)  alloc((size_t)(NBAT + 1) * 4);
  int*   start_g = (int*)  alloc((size_t)(NBAT + 1) * 4);
  float* pool_s  = (float*)alloc((size_t)NBAT * 64 * 4);
  float* pool_g  = (float*)alloc((size_t)NBAT * 64 * 4);

  build_tables<<<1, 256, 0, stream>>>(edW1, edb1, edW2, edb2, s2LW, s2Lb, g2LW, g2Lb, tabs);

  // --- dense-write CSR build for BOTH graphs
  hipMemsetAsync(ccnt, 0, (size_t)NC * 4, stream);
  coarse_hist<<<ABLK, 256, 0, stream>>>(ei_s + NEDG, ei_g + NEDG, ccnt);
  coarse_scan<<<1, 1024, 0, stream>>>(ccnt, cbase, gcur, rowptr);
  coarse_partition<<<ABLK, 256, 0, stream>>>(ei_s, ei_s + NEDG, ea_s,
                                             ei_g, ei_g + NEDG, ea_g,
                                             tabs, gcur, part);
  partition_to_csr<<<NC, 256, 0, stream>>>(ccnt, cbase, part, rowptr, colattr);
  batch_bounds_dual<<<782, 256, 0, stream>>>(bat_s, bat_g, start_s, start_g);

  // --- merged dual-graph encoder pipeline (one launch per stage)
  node_embed_dual<<<(TN + 255) / 256, 256, 0, stream>>>(names_s, names_g,
                                                        idW1, idb1, idW2, idb2, x0buf, x0h);
  conv1_dual<<<TN / 4, 256, 0, stream>>>(x0buf, x0h, rowptr, colattr, tabs, h1buf);
  mlp_dual<32><<<TN / 64, 256, 0, stream>>>(h1buf,
                                            s1W1, s1b1, s1W2, s1b2,
                                            g1W1, g1b1, g1W2, g1b2, x1buf, x1h);
  conv2_dual<<<TN / 4, 256, 0, stream>>>(x1buf, x1h, rowptr, colattr, tabs, h2buf);
  mlp_dual<64><<<TN / 64, 256, 0, stream>>>(h2buf,
                                            s2W1, s2b1, s2W2, s2b2,
                                            g2W1, g2b1, g2W2, g2b2, x2buf, (__half*)nullptr);
  pool_dual<<<2 * NBAT, 256, 0, stream>>>(x2buf, start_s, start_g, pool_s, pool_g);

  regressor16<<<32, 256, 0, stream>>>(pool_s, pool_g, depth, rW1, rb1, rW2, rb2, (float*)d_out);
}

// Round 13
// 696.865 us; speedup vs baseline: 1.2572x; 1.0845x over previous
//
#include <hip/hip_runtime.h>
#include <hip/hip_fp16.h>
#include <stdint.h>

namespace {

constexpr int NN   = 100000;    // nodes per graph
constexpr int TN   = 2 * NN;    // nodes across both graphs
constexpr int NEDG = 1600000;   // edges per graph
constexpr int TE   = 2 * NEDG;  // 3.2M edges across both graphs
constexpr int NBAT = 512;       // graphs per batch
constexpr int NSEG = 33;        // piecewise-linear segments of edge MLP (32 breakpoints)

// coarse partition: 256 dst-nodes per coarse bucket, fixed-capacity scratch
constexpr int NC     = 782;     // ceil(TN / 256)
constexpr int TILE   = 4096;    // edges per partition block (16 per thread)
constexpr int ABLK   = (TE + TILE - 1) / TILE;  // 782
constexpr int ENTCAP = 5120;    // bucket capacity (mean 4096, +16 sigma)

// padded LDS strides for the conv edge tables (r9: kills 8-way conflicts)
constexpr int S1 = 36;  // conv1 (32 features)
constexpr int S2 = 68;  // conv2 (64 features)

// table layout (floats): bp[32] | d1[NSEG*32] | c1[NSEG*32] | per-enc {d2[NSEG*64], c2[NSEG*64]} x2
constexpr int TAB_BP = 0;
constexpr int TAB_D1 = 32;
constexpr int TAB_C1 = TAB_D1 + NSEG * 32;
constexpr int TAB_E2 = TAB_C1 + NSEG * 32;
constexpr int TAB_TOTAL = TAB_E2 + 4 * NSEG * 64;

__device__ __forceinline__ float relu_(float x) { return fmaxf(x, 0.0f); }

__device__ __forceinline__ float4 shfl_xor4(float4 v, int m) {
  return make_float4(__shfl_xor(v.x, m), __shfl_xor(v.y, m),
                     __shfl_xor(v.z, m), __shfl_xor(v.w, m));
}

__device__ __forceinline__ float2 h2f2(int u) {
  __half2 h = *reinterpret_cast<__half2*>(&u);
  return __half22float2(h);
}
__device__ __forceinline__ int f2h2(float a, float b) {
  __half2 h = __floats2half2_rn(a, b);
  return *reinterpret_cast<int*>(&h);
}

// ---------------------------------------------------------------------------
// Precompute piecewise-linear tables for e(a) = relu(a*W1+b1)@W2+b2 and the
// folded e2(a) = e(a)@linW + linb. Exact reassociation of the reference math.
// ---------------------------------------------------------------------------
__global__ void build_tables(const float* __restrict__ eW1, const float* __restrict__ eb1,
                             const float* __restrict__ eW2, const float* __restrict__ eb2,
                             const float* __restrict__ sLW, const float* __restrict__ sLb,
                             const float* __restrict__ gLW, const float* __restrict__ gLb,
                             float* __restrict__ tabs) {
  __shared__ float traw[32];
  __shared__ float ts[32];
  __shared__ float dt[NSEG * 32];
  __shared__ float ct[NSEG * 32];
  int tid = threadIdx.x;
  if (tid < 32) {
    float w = eW1[tid], b = eb1[tid];
    traw[tid] = (w != 0.0f) ? (-b / w) : 3.0e38f;
  }
  __syncthreads();
  if (tid < 32) {  // rank sort (stable for duplicates)
    float v = traw[tid];
    int r = 0;
    for (int j = 0; j < 32; ++j) {
      float u = traw[j];
      r += (u < v) || (u == v && j < tid);
    }
    ts[r] = v;
  }
  __syncthreads();
  if (tid < 32) tabs[TAB_BP + tid] = ts[tid];
  for (int idx = tid; idx < NSEG * 32; idx += blockDim.x) {
    int s = idx >> 5, j = idx & 31;
    float a;  // representative point strictly inside segment s: (ts[s-1], ts[s]]
    if (s == 0)            a = ts[0] - 1.0f;
    else if (s == NSEG - 1) a = ts[31] + 1.0f;
    else                   a = 0.5f * ts[s - 1] + 0.5f * ts[s];
    float d = 0.0f, c = 0.0f;
    for (int i = 0; i < 32; ++i) {
      float w = eW1[i], b = eb1[i];
      if (fmaf(a, w, b) > 0.0f) {
        float w2 = eW2[i * 32 + j];
        d = fmaf(w, w2, d);
        c = fmaf(b, w2, c);
      }
    }
    c += eb2[j];
    dt[idx] = d; ct[idx] = c;
    tabs[TAB_D1 + idx] = d;
    tabs[TAB_C1 + idx] = c;
  }
  __syncthreads();
  for (int idx = tid; idx < NSEG * 64; idx += blockDim.x) {
    int s = idx >> 6, k = idx & 63;
    float ds = 0.f, cs = 0.f, dg = 0.f, cg = 0.f;
    for (int j = 0; j < 32; ++j) {
      float dv = dt[s * 32 + j], cv = ct[s * 32 + j];
      float ws = sLW[j * 64 + k], wg = gLW[j * 64 + k];
      ds = fmaf(dv, ws, ds); cs = fmaf(cv, ws, cs);
      dg = fmaf(dv, wg, dg); cg = fmaf(cv, wg, cg);
    }
    cs += sLb[k]; cg += gLb[k];
    tabs[TAB_E2 + idx]                 = ds;
    tabs[TAB_E2 + NSEG * 64 + idx]     = cs;
    tabs[TAB_E2 + 2 * NSEG * 64 + idx] = dg;
    tabs[TAB_E2 + 3 * NSEG * 64 + idx] = cg;
  }
}

// ---------------------------------------------------------------------------
// Fused front: three INDEPENDENT jobs in one launch (block-range dispatch):
//   blocks [0, ABLK)           : coarse partition of both graphs' edges into
//                                fixed-capacity bucket scratch (no pre-hist)
//   blocks [ABLK, ABLK+782)    : node embed (x0 + fp16 shadow)
//   blocks [ABLK+782, +782)    : batch boundaries from sorted bat arrays
// Entry in part[]: src(17) | dlocal(8)<<17 | seg(6)<<25.
// ---------------------------------------------------------------------------
__global__ __launch_bounds__(256) void fused_front(
    const int* __restrict__ names_s, const int* __restrict__ names_g,
    const float* __restrict__ idW1, const float* __restrict__ idb1,
    const float* __restrict__ idW2, const float* __restrict__ idb2,
    const int* __restrict__ src_s, const int* __restrict__ dst_s, const float* __restrict__ attr_s,
    const int* __restrict__ src_g, const int* __restrict__ dst_g, const float* __restrict__ attr_g,
    const int* __restrict__ bat_s, const int* __restrict__ bat_g,
    const float* __restrict__ tabs,
    float* __restrict__ x0, __half* __restrict__ x0h,
    int* __restrict__ gcur, int2* __restrict__ part,
    int* __restrict__ start_s, int* __restrict__ start_g) {
  __shared__ int hist[NC];
  __shared__ int lofs[NC];
  __shared__ int lcur[NC];
  __shared__ int2 sorted[TILE];
  __shared__ int addr[TILE];
  __shared__ int scanbuf[256];
  __shared__ float bp[32];
  int t = threadIdx.x;
  if (blockIdx.x < ABLK) {
    // ---- coarse partition tile ----
    if (t < 32) bp[t] = tabs[TAB_BP + t];
    for (int i = t; i < NC; i += 256) hist[i] = 0;
    __syncthreads();
    int base = blockIdx.x * TILE;
#pragma unroll
    for (int j = 0; j < 16; ++j) {
      int i = base + j * 256 + t;
      if (i < TE) {
        int d = (i < NEDG) ? dst_s[i] : (dst_g[i - NEDG] + NN);
        atomicAdd(&hist[d >> 8], 1);
      }
    }
    __syncthreads();
    int loc[4];
    int sum = 0;
#pragma unroll
    for (int j = 0; j < 4; ++j) {
      int b = t * 4 + j;
      int v = (b < NC) ? hist[b] : 0;
      loc[j] = sum; sum += v;
    }
    scanbuf[t] = sum;
    __syncthreads();
    for (int st = 1; st < 256; st <<= 1) {
      int u = (t >= st) ? scanbuf[t - st] : 0;
      __syncthreads();
      scanbuf[t] += u;
      __syncthreads();
    }
    int texcl = scanbuf[t] - sum;
#pragma unroll
    for (int j = 0; j < 4; ++j) {
      int b = t * 4 + j;
      if (b < NC) { lofs[b] = texcl + loc[j]; lcur[b] = 0; }
    }
    __syncthreads();
    // reserve space in each bucket's fixed-capacity region
    for (int b = t; b < NC; b += 256) {
      int c = hist[b];
      hist[b] = c ? atomicAdd(&gcur[b], c) : 0;
    }
    __syncthreads();
#pragma unroll
    for (int j = 0; j < 16; ++j) {
      int i = base + j * 256 + t;
      if (i < TE) {
        int sl, d; float a;
        if (i < NEDG) { sl = src_s[i]; d = dst_s[i]; a = attr_s[i]; }
        else { int k = i - NEDG; sl = src_g[k]; d = dst_g[k] + NN; a = attr_g[k]; }
        int seg = 0;
#pragma unroll
        for (int q = 0; q < 32; ++q) seg += (bp[q] < a);
        int c = d >> 8;
        int r = atomicAdd(&lcur[c], 1);
        int s = lofs[c] + r;
        sorted[s] = make_int2(sl | ((d & 255) << 17) | (seg << 25), __float_as_int(a));
        addr[s] = c * ENTCAP + hist[c] + r;
      }
    }
    __syncthreads();
    int tot = (base + TILE <= TE) ? TILE : (TE - base);
    for (int s = t; s < tot; s += 256) part[addr[s]] = sorted[s];
  } else if (blockIdx.x < ABLK + 782) {
    // ---- node embed (both graphs) ----
    int n = (blockIdx.x - ABLK) * 256 + t;
    if (n >= TN) return;
    int name = (n < NN) ? names_s[n] : names_g[n - NN];
    float norm = ((float)name + 2.0f) / 281474976710655.0f;
    norm = fminf(fmaxf(norm, 0.0f), 1.0f);
    float h[32];
#pragma unroll
    for (int i = 0; i < 32; ++i) h[i] = relu_(fmaf(norm, idW1[i], idb1[i]));
    float4* out = (float4*)(x0 + (size_t)n * 32);
    int2* outh = (int2*)(x0h + (size_t)n * 32);
    for (int j0 = 0; j0 < 32; j0 += 4) {
      float a0 = idb2[j0], a1 = idb2[j0 + 1], a2 = idb2[j0 + 2], a3 = idb2[j0 + 3];
#pragma unroll
      for (int i = 0; i < 32; ++i) {
        float hv = h[i];
        a0 = fmaf(hv, idW2[i * 32 + j0],     a0);
        a1 = fmaf(hv, idW2[i * 32 + j0 + 1], a1);
        a2 = fmaf(hv, idW2[i * 32 + j0 + 2], a2);
        a3 = fmaf(hv, idW2[i * 32 + j0 + 3], a3);
      }
      out[j0 >> 2] = make_float4(a0, a1, a2, a3);
      outh[j0 >> 2] = make_int2(f2h2(a0, a1), f2h2(a2, a3));
    }
  } else {
    // ---- batch boundaries ----
    int blk = blockIdx.x - ABLK - 782;
    int half = blk >= 391;
    const int* bat = half ? bat_g : bat_s;
    int* start = half ? start_g : start_s;
    int i = (blk - half * 391) * 256 + t;
    if (i >= NN) return;
    int cur = bat[i];
    int prev = (i == 0) ? -1 : bat[i - 1];
    for (int b = prev + 1; b <= cur; ++b) start[b] = i;
    if (i == NN - 1) {
      for (int b = cur + 1; b <= NBAT; ++b) start[b] = NN;
    }
  }
}

__global__ __launch_bounds__(1024) void coarse_scan(
    const int* __restrict__ gcur, int* __restrict__ cbase, int* __restrict__ rowptr) {
  __shared__ int s[1024];
  int t = threadIdx.x;
  int v = (t < NC) ? min(gcur[t], ENTCAP) : 0;
  s[t] = v;
  __syncthreads();
  for (int st = 1; st < 1024; st <<= 1) {
    int u = (t >= st) ? s[t - st] : 0;
    __syncthreads();
    s[t] += u;
    __syncthreads();
  }
  if (t < NC) cbase[t] = s[t] - v;
  if (t == 0) rowptr[TN] = TE;
}

__global__ __launch_bounds__(256) void partition_to_csr(
    const int* __restrict__ gcur, const int* __restrict__ cbase,
    const int2* __restrict__ part,
    int* __restrict__ rowptr, int2* __restrict__ colattr) {
  __shared__ int2 outE[ENTCAP];  // 40 KB
  __shared__ int hist[256];
  __shared__ int cur[256];
  __shared__ int sc[256];
  int t = threadIdx.x, b = blockIdx.x;  // grid exact: NC
  hist[t] = 0;
  __syncthreads();
  int cnt = min(gcur[b], ENTCAP);
  int ibase = b * ENTCAP;
  int obase = cbase[b];
  for (int i = t; i < cnt; i += 256)
    atomicAdd(&hist[(part[ibase + i].x >> 17) & 255], 1);
  __syncthreads();
  int v = hist[t];
  sc[t] = v;
  __syncthreads();
  for (int st = 1; st < 256; st <<= 1) {
    int u = (t >= st) ? sc[t - st] : 0;
    __syncthreads();
    sc[t] += u;
    __syncthreads();
  }
  int excl = sc[t] - v;
  int gnode = b * 256 + t;
  if (gnode < TN) rowptr[gnode] = obase + excl;
  cur[t] = excl;
  __syncthreads();
  for (int i = t; i < cnt; i += 256) {
    int2 e = part[ibase + i];
    int dl = (e.x >> 17) & 255;
    int srcn = e.x & 0x1FFFF;
    int seg = (e.x >> 25) & 63;
    int pos = atomicAdd(&cur[dl], 1);
    outE[pos] = make_int2(srcn | (seg << 20), e.y);  // conv format: src<2^17, seg<64
  }
  __syncthreads();
  for (int i = t; i < cnt; i += 256) colattr[obase + i] = outE[i];
}

// ---------------------------------------------------------------------------
// GINE aggregation over BOTH graphs, dst-major. Gather source = fp16 shadow;
// self term + accumulate in fp32. r8 lane layout, padded LDS tables (r9).
// ---------------------------------------------------------------------------
__global__ __launch_bounds__(256) void conv1_dual(
    const float* __restrict__ x0, const __half* __restrict__ x0h,
    const int* __restrict__ rowptr, const int2* __restrict__ colattr,
    const float* __restrict__ tabs, float* __restrict__ hb) {
  __shared__ float dt[NSEG * S1];
  __shared__ float ct[NSEG * S1];
  for (int i = threadIdx.x; i < NSEG * 32; i += 256) {
    int s = i >> 5, j = i & 31;
    dt[s * S1 + j] = tabs[TAB_D1 + i];
    ct[s * S1 + j] = tabs[TAB_C1 + i];
  }
  __syncthreads();
  int n = blockIdx.x * 4 + (threadIdx.x >> 6);  // grid exact: TN/4
  const __half* xb = x0h + (n >= NN ? (size_t)NN * 32 : 0);  // src ids graph-local
  int lane = threadIdx.x & 63;
  int sub = lane & 7;        // 8 edges in flight (x2 unroll = 16)
  int f0  = (lane >> 3) * 4; // 8 quads -> 32 features
  int beg = rowptr[n], end = rowptr[n + 1];
  float4 acc = make_float4(0.f, 0.f, 0.f, 0.f);
  for (int k = beg + sub; k < end; k += 16) {
    int2 ca0 = colattr[k];
    int kb = k + 8;
    bool h1 = kb < end;
    int2 ca1 = h1 ? colattr[kb] : ca0;
    unsigned p0 = (unsigned)ca0.x, p1 = (unsigned)ca1.x;
    int s0 = (int)(p0 & 0xFFFFFu), g0 = (int)(p0 >> 20);
    int s1 = (int)(p1 & 0xFFFFFu), g1 = (int)(p1 >> 20);
    float a0 = __int_as_float(ca0.y), a1 = __int_as_float(ca1.y);
    int2 hv0 = *(const int2*)(xb + (size_t)s0 * 32 + f0);
    int2 hv1 = *(const int2*)(xb + (size_t)s1 * 32 + f0);
    float2 x00 = h2f2(hv0.x), x01 = h2f2(hv0.y);
    float2 x10 = h2f2(hv1.x), x11 = h2f2(hv1.y);
    float4 d0 = *(const float4*)&dt[g0 * S1 + f0];
    float4 c0 = *(const float4*)&ct[g0 * S1 + f0];
    float4 d1 = *(const float4*)&dt[g1 * S1 + f0];
    float4 c1 = *(const float4*)&ct[g1 * S1 + f0];
    acc.x += relu_(x00.x + fmaf(a0, d0.x, c0.x));
    acc.y += relu_(x00.y + fmaf(a0, d0.y, c0.y));
    acc.z += relu_(x01.x + fmaf(a0, d0.z, c0.z));
    acc.w += relu_(x01.y + fmaf(a0, d0.w, c0.w));
    if (h1) {
      acc.x += relu_(x10.x + fmaf(a1, d1.x, c1.x));
      acc.y += relu_(x10.y + fmaf(a1, d1.y, c1.y));
      acc.z += relu_(x11.x + fmaf(a1, d1.z, c1.z));
      acc.w += relu_(x11.y + fmaf(a1, d1.w, c1.w));
    }
  }
#pragma unroll
  for (int m = 1; m < 8; m <<= 1) {
    float4 o = shfl_xor4(acc, m);
    acc.x += o.x; acc.y += o.y; acc.z += o.z; acc.w += o.w;
  }
  if (sub == 0) {
    const float4 self = *(const float4*)(x0 + (size_t)n * 32 + f0);
    *(float4*)(hb + (size_t)n * 32 + f0) =
        make_float4(self.x + acc.x, self.y + acc.y, self.z + acc.z, self.w + acc.w);
  }
}

__global__ __launch_bounds__(256) void conv2_dual(
    const float* __restrict__ x1, const __half* __restrict__ x1h,
    const int* __restrict__ rowptr, const int2* __restrict__ colattr,
    const float* __restrict__ tabs, float* __restrict__ hb) {
  __shared__ float dt[NSEG * S2];
  __shared__ float ct[NSEG * S2];
  int half = blockIdx.x >= (NN / 4);   // block's 4 nodes never span (NN%4==0)
  const float* d2 = tabs + TAB_E2 + (size_t)half * 2 * NSEG * 64;
  for (int i = threadIdx.x; i < NSEG * 64; i += 256) {
    int s = i >> 6, j = i & 63;
    dt[s * S2 + j] = d2[i];
    ct[s * S2 + j] = d2[NSEG * 64 + i];
  }
  __syncthreads();
  int n = blockIdx.x * 4 + (threadIdx.x >> 6);  // grid exact: TN/4
  const __half* xb = x1h + (size_t)half * NN * 64;  // src ids graph-local
  int lane = threadIdx.x & 63;
  int sub = lane & 7;        // 8 edges in flight (x2 unroll = 16)
  int f0  = (lane >> 3) * 8; // 8 features per lane -> 64 features
  int beg = rowptr[n], end = rowptr[n + 1];
  float4 accA = make_float4(0.f, 0.f, 0.f, 0.f);
  float4 accB = make_float4(0.f, 0.f, 0.f, 0.f);
  for (int k = beg + sub; k < end; k += 16) {
    int2 ca0 = colattr[k];
    int kb = k + 8;
    bool h1 = kb < end;
    int2 ca1 = h1 ? colattr[kb] : ca0;
    unsigned p0 = (unsigned)ca0.x, p1 = (unsigned)ca1.x;
    int s0 = (int)(p0 & 0xFFFFFu), g0 = (int)(p0 >> 20);
    int s1 = (int)(p1 & 0xFFFFFu), g1 = (int)(p1 >> 20);
    float a0 = __int_as_float(ca0.y), a1 = __int_as_float(ca1.y);
    int4 hv0 = *(const int4*)(xb + (size_t)s0 * 64 + f0);
    int4 hv1 = *(const int4*)(xb + (size_t)s1 * 64 + f0);
    float2 xa0 = h2f2(hv0.x), xa1 = h2f2(hv0.y), xa2 = h2f2(hv0.z), xa3 = h2f2(hv0.w);
    const float* dp0 = dt + g0 * S2 + f0;
    const float* cp0 = ct + g0 * S2 + f0;
    float4 da0 = *(const float4*)dp0;
    float4 db0 = *(const float4*)(dp0 + 4);
    float4 ea0 = *(const float4*)cp0;
    float4 eb0 = *(const float4*)(cp0 + 4);
    accA.x += relu_(xa0.x + fmaf(a0, da0.x, ea0.x));
    accA.y += relu_(xa0.y + fmaf(a0, da0.y, ea0.y));
    accA.z += relu_(xa1.x + fmaf(a0, da0.z, ea0.z));
    accA.w += relu_(xa1.y + fmaf(a0, da0.w, ea0.w));
    accB.x += relu_(xa2.x + fmaf(a0, db0.x, eb0.x));
    accB.y += relu_(xa2.y + fmaf(a0, db0.y, eb0.y));
    accB.z += relu_(xa3.x + fmaf(a0, db0.z, eb0.z));
    accB.w += relu_(xa3.y + fmaf(a0, db0.w, eb0.w));
    if (h1) {
      float2 ya0 = h2f2(hv1.x), ya1 = h2f2(hv1.y), ya2 = h2f2(hv1.z), ya3 = h2f2(hv1.w);
      const float* dp1 = dt + g1 * S2 + f0;
      const float* cp1 = ct + g1 * S2 + f0;
      float4 da1 = *(const float4*)dp1;
      float4 db1 = *(const float4*)(dp1 + 4);
      float4 ea1 = *(const float4*)cp1;
      float4 eb1 = *(const float4*)(cp1 + 4);
      accA.x += relu_(ya0.x + fmaf(a1, da1.x, ea1.x));
      accA.y += relu_(ya0.y + fmaf(a1, da1.y, ea1.y));
      accA.z += relu_(ya1.x + fmaf(a1, da1.z, ea1.z));
      accA.w += relu_(ya1.y + fmaf(a1, da1.w, ea1.w));
      accB.x += relu_(ya2.x + fmaf(a1, db1.x, eb1.x));
      accB.y += relu_(ya2.y + fmaf(a1, db1.y, eb1.y));
      accB.z += relu_(ya3.x + fmaf(a1, db1.z, eb1.z));
      accB.w += relu_(ya3.y + fmaf(a1, db1.w, eb1.w));
    }
  }
#pragma unroll
  for (int m = 1; m < 8; m <<= 1) {
    float4 oA = shfl_xor4(accA, m);
    float4 oB = shfl_xor4(accB, m);
    accA.x += oA.x; accA.y += oA.y; accA.z += oA.z; accA.w += oA.w;
    accB.x += oB.x; accB.y += oB.y; accB.z += oB.z; accB.w += oB.w;
  }
  if (sub == 0) {
    const float* sp = x1 + (size_t)n * 64 + f0;
    const float4 sA = *(const float4*)sp;
    const float4 sB = *(const float4*)(sp + 4);
    float* op = hb + (size_t)n * 64 + f0;
    *(float4*)op       = make_float4(sA.x + accA.x, sA.y + accA.y, sA.z + accA.z, sA.w + accA.w);
    *(float4*)(op + 4) = make_float4(sB.x + accB.x, sB.y + accB.y, sB.z + accB.z, sB.w + accB.w);
  }
}

// ---------------------------------------------------------------------------
// Per-node MLP2 (32 -> 64 -> 64) over BOTH graphs, with fp16 shadow output.
// Register-tiled VALU GEMM: 64 nodes/block, thread owns 4 nodes x 4 features.
// ---------------------------------------------------------------------------
__global__ __launch_bounds__(256) void mlp1_dual(
    const float* __restrict__ hin,
    const float* __restrict__ sW1, const float* __restrict__ sb1,
    const float* __restrict__ sW2, const float* __restrict__ sb2,
    const float* __restrict__ gW1, const float* __restrict__ gb1,
    const float* __restrict__ gW2, const float* __restrict__ gb2,
    float* __restrict__ xout, __half* __restrict__ hout) {
  constexpr int IN = 32;
  __shared__ float hsT[IN][65];
  __shared__ float ysT[64][65];
  int base = blockIdx.x * 64;     // grid exact: TN/64 = 3125
  for (int idx = threadIdx.x; idx < 64 * IN; idx += 256) {
    int node = idx / IN, k = idx - node * IN;
    hsT[k][node] = hin[(size_t)(base + node) * IN + k];
  }
  __syncthreads();
  int nt = threadIdx.x >> 4, jx = threadIdx.x & 15;
  int n0 = nt * 4, f0 = jx * 4;
  bool isg = (base + n0) >= NN;
  const float* W1 = isg ? gW1 : sW1;
  const float* b1 = isg ? gb1 : sb1;
  const float* W2 = isg ? gW2 : sW2;
  const float* b2 = isg ? gb2 : sb2;
  float4 acc0, acc1, acc2, acc3;
  {
    const float4 b = *(const float4*)(b1 + f0);
    acc0 = b; acc1 = b; acc2 = b; acc3 = b;
  }
  for (int k = 0; k < IN; ++k) {
    const float4 h = *(const float4*)&hsT[k][n0];
    const float4 w = *(const float4*)(W1 + k * 64 + f0);
    acc0.x = fmaf(h.x, w.x, acc0.x); acc0.y = fmaf(h.x, w.y, acc0.y);
    acc0.z = fmaf(h.x, w.z, acc0.z); acc0.w = fmaf(h.x, w.w, acc0.w);
    acc1.x = fmaf(h.y, w.x, acc1.x); acc1.y = fmaf(h.y, w.y, acc1.y);
    acc1.z = fmaf(h.y, w.z, acc1.z); acc1.w = fmaf(h.y, w.w, acc1.w);
    acc2.x = fmaf(h.z, w.x, acc2.x); acc2.y = fmaf(h.z, w.y, acc2.y);
    acc2.z = fmaf(h.z, w.z, acc2.z); acc2.w = fmaf(h.z, w.w, acc2.w);
    acc3.x = fmaf(h.w, w.x, acc3.x); acc3.y = fmaf(h.w, w.y, acc3.y);
    acc3.z = fmaf(h.w, w.z, acc3.z); acc3.w = fmaf(h.w, w.w, acc3.w);
  }
  ysT[f0 + 0][n0 + 0] = relu_(acc0.x); ysT[f0 + 1][n0 + 0] = relu_(acc0.y);
  ysT[f0 + 2][n0 + 0] = relu_(acc0.z); ysT[f0 + 3][n0 + 0] = relu_(acc0.w);
  ysT[f0 + 0][n0 + 1] = relu_(acc1.x); ysT[f0 + 1][n0 + 1] = relu_(acc1.y);
  ysT[f0 + 2][n0 + 1] = relu_(acc1.z); ysT[f0 + 3][n0 + 1] = relu_(acc1.w);
  ysT[f0 + 0][n0 + 2] = relu_(acc2.x); ysT[f0 + 1][n0 + 2] = relu_(acc2.y);
  ysT[f0 + 2][n0 + 2] = relu_(acc2.z); ysT[f0 + 3][n0 + 2] = relu_(acc2.w);
  ysT[f0 + 0][n0 + 3] = relu_(acc3.x); ysT[f0 + 1][n0 + 3] = relu_(acc3.y);
  ysT[f0 + 2][n0 + 3] = relu_(acc3.z); ysT[f0 + 3][n0 + 3] = relu_(acc3.w);
  __syncthreads();
  {
    const float4 b = *(const float4*)(b2 + f0);
    acc0 = b; acc1 = b; acc2 = b; acc3 = b;
  }
  for (int k = 0; k < 64; ++k) {
    const float4 h = *(const float4*)&ysT[k][n0];
    const float4 w = *(const float4*)(W2 + k * 64 + f0);
    acc0.x = fmaf(h.x, w.x, acc0.x); acc0.y = fmaf(h.x, w.y, acc0.y);
    acc0.z = fmaf(h.x, w.z, acc0.z); acc0.w = fmaf(h.x, w.w, acc0.w);
    acc1.x = fmaf(h.y, w.x, acc1.x); acc1.y = fmaf(h.y, w.y, acc1.y);
    acc1.z = fmaf(h.y, w.z, acc1.z); acc1.w = fmaf(h.y, w.w, acc1.w);
    acc2.x = fmaf(h.z, w.x, acc2.x); acc2.y = fmaf(h.z, w.y, acc2.y);
    acc2.z = fmaf(h.z, w.z, acc2.z); acc2.w = fmaf(h.z, w.w, acc2.w);
    acc3.x = fmaf(h.w, w.x, acc3.x); acc3.y = fmaf(h.w, w.y, acc3.y);
    acc3.z = fmaf(h.w, w.z, acc3.z); acc3.w = fmaf(h.w, w.w, acc3.w);
  }
  float4 o;
  o = make_float4(relu_(acc0.x), relu_(acc0.y), relu_(acc0.z), relu_(acc0.w));
  *(float4*)(xout + (size_t)(base + n0 + 0) * 64 + f0) = o;
  *(int2*)(hout + (size_t)(base + n0 + 0) * 64 + f0) = make_int2(f2h2(o.x, o.y), f2h2(o.z, o.w));
  o = make_float4(relu_(acc1.x), relu_(acc1.y), relu_(acc1.z), relu_(acc1.w));
  *(float4*)(xout + (size_t)(base + n0 + 1) * 64 + f0) = o;
  *(int2*)(hout + (size_t)(base + n0 + 1) * 64 + f0) = make_int2(f2h2(o.x, o.y), f2h2(o.z, o.w));
  o = make_float4(relu_(acc2.x), relu_(acc2.y), relu_(acc2.z), relu_(acc2.w));
  *(float4*)(xout + (size_t)(base + n0 + 2) * 64 + f0) = o;
  *(int2*)(hout + (size_t)(base + n0 + 2) * 64 + f0) = make_int2(f2h2(o.x, o.y), f2h2(o.z, o.w));
  o = make_float4(relu_(acc3.x), relu_(acc3.y), relu_(acc3.z), relu_(acc3.w));
  *(float4*)(xout + (size_t)(base + n0 + 3) * 64 + f0) = o;
  *(int2*)(hout + (size_t)(base + n0 + 3) * 64 + f0) = make_int2(f2h2(o.x, o.y), f2h2(o.z, o.w));
}

// ---------------------------------------------------------------------------
// mlp2 + pool fused: outputs go to LDS, per-block run-length reduction over
// batch segments, ~300 fp32 atomics/block into psum (no x2 round-trip).
// psum rows: [0,NBAT) = graph s sums, [NBAT,2*NBAT) = graph g sums.
// ---------------------------------------------------------------------------
__global__ __launch_bounds__(256) void mlp2_pool_dual(
    const float* __restrict__ hin,
    const float* __restrict__ sW1, const float* __restrict__ sb1,
    const float* __restrict__ sW2, const float* __restrict__ sb2,
    const float* __restrict__ gW1, const float* __restrict__ gb1,
    const float* __restrict__ gW2, const float* __restrict__ gb2,
    const int* __restrict__ bat_s, const int* __restrict__ bat_g,
    float* __restrict__ psum) {
  constexpr int IN = 64;
  __shared__ float hsT[IN][65];
  __shared__ float ysT[64][65];
  __shared__ int pid[64];
  int base = blockIdx.x * 64;     // grid exact: TN/64 = 3125
  for (int idx = threadIdx.x; idx < 64 * IN; idx += 256) {
    int node = idx / IN, k = idx - node * IN;
    hsT[k][node] = hin[(size_t)(base + node) * IN + k];
  }
  if (threadIdx.x < 64) {
    int gb = base + threadIdx.x;
    pid[threadIdx.x] = (gb < NN) ? bat_s[gb] : (NBAT + bat_g[gb - NN]);
  }
  __syncthreads();
  int nt = threadIdx.x >> 4, jx = threadIdx.x & 15;
  int n0 = nt * 4, f0 = jx * 4;
  bool isg = (base + n0) >= NN;
  const float* W1 = isg ? gW1 : sW1;
  const float* b1 = isg ? gb1 : sb1;
  const float* W2 = isg ? gW2 : sW2;
  const float* b2 = isg ? gb2 : sb2;
  float4 acc0, acc1, acc2, acc3;
  {
    const float4 b = *(const float4*)(b1 + f0);
    acc0 = b; acc1 = b; acc2 = b; acc3 = b;
  }
  for (int k = 0; k < IN; ++k) {
    const float4 h = *(const float4*)&hsT[k][n0];
    const float4 w = *(const float4*)(W1 + k * 64 + f0);
    acc0.x = fmaf(h.x, w.x, acc0.x); acc0.y = fmaf(h.x, w.y, acc0.y);
    acc0.z = fmaf(h.x, w.z, acc0.z); acc0.w = fmaf(h.x, w.w, acc0.w);
    acc1.x = fmaf(h.y, w.x, acc1.x); acc1.y = fmaf(h.y, w.y, acc1.y);
    acc1.z = fmaf(h.y, w.z, acc1.z); acc1.w = fmaf(h.y, w.w, acc1.w);
    acc2.x = fmaf(h.z, w.x, acc2.x); acc2.y = fmaf(h.z, w.y, acc2.y);
    acc2.z = fmaf(h.z, w.z, acc2.z); acc2.w = fmaf(h.z, w.w, acc2.w);
    acc3.x = fmaf(h.w, w.x, acc3.x); acc3.y = fmaf(h.w, w.y, acc3.y);
    acc3.z = fmaf(h.w, w.z, acc3.z); acc3.w = fmaf(h.w, w.w, acc3.w);
  }
  ysT[f0 + 0][n0 + 0] = relu_(acc0.x); ysT[f0 + 1][n0 + 0] = relu_(acc0.y);
  ysT[f0 + 2][n0 + 0] = relu_(acc0.z); ysT[f0 + 3][n0 + 0] = relu_(acc0.w);
  ysT[f0 + 0][n0 + 1] = relu_(acc1.x); ysT[f0 + 1][n0 + 1] = relu_(acc1.y);
  ysT[f0 + 2][n0 + 1] = relu_(acc1.z); ysT[f0 + 3][n0 + 1] = relu_(acc1.w);
  ysT[f0 + 0][n0 + 2] = relu_(acc2.x); ysT[f0 + 1][n0 + 2] = relu_(acc2.y);
  ysT[f0 + 2][n0 + 2] = relu_(acc2.z); ysT[f0 + 3][n0 + 2] = relu_(acc2.w);
  ysT[f0 + 0][n0 + 3] = relu_(acc3.x); ysT[f0 + 1][n0 + 3] = relu_(acc3.y);
  ysT[f0 + 2][n0 + 3] = relu_(acc3.z); ysT[f0 + 3][n0 + 3] = relu_(acc3.w);
  __syncthreads();
  {
    const float4 b = *(const float4*)(b2 + f0);
    acc0 = b; acc1 = b; acc2 = b; acc3 = b;
  }
  for (int k = 0; k < 64; ++k) {
    const float4 h = *(const float4*)&ysT[k][n0];
    const float4 w = *(const float4*)(W2 + k * 64 + f0);
    acc0.x = fmaf(h.x, w.x, acc0.x); acc0.y = fmaf(h.x, w.y, acc0.y);
    acc0.z = fmaf(h.x, w.z, acc0.z); acc0.w = fmaf(h.x, w.w, acc0.w);
    acc1.x = fmaf(h.y, w.x, acc1.x); acc1.y = fmaf(h.y, w.y, acc1.y);
    acc1.z = fmaf(h.y, w.z, acc1.z); acc1.w = fmaf(h.y, w.w, acc1.w);
    acc2.x = fmaf(h.z, w.x, acc2.x); acc2.y = fmaf(h.z, w.y, acc2.y);
    acc2.z = fmaf(h.z, w.z, acc2.z); acc2.w = fmaf(h.z, w.w, acc2.w);
    acc3.x = fmaf(h.w, w.x, acc3.x); acc3.y = fmaf(h.w, w.y, acc3.y);
    acc3.z = fmaf(h.w, w.z, acc3.z); acc3.w = fmaf(h.w, w.w, acc3.w);
  }
  __syncthreads();  // all reads of ysT done; reuse it for outputs [f][node]
  ysT[f0 + 0][n0 + 0] = relu_(acc0.x); ysT[f0 + 1][n0 + 0] = relu_(acc0.y);
  ysT[f0 + 2][n0 + 0] = relu_(acc0.z); ysT[f0 + 3][n0 + 0] = relu_(acc0.w);
  ysT[f0 + 0][n0 + 1] = relu_(acc1.x); ysT[f0 + 1][n0 + 1] = relu_(acc1.y);
  ysT[f0 + 2][n0 + 1] = relu_(acc1.z); ysT[f0 + 3][n0 + 1] = relu_(acc1.w);
  ysT[f0 + 0][n0 + 2] = relu_(acc2.x); ysT[f0 + 1][n0 + 2] = relu_(acc2.y);
  ysT[f0 + 2][n0 + 2] = relu_(acc2.z); ysT[f0 + 3][n0 + 2] = relu_(acc2.w);
  ysT[f0 + 0][n0 + 3] = relu_(acc3.x); ysT[f0 + 1][n0 + 3] = relu_(acc3.y);
  ysT[f0 + 2][n0 + 3] = relu_(acc3.z); ysT[f0 + 3][n0 + 3] = relu_(acc3.w);
  __syncthreads();
  // pool: thread (c, f) sums nodes [c*16, c*16+16) of feature f, flushing
  // per batch-segment run (nodes are sorted by batch within each graph)
  int c = threadIdx.x >> 6, f = threadIdx.x & 63;
  int cur = pid[c * 16];
  float run = 0.0f;
  for (int i = 0; i < 16; ++i) {
    int nx = c * 16 + i;
    int p = pid[nx];
    if (p != cur) { atomicAdd(&psum[(size_t)cur * 64 + f], run); run = 0.0f; cur = p; }
    run += ysT[f][nx];
  }
  atomicAdd(&psum[(size_t)cur * 64 + f], run);
}

// ---------------------------------------------------------------------------
// regressor: out[b] = relu([s_mean|g_mean|depth] @ rW1 + rb1) @ rW2 + rb2
// means = psum / count (counts from batch boundary arrays)
// ---------------------------------------------------------------------------
__global__ __launch_bounds__(256) void regressor16(
    const float* __restrict__ psum,
    const int* __restrict__ start_s, const int* __restrict__ start_g,
    const float* __restrict__ depth,
    const float* __restrict__ W1, const float* __restrict__ b1,
    const float* __restrict__ W2, const float* __restrict__ b2,
    float* __restrict__ out) {
  __shared__ float zs[16][132];   // [row][k], k in [0,129)
  __shared__ float ys[64][17];
  __shared__ float inv_s[16], inv_g[16];
  int base = blockIdx.x * 16;     // grid 32 blocks x 16 rows = 512 exact
  if (threadIdx.x < 16) {
    int b = base + threadIdx.x;
    inv_s[threadIdx.x] = 1.0f / fmaxf((float)(start_s[b + 1] - start_s[b]), 1.0f);
    inv_g[threadIdx.x] = 1.0f / fmaxf((float)(start_g[b + 1] - start_g[b]), 1.0f);
  }
  __syncthreads();
  for (int i = threadIdx.x; i < 16 * 64; i += 256) {
    int ln = i >> 6, k = i & 63;
    zs[ln][k]      = psum[(size_t)(base + ln) * 64 + k] * inv_s[ln];
    zs[ln][64 + k] = psum[(size_t)(NBAT + base + ln) * 64 + k] * inv_g[ln];
  }
  if (threadIdx.x < 16) zs[threadIdx.x][128] = depth[base + threadIdx.x];
  __syncthreads();
  int g = threadIdx.x >> 4;
  int j = threadIdx.x & 15;
  int f0 = j * 4;
  float a0, a1, a2, a3;
  {
    const float4 b = *(const float4*)(b1 + f0);
    a0 = b.x; a1 = b.y; a2 = b.z; a3 = b.w;
  }
  for (int k = 0; k < 129; ++k) {
    float zv = zs[g][k];
    const float4 w = *(const float4*)(W1 + k * 64 + f0);
    a0 = fmaf(zv, w.x, a0); a1 = fmaf(zv, w.y, a1);
    a2 = fmaf(zv, w.z, a2); a3 = fmaf(zv, w.w, a3);
  }
  ys[f0 + 0][g] = relu_(a0);
  ys[f0 + 1][g] = relu_(a1);
  ys[f0 + 2][g] = relu_(a2);
  ys[f0 + 3][g] = relu_(a3);
  __syncthreads();
  float s = ys[f0 + 0][g] * W2[f0 + 0] + ys[f0 + 1][g] * W2[f0 + 1] +
            ys[f0 + 2][g] * W2[f0 + 2] + ys[f0 + 3][g] * W2[f0 + 3];
#pragma unroll
  for (int m = 1; m < 16; m <<= 1) s += __shfl_xor(s, m);
  if (j == 0) out[base + g] = s + b2[0];
}

}  // namespace

extern "C" void kernel_launch(void* const* d_in, const int* in_sizes, int n_in,
                              void* d_out, int out_size, void* d_ws, size_t ws_size,
                              hipStream_t stream) {
  const int*   names_s = (const int*)d_in[0];
  const int*   ei_s    = (const int*)d_in[1];
  const float* ea_s    = (const float*)d_in[2];
  const int*   bat_s   = (const int*)d_in[3];
  const int*   names_g = (const int*)d_in[4];
  const int*   ei_g    = (const int*)d_in[5];
  const float* ea_g    = (const float*)d_in[6];
  const int*   bat_g   = (const int*)d_in[7];
  const float* depth   = (const float*)d_in[8];
  const float* idW1 = (const float*)d_in[9],  *idb1 = (const float*)d_in[10];
  const float* idW2 = (const float*)d_in[11], *idb2 = (const float*)d_in[12];
  const float* edW1 = (const float*)d_in[13], *edb1 = (const float*)d_in[14];
  const float* edW2 = (const float*)d_in[15], *edb2 = (const float*)d_in[16];
  const float* s1W1 = (const float*)d_in[17], *s1b1 = (const float*)d_in[18];
  const float* s1W2 = (const float*)d_in[19], *s1b2 = (const float*)d_in[20];
  const float* s2W1 = (const float*)d_in[21], *s2b1 = (const float*)d_in[22];
  const float* s2W2 = (const float*)d_in[23], *s2b2 = (const float*)d_in[24];
  const float* s2LW = (const float*)d_in[25], *s2Lb = (const float*)d_in[26];
  const float* g1W1 = (const float*)d_in[27], *g1b1 = (const float*)d_in[28];
  const float* g1W2 = (const float*)d_in[29], *g1b2 = (const float*)d_in[30];
  const float* g2W1 = (const float*)d_in[31], *g2b1 = (const float*)d_in[32];
  const float* g2W2 = (const float*)d_in[33], *g2b2 = (const float*)d_in[34];
  const float* g2LW = (const float*)d_in[35], *g2Lb = (const float*)d_in[36];
  const float* rW1  = (const float*)d_in[37], *rb1  = (const float*)d_in[38];
  const float* rW2  = (const float*)d_in[39], *rb2  = (const float*)d_in[40];
  (void)in_sizes; (void)n_in; (void)out_size; (void)ws_size;

  char* ws = (char*)d_ws;
  size_t off = 0;
  auto alloc = [&](size_t bytes) -> char* {
    char* p = ws + off;
    off += (bytes + 255) & ~(size_t)255;
    return p;
  };
  float* tabs    = (float*)alloc((size_t)TAB_TOTAL * 4);
  // Activation region (102.4 MB):
  //   x0 [TN][32] at [0, 25.6M); h1 [TN][32] at [25.6M, 51.2M);
  //   x1 [TN][64] at [51.2M, 102.4M).
  //   part scratch (NC*ENTCAP*8 = 32.03M) aliases the x1 region -- consumed
  //   by partition_to_csr before mlp1 writes x1; disjoint from x0/h1 so the
  //   fused_front launch can run embed and partition concurrently.
  //   h2 [TN][64] aliases [0, 51.2M) (x0+h1 dead by conv2).
  char*  act   = alloc((size_t)TN * 64 * 4 * 2);            // 102,400,000 B
  float* x0buf = (float*)act;
  float* h1buf = (float*)(act + (size_t)TN * 32 * 4);
  float* x1buf = (float*)(act + (size_t)TN * 64 * 4);
  int2*  part  = (int2*)x1buf;
  float* h2buf = (float*)act;
  __half* x0h  = (__half*)alloc((size_t)TN * 32 * 2);       // 12.8 MB fp16 shadow
  __half* x1h  = (__half*)alloc((size_t)TN * 64 * 2);       // 25.6 MB fp16 shadow
  int2*  colattr = (int2*) alloc((size_t)TE * 8);           // final CSR order
  int*   gcur    = (int*)  alloc((size_t)NC * 4);
  int*   cbase   = (int*)  alloc((size_t)NC * 4);
  int*   rowptr  = (int*)  alloc((size_t)(TN + 1) * 4);
  int*   start_s = (int*)  alloc((size_t)(NBAT + 1) * 4);
  int*   start_g = (int*)  alloc((size_t)(NBAT + 1) * 4);
  float* psum    = (float*)alloc((size_t)2 * NBAT * 64 * 4);

  build_tables<<<1, 256, 0, stream>>>(edW1, edb1, edW2, edb2, s2LW, s2Lb, g2LW, g2Lb, tabs);
  hipMemsetAsync(gcur, 0, (size_t)NC * 4, stream);
  hipMemsetAsync(psum, 0, (size_t)2 * NBAT * 64 * 4, stream);

  // embed || partition || batch_bounds in one launch
  fused_front<<<ABLK + 782 + 782, 256, 0, stream>>>(
      names_s, names_g, idW1, idb1, idW2, idb2,
      ei_s, ei_s + NEDG, ea_s, ei_g, ei_g + NEDG, ea_g,
      bat_s, bat_g, tabs, x0buf, x0h, gcur, part, start_s, start_g);
  coarse_scan<<<1, 1024, 0, stream>>>(gcur, cbase, rowptr);
  partition_to_csr<<<NC, 256, 0, stream>>>(gcur, cbase, part, rowptr, colattr);

  conv1_dual<<<TN / 4, 256, 0, stream>>>(x0buf, x0h, rowptr, colattr, tabs, h1buf);
  mlp1_dual<<<TN / 64, 256, 0, stream>>>(h1buf,
                                         s1W1, s1b1, s1W2, s1b2,
                                         g1W1, g1b1, g1W2, g1b2, x1buf, x1h);
  conv2_dual<<<TN / 4, 256, 0, stream>>>(x1buf, x1h, rowptr, colattr, tabs, h2buf);
  mlp2_pool_dual<<<TN / 64, 256, 0, stream>>>(h2buf,
                                              s2W1, s2b1, s2W2, s2b2,
                                              g2W1, g2b1, g2W2, g2b2,
                                              bat_s, bat_g, psum);
  regressor16<<<32, 256, 0, stream>>>(psum, start_s, start_g, depth,
                                      rW1, rb1, rW2, rb2, (float*)d_out);
}

// Round 15
// 659.158 us; speedup vs baseline: 1.3291x; 1.0572x over previous
//
#include <hip/hip_runtime.h>
#include <hip/hip_fp16.h>
#include <stdint.h>

namespace {

constexpr int NN   = 100000;    // nodes per graph
constexpr int TN   = 2 * NN;    // nodes across both graphs
constexpr int NEDG = 1600000;   // edges per graph
constexpr int TE   = 2 * NEDG;  // 3.2M edges across both graphs
constexpr int NBAT = 512;       // graphs per batch
constexpr int NSEG = 33;        // piecewise-linear segments of edge MLP (32 breakpoints)

// coarse partition: 256 dst-nodes per coarse bucket, fixed-capacity scratch
constexpr int NC     = 782;     // ceil(TN / 256)
constexpr int TILE   = 4096;    // edges per partition block (16 per thread)
constexpr int ABLK   = (TE + TILE - 1) / TILE;  // 782
constexpr int ENTCAP = 5120;    // bucket capacity (mean 4096, +16 sigma)

// half2 LDS strides for the conv edge tables (16B-aligned for b128/b64 reads;
// stride*4 % 16 == 0, and stride mod 32 != 0 spreads the random seg id g
// across bank offsets)
constexpr int S1H = 20;  // conv1: 16 half2 (32 feat) + 4 pad
constexpr int S2H = 36;  // conv2: 32 half2 (64 feat) + 4 pad

// table layout (floats): bp[32] | d1[NSEG*32] | c1[NSEG*32] | per-enc {d2[NSEG*64], c2[NSEG*64]} x2
constexpr int TAB_BP = 0;
constexpr int TAB_D1 = 32;
constexpr int TAB_C1 = TAB_D1 + NSEG * 32;
constexpr int TAB_E2 = TAB_C1 + NSEG * 32;
constexpr int TAB_TOTAL = TAB_E2 + 4 * NSEG * 64;

__device__ __forceinline__ float relu_(float x) { return fmaxf(x, 0.0f); }

__device__ __forceinline__ float4 shfl_xor4(float4 v, int m) {
  return make_float4(__shfl_xor(v.x, m), __shfl_xor(v.y, m),
                     __shfl_xor(v.z, m), __shfl_xor(v.w, m));
}

__device__ __forceinline__ __half2 bch(int u) {
  return *reinterpret_cast<__half2*>(&u);
}
__device__ __forceinline__ int f2h2(float a, float b) {
  __half2 h = __floats2half2_rn(a, b);
  return *reinterpret_cast<int*>(&h);
}

// ---------------------------------------------------------------------------
// Precompute piecewise-linear tables for e(a) = relu(a*W1+b1)@W2+b2 and the
// folded e2(a) = e(a)@linW + linb. Exact reassociation of the reference math.
// ---------------------------------------------------------------------------
__global__ void build_tables(const float* __restrict__ eW1, const float* __restrict__ eb1,
                             const float* __restrict__ eW2, const float* __restrict__ eb2,
                             const float* __restrict__ sLW, const float* __restrict__ sLb,
                             const float* __restrict__ gLW, const float* __restrict__ gLb,
                             float* __restrict__ tabs) {
  __shared__ float traw[32];
  __shared__ float ts[32];
  __shared__ float dt[NSEG * 32];
  __shared__ float ct[NSEG * 32];
  int tid = threadIdx.x;
  if (tid < 32) {
    float w = eW1[tid], b = eb1[tid];
    traw[tid] = (w != 0.0f) ? (-b / w) : 3.0e38f;
  }
  __syncthreads();
  if (tid < 32) {  // rank sort (stable for duplicates)
    float v = traw[tid];
    int r = 0;
    for (int j = 0; j < 32; ++j) {
      float u = traw[j];
      r += (u < v) || (u == v && j < tid);
    }
    ts[r] = v;
  }
  __syncthreads();
  if (tid < 32) tabs[TAB_BP + tid] = ts[tid];
  for (int idx = tid; idx < NSEG * 32; idx += blockDim.x) {
    int s = idx >> 5, j = idx & 31;
    float a;  // representative point strictly inside segment s: (ts[s-1], ts[s]]
    if (s == 0)            a = ts[0] - 1.0f;
    else if (s == NSEG - 1) a = ts[31] + 1.0f;
    else                   a = 0.5f * ts[s - 1] + 0.5f * ts[s];
    float d = 0.0f, c = 0.0f;
    for (int i = 0; i < 32; ++i) {
      float w = eW1[i], b = eb1[i];
      if (fmaf(a, w, b) > 0.0f) {
        float w2 = eW2[i * 32 + j];
        d = fmaf(w, w2, d);
        c = fmaf(b, w2, c);
      }
    }
    c += eb2[j];
    dt[idx] = d; ct[idx] = c;
    tabs[TAB_D1 + idx] = d;
    tabs[TAB_C1 + idx] = c;
  }
  __syncthreads();
  for (int idx = tid; idx < NSEG * 64; idx += blockDim.x) {
    int s = idx >> 6, k = idx & 63;
    float ds = 0.f, cs = 0.f, dg = 0.f, cg = 0.f;
    for (int j = 0; j < 32; ++j) {
      float dv = dt[s * 32 + j], cv = ct[s * 32 + j];
      float ws = sLW[j * 64 + k], wg = gLW[j * 64 + k];
      ds = fmaf(dv, ws, ds); cs = fmaf(cv, ws, cs);
      dg = fmaf(dv, wg, dg); cg = fmaf(cv, wg, cg);
    }
    cs += sLb[k]; cg += gLb[k];
    tabs[TAB_E2 + idx]                 = ds;
    tabs[TAB_E2 + NSEG * 64 + idx]     = cs;
    tabs[TAB_E2 + 2 * NSEG * 64 + idx] = dg;
    tabs[TAB_E2 + 3 * NSEG * 64 + idx] = cg;
  }
}

// ---------------------------------------------------------------------------
// Fused front: three INDEPENDENT jobs in one launch (block-range dispatch):
//   blocks [0, ABLK)           : coarse partition into fixed-capacity buckets
//   blocks [ABLK, ABLK+782)    : node embed (x0 + fp16 shadow)
//   blocks [ABLK+782, +782)    : batch boundaries from sorted bat arrays
// Entry in part[]: src(17) | dlocal(8)<<17 | seg(6)<<25.
// ---------------------------------------------------------------------------
__global__ __launch_bounds__(256) void fused_front(
    const int* __restrict__ names_s, const int* __restrict__ names_g,
    const float* __restrict__ idW1, const float* __restrict__ idb1,
    const float* __restrict__ idW2, const float* __restrict__ idb2,
    const int* __restrict__ src_s, const int* __restrict__ dst_s, const float* __restrict__ attr_s,
    const int* __restrict__ src_g, const int* __restrict__ dst_g, const float* __restrict__ attr_g,
    const int* __restrict__ bat_s, const int* __restrict__ bat_g,
    const float* __restrict__ tabs,
    float* __restrict__ x0, __half* __restrict__ x0h,
    int* __restrict__ gcur, int2* __restrict__ part,
    int* __restrict__ start_s, int* __restrict__ start_g) {
  __shared__ int hist[NC];
  __shared__ int lofs[NC];
  __shared__ int lcur[NC];
  __shared__ int2 sorted[TILE];
  __shared__ int addr[TILE];
  __shared__ int scanbuf[256];
  __shared__ float bp[32];
  int t = threadIdx.x;
  if (blockIdx.x < ABLK) {
    // ---- coarse partition tile ----
    if (t < 32) bp[t] = tabs[TAB_BP + t];
    for (int i = t; i < NC; i += 256) hist[i] = 0;
    __syncthreads();
    int base = blockIdx.x * TILE;
#pragma unroll
    for (int j = 0; j < 16; ++j) {
      int i = base + j * 256 + t;
      if (i < TE) {
        int d = (i < NEDG) ? dst_s[i] : (dst_g[i - NEDG] + NN);
        atomicAdd(&hist[d >> 8], 1);
      }
    }
    __syncthreads();
    int loc[4];
    int sum = 0;
#pragma unroll
    for (int j = 0; j < 4; ++j) {
      int b = t * 4 + j;
      int v = (b < NC) ? hist[b] : 0;
      loc[j] = sum; sum += v;
    }
    scanbuf[t] = sum;
    __syncthreads();
    for (int st = 1; st < 256; st <<= 1) {
      int u = (t >= st) ? scanbuf[t - st] : 0;
      __syncthreads();
      scanbuf[t] += u;
      __syncthreads();
    }
    int texcl = scanbuf[t] - sum;
#pragma unroll
    for (int j = 0; j < 4; ++j) {
      int b = t * 4 + j;
      if (b < NC) { lofs[b] = texcl + loc[j]; lcur[b] = 0; }
    }
    __syncthreads();
    // reserve space in each bucket's fixed-capacity region
    for (int b = t; b < NC; b += 256) {
      int c = hist[b];
      hist[b] = c ? atomicAdd(&gcur[b], c) : 0;
    }
    __syncthreads();
#pragma unroll
    for (int j = 0; j < 16; ++j) {
      int i = base + j * 256 + t;
      if (i < TE) {
        int sl, d; float a;
        if (i < NEDG) { sl = src_s[i]; d = dst_s[i]; a = attr_s[i]; }
        else { int k = i - NEDG; sl = src_g[k]; d = dst_g[k] + NN; a = attr_g[k]; }
        int seg = 0;
#pragma unroll
        for (int q = 0; q < 32; ++q) seg += (bp[q] < a);
        int c = d >> 8;
        int r = atomicAdd(&lcur[c], 1);
        int s = lofs[c] + r;
        sorted[s] = make_int2(sl | ((d & 255) << 17) | (seg << 25), __float_as_int(a));
        addr[s] = c * ENTCAP + hist[c] + r;
      }
    }
    __syncthreads();
    int tot = (base + TILE <= TE) ? TILE : (TE - base);
    for (int s = t; s < tot; s += 256) part[addr[s]] = sorted[s];
  } else if (blockIdx.x < ABLK + 782) {
    // ---- node embed (both graphs) ----
    int n = (blockIdx.x - ABLK) * 256 + t;
    if (n >= TN) return;
    int name = (n < NN) ? names_s[n] : names_g[n - NN];
    float norm = ((float)name + 2.0f) / 281474976710655.0f;
    norm = fminf(fmaxf(norm, 0.0f), 1.0f);
    float h[32];
#pragma unroll
    for (int i = 0; i < 32; ++i) h[i] = relu_(fmaf(norm, idW1[i], idb1[i]));
    float4* out = (float4*)(x0 + (size_t)n * 32);
    int2* outh = (int2*)(x0h + (size_t)n * 32);
    for (int j0 = 0; j0 < 32; j0 += 4) {
      float a0 = idb2[j0], a1 = idb2[j0 + 1], a2 = idb2[j0 + 2], a3 = idb2[j0 + 3];
#pragma unroll
      for (int i = 0; i < 32; ++i) {
        float hv = h[i];
        a0 = fmaf(hv, idW2[i * 32 + j0],     a0);
        a1 = fmaf(hv, idW2[i * 32 + j0 + 1], a1);
        a2 = fmaf(hv, idW2[i * 32 + j0 + 2], a2);
        a3 = fmaf(hv, idW2[i * 32 + j0 + 3], a3);
      }
      out[j0 >> 2] = make_float4(a0, a1, a2, a3);
      outh[j0 >> 2] = make_int2(f2h2(a0, a1), f2h2(a2, a3));
    }
  } else {
    // ---- batch boundaries ----
    int blk = blockIdx.x - ABLK - 782;
    int half = blk >= 391;
    const int* bat = half ? bat_g : bat_s;
    int* start = half ? start_g : start_s;
    int i = (blk - half * 391) * 256 + t;
    if (i >= NN) return;
    int cur = bat[i];
    int prev = (i == 0) ? -1 : bat[i - 1];
    for (int b = prev + 1; b <= cur; ++b) start[b] = i;
    if (i == NN - 1) {
      for (int b = cur + 1; b <= NBAT; ++b) start[b] = NN;
    }
  }
}

__global__ __launch_bounds__(1024) void coarse_scan(
    const int* __restrict__ gcur, int* __restrict__ cbase, int* __restrict__ rowptr) {
  __shared__ int s[1024];
  int t = threadIdx.x;
  int v = (t < NC) ? min(gcur[t], ENTCAP) : 0;
  s[t] = v;
  __syncthreads();
  for (int st = 1; st < 1024; st <<= 1) {
    int u = (t >= st) ? s[t - st] : 0;
    __syncthreads();
    s[t] += u;
    __syncthreads();
  }
  if (t < NC) cbase[t] = s[t] - v;
  if (t == 0) rowptr[TN] = TE;
}

__global__ __launch_bounds__(256) void partition_to_csr(
    const int* __restrict__ gcur, const int* __restrict__ cbase,
    const int2* __restrict__ part,
    int* __restrict__ rowptr, int2* __restrict__ colattr) {
  __shared__ int2 outE[ENTCAP];  // 40 KB
  __shared__ int hist[256];
  __shared__ int cur[256];
  __shared__ int sc[256];
  int t = threadIdx.x, b = blockIdx.x;  // grid exact: NC
  hist[t] = 0;
  __syncthreads();
  int cnt = min(gcur[b], ENTCAP);
  int ibase = b * ENTCAP;
  int obase = cbase[b];
  for (int i = t; i < cnt; i += 256)
    atomicAdd(&hist[(part[ibase + i].x >> 17) & 255], 1);
  __syncthreads();
  int v = hist[t];
  sc[t] = v;
  __syncthreads();
  for (int st = 1; st < 256; st <<= 1) {
    int u = (t >= st) ? sc[t - st] : 0;
    __syncthreads();
    sc[t] += u;
    __syncthreads();
  }
  int excl = sc[t] - v;
  int gnode = b * 256 + t;
  if (gnode < TN) rowptr[gnode] = obase + excl;
  cur[t] = excl;
  __syncthreads();
  for (int i = t; i < cnt; i += 256) {
    int2 e = part[ibase + i];
    int dl = (e.x >> 17) & 255;
    int srcn = e.x & 0x1FFFF;
    int seg = (e.x >> 25) & 63;
    int pos = atomicAdd(&cur[dl], 1);
    outE[pos] = make_int2(srcn | (seg << 20), e.y);  // conv format: src<2^17, seg<64
  }
  __syncthreads();
  for (int i = t; i < cnt; i += 256) colattr[obase + i] = outE[i];
}

// ---------------------------------------------------------------------------
// GINE aggregation over BOTH graphs, dst-major. Gather source = fp16 shadow;
// edge math in packed fp16 (LDS tables as half2: halves LDS traffic + pk-fma
// halves the fma/add count); relu + accumulate in fp32. r8 lane layout.
// ---------------------------------------------------------------------------
__global__ __launch_bounds__(256) void conv1_dual(
    const float* __restrict__ x0, const __half* __restrict__ x0h,
    const int* __restrict__ rowptr, const int2* __restrict__ colattr,
    const float* __restrict__ tabs, float* __restrict__ hb) {
  __shared__ __half2 dt2[NSEG * S1H];
  __shared__ __half2 ct2[NSEG * S1H];
  for (int i = threadIdx.x; i < NSEG * 16; i += 256) {
    int s = i >> 4, j = i & 15;
    dt2[s * S1H + j] = __floats2half2_rn(tabs[TAB_D1 + s * 32 + 2 * j],
                                         tabs[TAB_D1 + s * 32 + 2 * j + 1]);
    ct2[s * S1H + j] = __floats2half2_rn(tabs[TAB_C1 + s * 32 + 2 * j],
                                         tabs[TAB_C1 + s * 32 + 2 * j + 1]);
  }
  __syncthreads();
  int n = blockIdx.x * 4 + (threadIdx.x >> 6);  // grid exact: TN/4
  const __half* xb = x0h + (n >= NN ? (size_t)NN * 32 : 0);  // src ids graph-local
  int lane = threadIdx.x & 63;
  int sub = lane & 7;        // 8 edges in flight (x2 unroll = 16)
  int f0  = (lane >> 3) * 4; // 4 features per lane
  int h0  = (lane >> 3) * 2; // half2 index
  int beg = rowptr[n], end = rowptr[n + 1];
  float4 acc = make_float4(0.f, 0.f, 0.f, 0.f);
  for (int k = beg + sub; k < end; k += 16) {
    int2 ca0 = colattr[k];
    int kb = k + 8;
    bool has1 = kb < end;
    int2 ca1 = has1 ? colattr[kb] : ca0;
    unsigned p0 = (unsigned)ca0.x, p1 = (unsigned)ca1.x;
    int s0 = (int)(p0 & 0xFFFFFu), g0 = (int)(p0 >> 20);
    int s1 = (int)(p1 & 0xFFFFFu), g1 = (int)(p1 >> 20);
    float a0 = __int_as_float(ca0.y), a1 = __int_as_float(ca1.y);
    __half2 az0 = __floats2half2_rn(a0, a0);
    __half2 az1 = __floats2half2_rn(a1, a1);
    int2 xv0 = *(const int2*)(xb + (size_t)s0 * 32 + f0);
    int2 xv1 = *(const int2*)(xb + (size_t)s1 * 32 + f0);
    int2 dv0 = *(const int2*)&dt2[g0 * S1H + h0];
    int2 cv0 = *(const int2*)&ct2[g0 * S1H + h0];
    __half2 v;
    float2 f;
    v = __hadd2(bch(xv0.x), __hfma2(az0, bch(dv0.x), bch(cv0.x)));
    f = __half22float2(v); acc.x += relu_(f.x); acc.y += relu_(f.y);
    v = __hadd2(bch(xv0.y), __hfma2(az0, bch(dv0.y), bch(cv0.y)));
    f = __half22float2(v); acc.z += relu_(f.x); acc.w += relu_(f.y);
    if (has1) {
      int2 dv1 = *(const int2*)&dt2[g1 * S1H + h0];
      int2 cv1 = *(const int2*)&ct2[g1 * S1H + h0];
      v = __hadd2(bch(xv1.x), __hfma2(az1, bch(dv1.x), bch(cv1.x)));
      f = __half22float2(v); acc.x += relu_(f.x); acc.y += relu_(f.y);
      v = __hadd2(bch(xv1.y), __hfma2(az1, bch(dv1.y), bch(cv1.y)));
      f = __half22float2(v); acc.z += relu_(f.x); acc.w += relu_(f.y);
    }
  }
#pragma unroll
  for (int m = 1; m < 8; m <<= 1) {
    float4 o = shfl_xor4(acc, m);
    acc.x += o.x; acc.y += o.y; acc.z += o.z; acc.w += o.w;
  }
  if (sub == 0) {
    const float4 self = *(const float4*)(x0 + (size_t)n * 32 + f0);
    *(float4*)(hb + (size_t)n * 32 + f0) =
        make_float4(self.x + acc.x, self.y + acc.y, self.z + acc.z, self.w + acc.w);
  }
}

__global__ __launch_bounds__(256) void conv2_dual(
    const float* __restrict__ x1, const __half* __restrict__ x1h,
    const int* __restrict__ rowptr, const int2* __restrict__ colattr,
    const float* __restrict__ tabs, float* __restrict__ hb) {
  __shared__ __half2 dt2[NSEG * S2H];
  __shared__ __half2 ct2[NSEG * S2H];
  int half = blockIdx.x >= (NN / 4);   // block's 4 nodes never span (NN%4==0)
  const float* d2 = tabs + TAB_E2 + (size_t)half * 2 * NSEG * 64;
  for (int i = threadIdx.x; i < NSEG * 32; i += 256) {
    int s = i >> 5, j = i & 31;
    dt2[s * S2H + j] = __floats2half2_rn(d2[s * 64 + 2 * j], d2[s * 64 + 2 * j + 1]);
    ct2[s * S2H + j] = __floats2half2_rn(d2[NSEG * 64 + s * 64 + 2 * j],
                                         d2[NSEG * 64 + s * 64 + 2 * j + 1]);
  }
  __syncthreads();
  int n = blockIdx.x * 4 + (threadIdx.x >> 6);  // grid exact: TN/4
  const __half* xb = x1h + (size_t)half * NN * 64;  // src ids graph-local
  int lane = threadIdx.x & 63;
  int sub = lane & 7;        // 8 edges in flight (x2 unroll = 16)
  int f0  = (lane >> 3) * 8; // 8 features per lane
  int h0  = (lane >> 3) * 4; // half2 index
  int beg = rowptr[n], end = rowptr[n + 1];
  float4 accA = make_float4(0.f, 0.f, 0.f, 0.f);
  float4 accB = make_float4(0.f, 0.f, 0.f, 0.f);
  for (int k = beg + sub; k < end; k += 16) {
    int2 ca0 = colattr[k];
    int kb = k + 8;
    bool has1 = kb < end;
    int2 ca1 = has1 ? colattr[kb] : ca0;
    unsigned p0 = (unsigned)ca0.x, p1 = (unsigned)ca1.x;
    int s0 = (int)(p0 & 0xFFFFFu), g0 = (int)(p0 >> 20);
    int s1 = (int)(p1 & 0xFFFFFu), g1 = (int)(p1 >> 20);
    float a0 = __int_as_float(ca0.y), a1 = __int_as_float(ca1.y);
    __half2 az0 = __floats2half2_rn(a0, a0);
    __half2 az1 = __floats2half2_rn(a1, a1);
    int4 xv0 = *(const int4*)(xb + (size_t)s0 * 64 + f0);
    int4 xv1 = *(const int4*)(xb + (size_t)s1 * 64 + f0);
    int4 dv0 = *(const int4*)&dt2[g0 * S2H + h0];
    int4 cv0 = *(const int4*)&ct2[g0 * S2H + h0];
    __half2 v;
    float2 f;
    v = __hadd2(bch(xv0.x), __hfma2(az0, bch(dv0.x), bch(cv0.x)));
    f = __half22float2(v); accA.x += relu_(f.x); accA.y += relu_(f.y);
    v = __hadd2(bch(xv0.y), __hfma2(az0, bch(dv0.y), bch(cv0.y)));
    f = __half22float2(v); accA.z += relu_(f.x); accA.w += relu_(f.y);
    v = __hadd2(bch(xv0.z), __hfma2(az0, bch(dv0.z), bch(cv0.z)));
    f = __half22float2(v); accB.x += relu_(f.x); accB.y += relu_(f.y);
    v = __hadd2(bch(xv0.w), __hfma2(az0, bch(dv0.w), bch(cv0.w)));
    f = __half22float2(v); accB.z += relu_(f.x); accB.w += relu_(f.y);
    if (has1) {
      int4 dv1 = *(const int4*)&dt2[g1 * S2H + h0];
      int4 cv1 = *(const int4*)&ct2[g1 * S2H + h0];
      v = __hadd2(bch(xv1.x), __hfma2(az1, bch(dv1.x), bch(cv1.x)));
      f = __half22float2(v); accA.x += relu_(f.x); accA.y += relu_(f.y);
      v = __hadd2(bch(xv1.y), __hfma2(az1, bch(dv1.y), bch(cv1.y)));
      f = __half22float2(v); accA.z += relu_(f.x); accA.w += relu_(f.y);
      v = __hadd2(bch(xv1.z), __hfma2(az1, bch(dv1.z), bch(cv1.z)));
      f = __half22float2(v); accB.x += relu_(f.x); accB.y += relu_(f.y);
      v = __hadd2(bch(xv1.w), __hfma2(az1, bch(dv1.w), bch(cv1.w)));
      f = __half22float2(v); accB.z += relu_(f.x); accB.w += relu_(f.y);
    }
  }
#pragma unroll
  for (int m = 1; m < 8; m <<= 1) {
    float4 oA = shfl_xor4(accA, m);
    float4 oB = shfl_xor4(accB, m);
    accA.x += oA.x; accA.y += oA.y; accA.z += oA.z; accA.w += oA.w;
    accB.x += oB.x; accB.y += oB.y; accB.z += oB.z; accB.w += oB.w;
  }
  if (sub == 0) {
    const float* sp = x1 + (size_t)n * 64 + f0;
    const float4 sA = *(const float4*)sp;
    const float4 sB = *(const float4*)(sp + 4);
    float* op = hb + (size_t)n * 64 + f0;
    *(float4*)op       = make_float4(sA.x + accA.x, sA.y + accA.y, sA.z + accA.z, sA.w + accA.w);
    *(float4*)(op + 4) = make_float4(sB.x + accB.x, sB.y + accB.y, sB.z + accB.z, sB.w + accB.w);
  }
}

// ---------------------------------------------------------------------------
// Per-node MLP2 (32 -> 64 -> 64) over BOTH graphs, with fp16 shadow output.
// Register-tiled VALU GEMM: 64 nodes/block, thread owns 4 nodes x 4 features.
// ---------------------------------------------------------------------------
__global__ __launch_bounds__(256) void mlp1_dual(
    const float* __restrict__ hin,
    const float* __restrict__ sW1, const float* __restrict__ sb1,
    const float* __restrict__ sW2, const float* __restrict__ sb2,
    const float* __restrict__ gW1, const float* __restrict__ gb1,
    const float* __restrict__ gW2, const float* __restrict__ gb2,
    float* __restrict__ xout, __half* __restrict__ hout) {
  constexpr int IN = 32;
  __shared__ float hsT[IN][65];
  __shared__ float ysT[64][65];
  int base = blockIdx.x * 64;     // grid exact: TN/64 = 3125
  for (int idx = threadIdx.x; idx < 64 * IN; idx += 256) {
    int node = idx / IN, k = idx - node * IN;
    hsT[k][node] = hin[(size_t)(base + node) * IN + k];
  }
  __syncthreads();
  int nt = threadIdx.x >> 4, jx = threadIdx.x & 15;
  int n0 = nt * 4, f0 = jx * 4;
  bool isg = (base + n0) >= NN;
  const float* W1 = isg ? gW1 : sW1;
  const float* b1 = isg ? gb1 : sb1;
  const float* W2 = isg ? gW2 : sW2;
  const float* b2 = isg ? gb2 : sb2;
  float4 acc0, acc1, acc2, acc3;
  {
    const float4 b = *(const float4*)(b1 + f0);
    acc0 = b; acc1 = b; acc2 = b; acc3 = b;
  }
  for (int k = 0; k < IN; ++k) {
    const float4 h = *(const float4*)&hsT[k][n0];
    const float4 w = *(const float4*)(W1 + k * 64 + f0);
    acc0.x = fmaf(h.x, w.x, acc0.x); acc0.y = fmaf(h.x, w.y, acc0.y);
    acc0.z = fmaf(h.x, w.z, acc0.z); acc0.w = fmaf(h.x, w.w, acc0.w);
    acc1.x = fmaf(h.y, w.x, acc1.x); acc1.y = fmaf(h.y, w.y, acc1.y);
    acc1.z = fmaf(h.y, w.z, acc1.z); acc1.w = fmaf(h.y, w.w, acc1.w);
    acc2.x = fmaf(h.z, w.x, acc2.x); acc2.y = fmaf(h.z, w.y, acc2.y);
    acc2.z = fmaf(h.z, w.z, acc2.z); acc2.w = fmaf(h.z, w.w, acc2.w);
    acc3.x = fmaf(h.w, w.x, acc3.x); acc3.y = fmaf(h.w, w.y, acc3.y);
    acc3.z = fmaf(h.w, w.z, acc3.z); acc3.w = fmaf(h.w, w.w, acc3.w);
  }
  ysT[f0 + 0][n0 + 0] = relu_(acc0.x); ysT[f0 + 1][n0 + 0] = relu_(acc0.y);
  ysT[f0 + 2][n0 + 0] = relu_(acc0.z); ysT[f0 + 3][n0 + 0] = relu_(acc0.w);
  ysT[f0 + 0][n0 + 1] = relu_(acc1.x); ysT[f0 + 1][n0 + 1] = relu_(acc1.y);
  ysT[f0 + 2][n0 + 1] = relu_(acc1.z); ysT[f0 + 3][n0 + 1] = relu_(acc1.w);
  ysT[f0 + 0][n0 + 2] = relu_(acc2.x); ysT[f0 + 1][n0 + 2] = relu_(acc2.y);
  ysT[f0 + 2][n0 + 2] = relu_(acc2.z); ysT[f0 + 3][n0 + 2] = relu_(acc2.w);
  ysT[f0 + 0][n0 + 3] = relu_(acc3.x); ysT[f0 + 1][n0 + 3] = relu_(acc3.y);
  ysT[f0 + 2][n0 + 3] = relu_(acc3.z); ysT[f0 + 3][n0 + 3] = relu_(acc3.w);
  __syncthreads();
  {
    const float4 b = *(const float4*)(b2 + f0);
    acc0 = b; acc1 = b; acc2 = b; acc3 = b;
  }
  for (int k = 0; k < 64; ++k) {
    const float4 h = *(const float4*)&ysT[k][n0];
    const float4 w = *(const float4*)(W2 + k * 64 + f0);
    acc0.x = fmaf(h.x, w.x, acc0.x); acc0.y = fmaf(h.x, w.y, acc0.y);
    acc0.z = fmaf(h.x, w.z, acc0.z); acc0.w = fmaf(h.x, w.w, acc0.w);
    acc1.x = fmaf(h.y, w.x, acc1.x); acc1.y = fmaf(h.y, w.y, acc1.y);
    acc1.z = fmaf(h.y, w.z, acc1.z); acc1.w = fmaf(h.y, w.w, acc1.w);
    acc2.x = fmaf(h.z, w.x, acc2.x); acc2.y = fmaf(h.z, w.y, acc2.y);
    acc2.z = fmaf(h.z, w.z, acc2.z); acc2.w = fmaf(h.z, w.w, acc2.w);
    acc3.x = fmaf(h.w, w.x, acc3.x); acc3.y = fmaf(h.w, w.y, acc3.y);
    acc3.z = fmaf(h.w, w.z, acc3.z); acc3.w = fmaf(h.w, w.w, acc3.w);
  }
  float4 o;
  o = make_float4(relu_(acc0.x), relu_(acc0.y), relu_(acc0.z), relu_(acc0.w));
  *(float4*)(xout + (size_t)(base + n0 + 0) * 64 + f0) = o;
  *(int2*)(hout + (size_t)(base + n0 + 0) * 64 + f0) = make_int2(f2h2(o.x, o.y), f2h2(o.z, o.w));
  o = make_float4(relu_(acc1.x), relu_(acc1.y), relu_(acc1.z), relu_(acc1.w));
  *(float4*)(xout + (size_t)(base + n0 + 1) * 64 + f0) = o;
  *(int2*)(hout + (size_t)(base + n0 + 1) * 64 + f0) = make_int2(f2h2(o.x, o.y), f2h2(o.z, o.w));
  o = make_float4(relu_(acc2.x), relu_(acc2.y), relu_(acc2.z), relu_(acc2.w));
  *(float4*)(xout + (size_t)(base + n0 + 2) * 64 + f0) = o;
  *(int2*)(hout + (size_t)(base + n0 + 2) * 64 + f0) = make_int2(f2h2(o.x, o.y), f2h2(o.z, o.w));
  o = make_float4(relu_(acc3.x), relu_(acc3.y), relu_(acc3.z), relu_(acc3.w));
  *(float4*)(xout + (size_t)(base + n0 + 3) * 64 + f0) = o;
  *(int2*)(hout + (size_t)(base + n0 + 3) * 64 + f0) = make_int2(f2h2(o.x, o.y), f2h2(o.z, o.w));
}

// ---------------------------------------------------------------------------
// mlp2 + pool fused: outputs go to LDS, per-block run-length reduction over
// batch segments, ~300 fp32 atomics/block into psum (no x2 round-trip).
// psum rows: [0,NBAT) = graph s sums, [NBAT,2*NBAT) = graph g sums.
// ---------------------------------------------------------------------------
__global__ __launch_bounds__(256) void mlp2_pool_dual(
    const float* __restrict__ hin,
    const float* __restrict__ sW1, const float* __restrict__ sb1,
    const float* __restrict__ sW2, const float* __restrict__ sb2,
    const float* __restrict__ gW1, const float* __restrict__ gb1,
    const float* __restrict__ gW2, const float* __restrict__ gb2,
    const int* __restrict__ bat_s, const int* __restrict__ bat_g,
    float* __restrict__ psum) {
  constexpr int IN = 64;
  __shared__ float hsT[IN][65];
  __shared__ float ysT[64][65];
  __shared__ int pid[64];
  int base = blockIdx.x * 64;     // grid exact: TN/64 = 3125
  for (int idx = threadIdx.x; idx < 64 * IN; idx += 256) {
    int node = idx / IN, k = idx - node * IN;
    hsT[k][node] = hin[(size_t)(base + node) * IN + k];
  }
  if (threadIdx.x < 64) {
    int gb = base + threadIdx.x;
    pid[threadIdx.x] = (gb < NN) ? bat_s[gb] : (NBAT + bat_g[gb - NN]);
  }
  __syncthreads();
  int nt = threadIdx.x >> 4, jx = threadIdx.x & 15;
  int n0 = nt * 4, f0 = jx * 4;
  bool isg = (base + n0) >= NN;
  const float* W1 = isg ? gW1 : sW1;
  const float* b1 = isg ? gb1 : sb1;
  const float* W2 = isg ? gW2 : sW2;
  const float* b2 = isg ? gb2 : sb2;
  float4 acc0, acc1, acc2, acc3;
  {
    const float4 b = *(const float4*)(b1 + f0);
    acc0 = b; acc1 = b; acc2 = b; acc3 = b;
  }
  for (int k = 0; k < IN; ++k) {
    const float4 h = *(const float4*)&hsT[k][n0];
    const float4 w = *(const float4*)(W1 + k * 64 + f0);
    acc0.x = fmaf(h.x, w.x, acc0.x); acc0.y = fmaf(h.x, w.y, acc0.y);
    acc0.z = fmaf(h.x, w.z, acc0.z); acc0.w = fmaf(h.x, w.w, acc0.w);
    acc1.x = fmaf(h.y, w.x, acc1.x); acc1.y = fmaf(h.y, w.y, acc1.y);
    acc1.z = fmaf(h.y, w.z, acc1.z); acc1.w = fmaf(h.y, w.w, acc1.w);
    acc2.x = fmaf(h.z, w.x, acc2.x); acc2.y = fmaf(h.z, w.y, acc2.y);
    acc2.z = fmaf(h.z, w.z, acc2.z); acc2.w = fmaf(h.z, w.w, acc2.w);
    acc3.x = fmaf(h.w, w.x, acc3.x); acc3.y = fmaf(h.w, w.y, acc3.y);
    acc3.z = fmaf(h.w, w.z, acc3.z); acc3.w = fmaf(h.w, w.w, acc3.w);
  }
  ysT[f0 + 0][n0 + 0] = relu_(acc0.x); ysT[f0 + 1][n0 + 0] = relu_(acc0.y);
  ysT[f0 + 2][n0 + 0] = relu_(acc0.z); ysT[f0 + 3][n0 + 0] = relu_(acc0.w);
  ysT[f0 + 0][n0 + 1] = relu_(acc1.x); ysT[f0 + 1][n0 + 1] = relu_(acc1.y);
  ysT[f0 + 2][n0 + 1] = relu_(acc1.z); ysT[f0 + 3][n0 + 1] = relu_(acc1.w);
  ysT[f0 + 0][n0 + 2] = relu_(acc2.x); ysT[f0 + 1][n0 + 2] = relu_(acc2.y);
  ysT[f0 + 2][n0 + 2] = relu_(acc2.z); ysT[f0 + 3][n0 + 2] = relu_(acc2.w);
  ysT[f0 + 0][n0 + 3] = relu_(acc3.x); ysT[f0 + 1][n0 + 3] = relu_(acc3.y);
  ysT[f0 + 2][n0 + 3] = relu_(acc3.z); ysT[f0 + 3][n0 + 3] = relu_(acc3.w);
  __syncthreads();
  {
    const float4 b = *(const float4*)(b2 + f0);
    acc0 = b; acc1 = b; acc2 = b; acc3 = b;
  }
  for (int k = 0; k < 64; ++k) {
    const float4 h = *(const float4*)&ysT[k][n0];
    const float4 w = *(const float4*)(W2 + k * 64 + f0);
    acc0.x = fmaf(h.x, w.x, acc0.x); acc0.y = fmaf(h.x, w.y, acc0.y);
    acc0.z = fmaf(h.x, w.z, acc0.z); acc0.w = fmaf(h.x, w.w, acc0.w);
    acc1.x = fmaf(h.y, w.x, acc1.x); acc1.y = fmaf(h.y, w.y, acc1.y);
    acc1.z = fmaf(h.y, w.z, acc1.z); acc1.w = fmaf(h.y, w.w, acc1.w);
    acc2.x = fmaf(h.z, w.x, acc2.x); acc2.y = fmaf(h.z, w.y, acc2.y);
    acc2.z = fmaf(h.z, w.z, acc2.z); acc2.w = fmaf(h.z, w.w, acc2.w);
    acc3.x = fmaf(h.w, w.x, acc3.x); acc3.y = fmaf(h.w, w.y, acc3.y);
    acc3.z = fmaf(h.w, w.z, acc3.z); acc3.w = fmaf(h.w, w.w, acc3.w);
  }
  __syncthreads();  // all reads of ysT done; reuse it for outputs [f][node]
  ysT[f0 + 0][n0 + 0] = relu_(acc0.x); ysT[f0 + 1][n0 + 0] = relu_(acc0.y);
  ysT[f0 + 2][n0 + 0] = relu_(acc0.z); ysT[f0 + 3][n0 + 0] = relu_(acc0.w);
  ysT[f0 + 0][n0 + 1] = relu_(acc1.x); ysT[f0 + 1][n0 + 1] = relu_(acc1.y);
  ysT[f0 + 2][n0 + 1] = relu_(acc1.z); ysT[f0 + 3][n0 + 1] = relu_(acc1.w);
  ysT[f0 + 0][n0 + 2] = relu_(acc2.x); ysT[f0 + 1][n0 + 2] = relu_(acc2.y);
  ysT[f0 + 2][n0 + 2] = relu_(acc2.z); ysT[f0 + 3][n0 + 2] = relu_(acc2.w);
  ysT[f0 + 0][n0 + 3] = relu_(acc3.x); ysT[f0 + 1][n0 + 3] = relu_(acc3.y);
  ysT[f0 + 2][n0 + 3] = relu_(acc3.z); ysT[f0 + 3][n0 + 3] = relu_(acc3.w);
  __syncthreads();
  // pool: thread (c, f) sums nodes [c*16, c*16+16) of feature f, flushing
  // per batch-segment run (nodes are sorted by batch within each graph)
  int c = threadIdx.x >> 6, f = threadIdx.x & 63;
  int cur = pid[c * 16];
  float run = 0.0f;
  for (int i = 0; i < 16; ++i) {
    int nx = c * 16 + i;
    int p = pid[nx];
    if (p != cur) { atomicAdd(&psum[(size_t)cur * 64 + f], run); run = 0.0f; cur = p; }
    run += ysT[f][nx];
  }
  atomicAdd(&psum[(size_t)cur * 64 + f], run);
}

// ---------------------------------------------------------------------------
// regressor: out[b] = relu([s_mean|g_mean|depth] @ rW1 + rb1) @ rW2 + rb2
// ---------------------------------------------------------------------------
__global__ __launch_bounds__(256) void regressor16(
    const float* __restrict__ psum,
    const int* __restrict__ start_s, const int* __restrict__ start_g,
    const float* __restrict__ depth,
    const float* __restrict__ W1, const float* __restrict__ b1,
    const float* __restrict__ W2, const float* __restrict__ b2,
    float* __restrict__ out) {
  __shared__ float zs[16][132];   // [row][k], k in [0,129)
  __shared__ float ys[64][17];
  __shared__ float inv_s[16], inv_g[16];
  int base = blockIdx.x * 16;     // grid 32 blocks x 16 rows = 512 exact
  if (threadIdx.x < 16) {
    int b = base + threadIdx.x;
    inv_s[threadIdx.x] = 1.0f / fmaxf((float)(start_s[b + 1] - start_s[b]), 1.0f);
    inv_g[threadIdx.x] = 1.0f / fmaxf((float)(start_g[b + 1] - start_g[b]), 1.0f);
  }
  __syncthreads();
  for (int i = threadIdx.x; i < 16 * 64; i += 256) {
    int ln = i >> 6, k = i & 63;
    zs[ln][k]      = psum[(size_t)(base + ln) * 64 + k] * inv_s[ln];
    zs[ln][64 + k] = psum[(size_t)(NBAT + base + ln) * 64 + k] * inv_g[ln];
  }
  if (threadIdx.x < 16) zs[threadIdx.x][128] = depth[base + threadIdx.x];
  __syncthreads();
  int g = threadIdx.x >> 4;
  int j = threadIdx.x & 15;
  int f0 = j * 4;
  float a0, a1, a2, a3;
  {
    const float4 b = *(const float4*)(b1 + f0);
    a0 = b.x; a1 = b.y; a2 = b.z; a3 = b.w;
  }
  for (int k = 0; k < 129; ++k) {
    float zv = zs[g][k];
    const float4 w = *(const float4*)(W1 + k * 64 + f0);
    a0 = fmaf(zv, w.x, a0); a1 = fmaf(zv, w.y, a1);
    a2 = fmaf(zv, w.z, a2); a3 = fmaf(zv, w.w, a3);
  }
  ys[f0 + 0][g] = relu_(a0);
  ys[f0 + 1][g] = relu_(a1);
  ys[f0 + 2][g] = relu_(a2);
  ys[f0 + 3][g] = relu_(a3);
  __syncthreads();
  float s = ys[f0 + 0][g] * W2[f0 + 0] + ys[f0 + 1][g] * W2[f0 + 1] +
            ys[f0 + 2][g] * W2[f0 + 2] + ys[f0 + 3][g] * W2[f0 + 3];
#pragma unroll
  for (int m = 1; m < 16; m <<= 1) s += __shfl_xor(s, m);
  if (j == 0) out[base + g] = s + b2[0];
}

}  // namespace

extern "C" void kernel_launch(void* const* d_in, const int* in_sizes, int n_in,
                              void* d_out, int out_size, void* d_ws, size_t ws_size,
                              hipStream_t stream) {
  const int*   names_s = (const int*)d_in[0];
  const int*   ei_s    = (const int*)d_in[1];
  const float* ea_s    = (const float*)d_in[2];
  const int*   bat_s   = (const int*)d_in[3];
  const int*   names_g = (const int*)d_in[4];
  const int*   ei_g    = (const int*)d_in[5];
  const float* ea_g    = (const float*)d_in[6];
  const int*   bat_g   = (const int*)d_in[7];
  const float* depth   = (const float*)d_in[8];
  const float* idW1 = (const float*)d_in[9],  *idb1 = (const float*)d_in[10];
  const float* idW2 = (const float*)d_in[11], *idb2 = (const float*)d_in[12];
  const float* edW1 = (const float*)d_in[13], *edb1 = (const float*)d_in[14];
  const float* edW2 = (const float*)d_in[15], *edb2 = (const float*)d_in[16];
  const float* s1W1 = (const float*)d_in[17], *s1b1 = (const float*)d_in[18];
  const float* s1W2 = (const float*)d_in[19], *s1b2 = (const float*)d_in[20];
  const float* s2W1 = (const float*)d_in[21], *s2b1 = (const float*)d_in[22];
  const float* s2W2 = (const float*)d_in[23], *s2b2 = (const float*)d_in[24];
  const float* s2LW = (const float*)d_in[25], *s2Lb = (const float*)d_in[26];
  const float* g1W1 = (const float*)d_in[27], *g1b1 = (const float*)d_in[28];
  const float* g1W2 = (const float*)d_in[29], *g1b2 = (const float*)d_in[30];
  const float* g2W1 = (const float*)d_in[31], *g2b1 = (const float*)d_in[32];
  const float* g2W2 = (const float*)d_in[33], *g2b2 = (const float*)d_in[34];
  const float* g2LW = (const float*)d_in[35], *g2Lb = (const float*)d_in[36];
  const float* rW1  = (const float*)d_in[37], *rb1  = (const float*)d_in[38];
  const float* rW2  = (const float*)d_in[39], *rb2  = (const float*)d_in[40];
  (void)in_sizes; (void)n_in; (void)out_size; (void)ws_size;

  char* ws = (char*)d_ws;
  size_t off = 0;
  auto alloc = [&](size_t bytes) -> char* {
    char* p = ws + off;
    off += (bytes + 255) & ~(size_t)255;
    return p;
  };
  float* tabs    = (float*)alloc((size_t)TAB_TOTAL * 4);
  // Activation region (102.4 MB):
  //   x0 [TN][32] at [0, 25.6M); h1 [TN][32] at [25.6M, 51.2M);
  //   x1 [TN][64] at [51.2M, 102.4M).
  //   part scratch (NC*ENTCAP*8 = 32.03M) aliases the x1 region -- consumed
  //   by partition_to_csr before mlp1 writes x1; disjoint from x0/h1 so the
  //   fused_front launch can run embed and partition concurrently.
  //   h2 [TN][64] aliases [0, 51.2M) (x0+h1 dead by conv2).
  char*  act   = alloc((size_t)TN * 64 * 4 * 2);            // 102,400,000 B
  float* x0buf = (float*)act;
  float* h1buf = (float*)(act + (size_t)TN * 32 * 4);
  float* x1buf = (float*)(act + (size_t)TN * 64 * 4);
  int2*  part  = (int2*)x1buf;
  float* h2buf = (float*)act;
  __half* x0h  = (__half*)alloc((size_t)TN * 32 * 2);       // 12.8 MB fp16 shadow
  __half* x1h  = (__half*)alloc((size_t)TN * 64 * 2);       // 25.6 MB fp16 shadow
  int2*  colattr = (int2*) alloc((size_t)TE * 8);           // final CSR order
  int*   gcur    = (int*)  alloc((size_t)NC * 4);
  int*   cbase   = (int*)  alloc((size_t)NC * 4);
  int*   rowptr  = (int*)  alloc((size_t)(TN + 1) * 4);
  int*   start_s = (int*)  alloc((size_t)(NBAT + 1) * 4);
  int*   start_g = (int*)  alloc((size_t)(NBAT + 1) * 4);
  float* psum    = (float*)alloc((size_t)2 * NBAT * 64 * 4);

  build_tables<<<1, 256, 0, stream>>>(edW1, edb1, edW2, edb2, s2LW, s2Lb, g2LW, g2Lb, tabs);
  hipMemsetAsync(gcur, 0, (size_t)NC * 4, stream);
  hipMemsetAsync(psum, 0, (size_t)2 * NBAT * 64 * 4, stream);

  // embed || partition || batch_bounds in one launch
  fused_front<<<ABLK + 782 + 782, 256, 0, stream>>>(
      names_s, names_g, idW1, idb1, idW2, idb2,
      ei_s, ei_s + NEDG, ea_s, ei_g, ei_g + NEDG, ea_g,
      bat_s, bat_g, tabs, x0buf, x0h, gcur, part, start_s, start_g);
  coarse_scan<<<1, 1024, 0, stream>>>(gcur, cbase, rowptr);
  partition_to_csr<<<NC, 256, 0, stream>>>(gcur, cbase, part, rowptr, colattr);

  conv1_dual<<<TN / 4, 256, 0, stream>>>(x0buf, x0h, rowptr, colattr, tabs, h1buf);
  mlp1_dual<<<TN / 64, 256, 0, stream>>>(h1buf,
                                         s1W1, s1b1, s1W2, s1b2,
                                         g1W1, g1b1, g1W2, g1b2, x1buf, x1h);
  conv2_dual<<<TN / 4, 256, 0, stream>>>(x1buf, x1h, rowptr, colattr, tabs, h2buf);
  mlp2_pool_dual<<<TN / 64, 256, 0, stream>>>(h2buf,
                                              s2W1, s2b1, s2W2, s2b2,
                                              g2W1, g2b1, g2W2, g2b2,
                                              bat_s, bat_g, psum);
  regressor16<<<32, 256, 0, stream>>>(psum, start_s, start_g, depth,
                                      rW1, rb1, rW2, rb2, (float*)d_out);
}